// Round 2
// baseline (2928.485 us; speedup 1.0000x reference)
//
#include <hip/hip_runtime.h>
#include <math.h>

#define CDIV(a,b) (((a)+(b)-1)/(b))

// float atomic max via int/uint trick (valid across mixed signs, init = -inf)
__device__ inline void atomicMaxF(float* addr, float val) {
  if (val >= 0.f) atomicMax((int*)addr, __float_as_int(val));
  else            atomicMin((unsigned int*)addr, __float_as_uint(val));
}

// ---------------- x = triplets(float) @ Wd + bd ----------------
__global__ void k_drug(const int* __restrict__ trip, const float* __restrict__ Wd,
                       const float* __restrict__ bd, float* __restrict__ x, int N) {
  int i = blockIdx.x * 256 + threadIdx.x;
  if (i >= N * 128) return;
  int n = i >> 7, c = i & 127;
  const int* t = trip + n * 4;
  float acc = bd[c];
  acc += (float)t[0] * Wd[c] + (float)t[1] * Wd[128 + c] +
         (float)t[2] * Wd[256 + c] + (float)t[3] * Wd[384 + c];
  x[i] = acc;
}

// ---------------- generic tiled fp32 GEMM: C = act(A[NxK]@B[KxM] + bias) ----------------
template <bool RELU>
__global__ void k_gemm(const float* __restrict__ A, const float* __restrict__ B,
                       const float* __restrict__ bias, float* __restrict__ C,
                       int N, int K, int M) {
  const int BM = 64, BN = 64, BK = 16;
  __shared__ float As[BK][BM + 1];
  __shared__ float Bs[BK][BN + 1];
  int tid = threadIdx.x;
  int tn = tid % 16, tm = tid / 16;
  int row0 = blockIdx.y * BM, col0 = blockIdx.x * BN;
  float acc[4][4] = {};
  for (int k0 = 0; k0 < K; k0 += BK) {
    for (int i = tid; i < BM * BK; i += 256) {
      int r = i / BK, kk = i % BK;
      int gr = row0 + r, gk = k0 + kk;
      As[kk][r] = (gr < N && gk < K) ? A[(size_t)gr * K + gk] : 0.f;
    }
    for (int i = tid; i < BK * BN; i += 256) {
      int kk = i / BN, cc = i % BN;
      int gk = k0 + kk, gc = col0 + cc;
      Bs[kk][cc] = (gk < K && gc < M) ? B[(size_t)gk * M + gc] : 0.f;
    }
    __syncthreads();
#pragma unroll
    for (int kk = 0; kk < BK; ++kk) {
      float a[4], b[4];
#pragma unroll
      for (int i = 0; i < 4; i++) a[i] = As[kk][tm * 4 + i];
#pragma unroll
      for (int j = 0; j < 4; j++) b[j] = Bs[kk][tn * 4 + j];
#pragma unroll
      for (int i = 0; i < 4; i++)
#pragma unroll
        for (int j = 0; j < 4; j++) acc[i][j] += a[i] * b[j];
    }
    __syncthreads();
  }
  for (int i = 0; i < 4; i++) {
    int gr = row0 + tm * 4 + i;
    if (gr >= N) continue;
    for (int j = 0; j < 4; j++) {
      int gc = col0 + tn * 4 + j;
      if (gc >= M) continue;
      float v = acc[i][j] + (bias ? bias[gc] : 0.f);
      if (RELU) v = fmaxf(v, 0.f);
      C[(size_t)gr * M + gc] = v;
    }
  }
}

// ---------------- es/ed per (node, head): dot(xh[n,h,:], a[h,:]) over C=128 ----------------
__global__ void k_coef(const float* __restrict__ xh, const float* __restrict__ as_,
                       const float* __restrict__ ad_, float* __restrict__ es,
                       float* __restrict__ ed, int N, int H) {
  int wid = (blockIdx.x * blockDim.x + threadIdx.x) >> 6;
  int lane = threadIdx.x & 63;
  if (wid >= N * H) return;
  int n = wid / H, h = wid % H;
  const float* xp = xh + ((size_t)n * H + h) * 128;
  const float* ap = as_ + h * 128;
  const float* bp = ad_ + h * 128;
  float x0 = xp[lane], x1 = xp[lane + 64];
  float e1 = x0 * ap[lane] + x1 * ap[lane + 64];
  float e2 = x0 * bp[lane] + x1 * bp[lane + 64];
  for (int off = 32; off; off >>= 1) {
    e1 += __shfl_xor(e1, off);
    e2 += __shfl_xor(e2, off);
  }
  if (lane == 0) { es[wid] = e1; ed[wid] = e2; }
}

__global__ void k_fill(float* p, float v, int n) {
  int i = blockIdx.x * 256 + threadIdx.x;
  if (i < n) p[i] = v;
}

// edge enumeration: i in [0, (E+N)*H); e<E uses edge list (skip self loops = masked),
// e>=E is the re-added self loop (always valid)
__global__ void k_edge_max(const int* __restrict__ src0, const int* __restrict__ dst0,
                           const float* __restrict__ es, const float* __restrict__ ed,
                           float* __restrict__ m, int E, int N, int H) {
  int i = blockIdx.x * 256 + threadIdx.x;
  if (i >= (E + N) * H) return;
  int e = i / H, h = i % H;
  int s, d;
  if (e < E) { s = src0[e]; d = dst0[e]; if (s == d) return; }
  else { s = d = e - E; }
  float v = es[s * H + h] + ed[d * H + h];
  v = v > 0.f ? v : 0.2f * v;
  atomicMaxF(&m[d * H + h], v);
}

__global__ void k_edge_sum(const int* __restrict__ src0, const int* __restrict__ dst0,
                           const float* __restrict__ es, const float* __restrict__ ed,
                           const float* __restrict__ m, float* __restrict__ ssum,
                           int E, int N, int H) {
  int i = blockIdx.x * 256 + threadIdx.x;
  if (i >= (E + N) * H) return;
  int e = i / H, h = i % H;
  int s, d;
  if (e < E) { s = src0[e]; d = dst0[e]; if (s == d) return; }
  else { s = d = e - E; }
  float v = es[s * H + h] + ed[d * H + h];
  v = v > 0.f ? v : 0.2f * v;
  atomicAdd(&ssum[d * H + h], __expf(v - m[d * H + h]));
}

// one wave per (edge, head); lanes cover the 128-wide channel dim
__global__ void k_edge_scatter(const int* __restrict__ src0, const int* __restrict__ dst0,
                               const float* __restrict__ es, const float* __restrict__ ed,
                               const float* __restrict__ m, const float* __restrict__ ssum,
                               const float* __restrict__ xh, float* __restrict__ gout,
                               int E, int N, int H) {
  int wid = (blockIdx.x * blockDim.x + threadIdx.x) >> 6;
  int lane = threadIdx.x & 63;
  if (wid >= (E + N) * H) return;
  int e = wid / H, h = wid % H;
  int s, d;
  if (e < E) { s = src0[e]; d = dst0[e]; if (s == d) return; }
  else { s = d = e - E; }
  float v = es[s * H + h] + ed[d * H + h];
  v = v > 0.f ? v : 0.2f * v;
  float alpha = __expf(v - m[d * H + h]) / ssum[d * H + h];
  const float* xs = xh + ((size_t)s * H + h) * 128;
  float* go = gout + ((size_t)d * H + h) * 128;
  atomicAdd(&go[lane], alpha * xs[lane]);
  atomicAdd(&go[lane + 64], alpha * xs[lane + 64]);
}

// g = elu(g + bias[col])  in place over N x HC
__global__ void k_bias_elu(float* __restrict__ g, const float* __restrict__ bias,
                           int total, int HC) {
  for (int i = blockIdx.x * blockDim.x + threadIdx.x; i < total;
       i += gridDim.x * blockDim.x) {
    float v = g[i] + bias[i % HC];
    g[i] = v > 0.f ? v : expm1f(v);
  }
}

// column sums of A[N x 128] accumulated into colsum[128]
__global__ void k_colsum(const float* __restrict__ A, float* __restrict__ colsum, int N) {
  int c = threadIdx.x;  // 128 threads
  int rows_per_block = CDIV(N, (int)gridDim.x);
  int r0 = blockIdx.x * rows_per_block;
  int r1 = min(N, r0 + rows_per_block);
  float acc = 0.f;
  for (int r = r0; r < r1; ++r) acc += A[(size_t)r * 128 + c];
  atomicAdd(&colsum[c], acc);
}

// single block: h = colsum/N; t1=relu(h@Wfc+bfc)[256]; hg=t1@Whg+bhg[128]; v_=relu(hg@Wv+bv)[384]
__global__ void k_head(const float* __restrict__ colsum, const float* __restrict__ Wfc,
                       const float* __restrict__ bfc, const float* __restrict__ Whg,
                       const float* __restrict__ bhg, const float* __restrict__ Wv,
                       const float* __restrict__ bv, float* __restrict__ vvec, float invN) {
  __shared__ float h[128], t1[256], hg[128];
  int t = threadIdx.x;  // 256
  if (t < 128) h[t] = colsum[t] * invN;
  __syncthreads();
  float acc = bfc[t];
  for (int k = 0; k < 128; k++) acc += h[k] * Wfc[k * 256 + t];
  t1[t] = fmaxf(acc, 0.f);
  __syncthreads();
  if (t < 128) {
    float a2 = bhg[t];
    for (int k = 0; k < 256; k++) a2 += t1[k] * Whg[k * 128 + t];
    hg[t] = a2;
  }
  __syncthreads();
  for (int j = t; j < 384; j += 256) {
    float a3 = bv[j];
    for (int k = 0; k < 128; k++) a3 += hg[k] * Wv[k * 384 + j];
    vvec[j] = fmaxf(a3, 0.f);
  }
}

// per-batch-row BAN: attsum[b] = sum_k hsum[k]*v[k]*q[b,k] + sum(h_bias);
// logits[b,c] = attsum[b] * sum_{j<3} v[3c+j]*q[b,3c+j]
__global__ void k_fused(const float* __restrict__ vvec, const float* __restrict__ q,
                        const float* __restrict__ hmat, const float* __restrict__ hbias,
                        float* __restrict__ logits) {
  int b = blockIdx.x, c = threadIdx.x;  // 128 threads
  __shared__ float red[128];
  float t[3];
  float part = 0.f;
#pragma unroll
  for (int j = 0; j < 3; j++) {
    int k = c * 3 + j;
    float hs = hmat[k] + hmat[384 + k] + hmat[768 + k] + hmat[1152 + k];
    t[j] = vvec[k] * q[(size_t)b * 384 + k];
    part += hs * t[j];
  }
  red[c] = part;
  __syncthreads();
  for (int s = 64; s > 0; s >>= 1) {
    if (c < s) red[c] += red[c + s];
    __syncthreads();
  }
  float attsum = red[0] + (hbias[0] + hbias[1] + hbias[2] + hbias[3]);
  logits[(size_t)b * 128 + c] = attsum * (t[0] + t[1] + t[2]);
}

// batchnorm over batch dim (biased var), one block per channel c
__global__ void k_bn(const float* __restrict__ logits, const float* __restrict__ gamma,
                     const float* __restrict__ beta, float* __restrict__ out, int B) {
  int c = blockIdx.x, b = threadIdx.x;  // B threads
  __shared__ float s1[256], s2[256];
  float v = logits[(size_t)b * 128 + c];
  s1[b] = v; s2[b] = v * v;
  __syncthreads();
  for (int s = B / 2; s > 0; s >>= 1) {
    if (b < s) { s1[b] += s1[b + s]; s2[b] += s2[b + s]; }
    __syncthreads();
  }
  float mu = s1[0] / B;
  float var = s2[0] / B - mu * mu;
  out[(size_t)b * 128 + c] = (v - mu) * rsqrtf(var + 1e-5f) * gamma[c] + beta[c];
}

extern "C" void kernel_launch(void* const* d_in, const int* in_sizes, int n_in,
                              void* d_out, int out_size, void* d_ws, size_t ws_size,
                              hipStream_t stream) {
  const float* cell = (const float*)d_in[0];
  const float* Wd   = (const float*)d_in[1];
  const float* bd   = (const float*)d_in[2];
  const float* W1   = (const float*)d_in[3];
  const float* a1s  = (const float*)d_in[4];
  const float* a1d  = (const float*)d_in[5];
  const float* b1   = (const float*)d_in[6];
  const float* Wl1  = (const float*)d_in[7];
  const float* bl1  = (const float*)d_in[8];
  const float* W2   = (const float*)d_in[9];
  const float* a2s  = (const float*)d_in[10];
  const float* a2d  = (const float*)d_in[11];
  const float* b2   = (const float*)d_in[12];
  const float* Wl2  = (const float*)d_in[13];
  const float* bl2  = (const float*)d_in[14];
  const float* Wfc  = (const float*)d_in[15];
  const float* bfc  = (const float*)d_in[16];
  const float* Whg  = (const float*)d_in[17];
  const float* bhg  = (const float*)d_in[18];
  const float* Wc   = (const float*)d_in[19];
  const float* bc   = (const float*)d_in[20];
  const float* Wv   = (const float*)d_in[21];
  const float* bv   = (const float*)d_in[22];
  const float* Wq   = (const float*)d_in[23];
  const float* bq   = (const float*)d_in[24];
  const float* hmat = (const float*)d_in[25];
  const float* hbias= (const float*)d_in[26];
  const float* gamma= (const float*)d_in[27];
  const float* beta = (const float*)d_in[28];
  const int* trip   = (const int*)d_in[29];
  const int* eidx   = (const int*)d_in[30];

  const int N = in_sizes[29] / 4;     // 20000
  const int E = in_sizes[30] / 2;     // 500000
  const int B = in_sizes[0] / 954;    // 256
  float* out = (float*)d_out;

  // workspace layout (floats) — total ~34M floats ~136 MB
  float* ws     = (float*)d_ws;
  float* x      = ws;
  float* h1     = x + (size_t)N * 128;
  float* h2     = h1 + (size_t)N * 128;
  float* xh     = h2 + (size_t)N * 128;     // N*640
  float* gout   = xh + (size_t)N * 640;     // N*640
  float* es     = gout + (size_t)N * 640;   // N*5
  float* ed     = es + (size_t)N * 5;
  float* mbuf   = ed + (size_t)N * 5;
  float* sbuf   = mbuf + (size_t)N * 5;
  float* colsum = sbuf + (size_t)N * 5;     // 128
  float* cbuf   = colsum + 128;             // B*128
  float* qbuf   = cbuf + (size_t)B * 128;   // B*384
  float* vvec   = qbuf + (size_t)B * 384;   // 384
  float* logits = vvec + 384;               // B*128

  const int* src0 = eidx;
  const int* dst0 = eidx + E;

  (void)hipMemsetAsync(colsum, 0, 128 * sizeof(float), stream);
  k_drug<<<CDIV(N * 128, 256), 256, 0, stream>>>(trip, Wd, bd, x, N);

  // ---------------- GAT1 (H=4) ----------------
  {
    dim3 g(CDIV(512, 64), CDIV(N, 64));
    k_gemm<false><<<g, 256, 0, stream>>>(x, W1, nullptr, xh, N, 128, 512);
  }
  k_coef<<<CDIV(N * 4, 4), 256, 0, stream>>>(xh, a1s, a1d, es, ed, N, 4);
  k_fill<<<CDIV(N * 5, 256), 256, 0, stream>>>(mbuf, -INFINITY, N * 5);
  (void)hipMemsetAsync(sbuf, 0, (size_t)N * 5 * sizeof(float), stream);
  {
    int tot = (E + N) * 4;
    k_edge_max<<<CDIV(tot, 256), 256, 0, stream>>>(src0, dst0, es, ed, mbuf, E, N, 4);
    k_edge_sum<<<CDIV(tot, 256), 256, 0, stream>>>(src0, dst0, es, ed, mbuf, sbuf, E, N, 4);
    (void)hipMemsetAsync(gout, 0, (size_t)N * 512 * sizeof(float), stream);
    k_edge_scatter<<<CDIV(tot * 64, 256), 256, 0, stream>>>(src0, dst0, es, ed, mbuf, sbuf,
                                                            xh, gout, E, N, 4);
  }
  k_bias_elu<<<2048, 256, 0, stream>>>(gout, b1, N * 512, 512);
  {
    dim3 g(CDIV(128, 64), CDIV(N, 64));
    k_gemm<false><<<g, 256, 0, stream>>>(gout, Wl1, bl1, h1, N, 512, 128);
  }
  k_colsum<<<256, 128, 0, stream>>>(h1, colsum, N);

  // ---------------- GAT2 (H=5) ----------------
  {
    dim3 g(CDIV(640, 64), CDIV(N, 64));
    k_gemm<false><<<g, 256, 0, stream>>>(h1, W2, nullptr, xh, N, 128, 640);
  }
  k_coef<<<CDIV(N * 5, 4), 256, 0, stream>>>(xh, a2s, a2d, es, ed, N, 5);
  k_fill<<<CDIV(N * 5, 256), 256, 0, stream>>>(mbuf, -INFINITY, N * 5);
  (void)hipMemsetAsync(sbuf, 0, (size_t)N * 5 * sizeof(float), stream);
  {
    int tot = (E + N) * 5;
    k_edge_max<<<CDIV(tot, 256), 256, 0, stream>>>(src0, dst0, es, ed, mbuf, E, N, 5);
    k_edge_sum<<<CDIV(tot, 256), 256, 0, stream>>>(src0, dst0, es, ed, mbuf, sbuf, E, N, 5);
    (void)hipMemsetAsync(gout, 0, (size_t)N * 640 * sizeof(float), stream);
    k_edge_scatter<<<CDIV(tot * 64, 256), 256, 0, stream>>>(src0, dst0, es, ed, mbuf, sbuf,
                                                            xh, gout, E, N, 5);
  }
  k_bias_elu<<<2048, 256, 0, stream>>>(gout, b2, N * 640, 640);
  {
    dim3 g(CDIV(128, 64), CDIV(N, 64));
    k_gemm<false><<<g, 256, 0, stream>>>(gout, Wl2, bl2, h2, N, 640, 128);
  }
  k_colsum<<<256, 128, 0, stream>>>(h2, colsum, N);

  // ---------------- head + BAN + BN ----------------
  k_head<<<1, 256, 0, stream>>>(colsum, Wfc, bfc, Whg, bhg, Wv, bv, vvec, 1.0f / N);
  {
    dim3 g(CDIV(128, 64), CDIV(B, 64));
    k_gemm<true><<<g, 256, 0, stream>>>(cell, Wc, bc, cbuf, B, 954, 128);
  }
  {
    dim3 g(CDIV(384, 64), CDIV(B, 64));
    k_gemm<true><<<g, 256, 0, stream>>>(cbuf, Wq, bq, qbuf, B, 128, 384);
  }
  k_fused<<<B, 128, 0, stream>>>(vvec, qbuf, hmat, hbias, logits);
  k_bn<<<128, B, 0, stream>>>(logits, gamma, beta, out, B);
}

// Round 3
// 1261.625 us; speedup vs baseline: 2.3212x; 2.3212x over previous
//
#include <hip/hip_runtime.h>
#include <math.h>

#define CDIV(a,b) (((a)+(b)-1)/(b))

// ---------------- x = triplets(float) @ Wd + bd ----------------
__global__ void k_drug(const int* __restrict__ trip, const float* __restrict__ Wd,
                       const float* __restrict__ bd, float* __restrict__ x, int N) {
  int i = blockIdx.x * 256 + threadIdx.x;
  if (i >= N * 128) return;
  int n = i >> 7, c = i & 127;
  const int* t = trip + n * 4;
  float acc = bd[c];
  acc += (float)t[0] * Wd[c] + (float)t[1] * Wd[128 + c] +
         (float)t[2] * Wd[256 + c] + (float)t[3] * Wd[384 + c];
  x[i] = acc;
}

// ---------------- generic tiled fp32 GEMM: C = act(A[NxK]@B[KxM] + bias) ----------------
template <bool RELU>
__global__ void k_gemm(const float* __restrict__ A, const float* __restrict__ B,
                       const float* __restrict__ bias, float* __restrict__ C,
                       int N, int K, int M) {
  const int BM = 64, BN = 64, BK = 16;
  __shared__ float As[BK][BM + 1];
  __shared__ float Bs[BK][BN + 1];
  int tid = threadIdx.x;
  int tn = tid % 16, tm = tid / 16;
  int row0 = blockIdx.y * BM, col0 = blockIdx.x * BN;
  float acc[4][4] = {};
  for (int k0 = 0; k0 < K; k0 += BK) {
    for (int i = tid; i < BM * BK; i += 256) {
      int r = i / BK, kk = i % BK;
      int gr = row0 + r, gk = k0 + kk;
      As[kk][r] = (gr < N && gk < K) ? A[(size_t)gr * K + gk] : 0.f;
    }
    for (int i = tid; i < BK * BN; i += 256) {
      int kk = i / BN, cc = i % BN;
      int gk = k0 + kk, gc = col0 + cc;
      Bs[kk][cc] = (gk < K && gc < M) ? B[(size_t)gk * M + gc] : 0.f;
    }
    __syncthreads();
#pragma unroll
    for (int kk = 0; kk < BK; ++kk) {
      float a[4], b[4];
#pragma unroll
      for (int i = 0; i < 4; i++) a[i] = As[kk][tm * 4 + i];
#pragma unroll
      for (int j = 0; j < 4; j++) b[j] = Bs[kk][tn * 4 + j];
#pragma unroll
      for (int i = 0; i < 4; i++)
#pragma unroll
        for (int j = 0; j < 4; j++) acc[i][j] += a[i] * b[j];
    }
    __syncthreads();
  }
  for (int i = 0; i < 4; i++) {
    int gr = row0 + tm * 4 + i;
    if (gr >= N) continue;
    for (int j = 0; j < 4; j++) {
      int gc = col0 + tn * 4 + j;
      if (gc >= M) continue;
      float v = acc[i][j] + (bias ? bias[gc] : 0.f);
      if (RELU) v = fmaxf(v, 0.f);
      C[(size_t)gr * M + gc] = v;
    }
  }
}

// ---------------- es/ed per (node, head): dot(xh[n,h,:], a[h,:]) over C=128 ----------------
__global__ void k_coef(const float* __restrict__ xh, const float* __restrict__ as_,
                       const float* __restrict__ ad_, float* __restrict__ es,
                       float* __restrict__ ed, int N, int H) {
  int wid = (blockIdx.x * blockDim.x + threadIdx.x) >> 6;
  int lane = threadIdx.x & 63;
  if (wid >= N * H) return;
  int n = wid / H, h = wid % H;
  const float* xp = xh + ((size_t)n * H + h) * 128;
  const float* ap = as_ + h * 128;
  const float* bp = ad_ + h * 128;
  float x0 = xp[lane], x1 = xp[lane + 64];
  float e1 = x0 * ap[lane] + x1 * ap[lane + 64];
  float e2 = x0 * bp[lane] + x1 * bp[lane + 64];
  for (int off = 32; off; off >>= 1) {
    e1 += __shfl_xor(e1, off);
    e2 += __shfl_xor(e2, off);
  }
  if (lane == 0) { es[wid] = e1; ed[wid] = e2; }
}

// ---------------- CSR build (by destination; self loops excluded, handled implicitly) ----
__global__ void k_deg(const int* __restrict__ src0, const int* __restrict__ dst0,
                      int* __restrict__ deg, int E) {
  int e = blockIdx.x * 256 + threadIdx.x;
  if (e >= E) return;
  int s = src0[e], d = dst0[e];
  if (s != d) atomicAdd(&deg[d], 1);
}

__global__ void k_scan(const int* __restrict__ deg, int* __restrict__ rowptr, int N) {
  __shared__ int part[1024];
  int t = threadIdx.x;
  int chunk = (N + 1023) >> 10;
  int b0 = t * chunk, b1 = min(N, b0 + chunk);
  int s = 0;
  for (int i = b0; i < b1; i++) s += deg[i];
  part[t] = s;
  __syncthreads();
  for (int off = 1; off < 1024; off <<= 1) {
    int v = (t >= off) ? part[t - off] : 0;
    __syncthreads();
    part[t] += v;
    __syncthreads();
  }
  int run = (t == 0) ? 0 : part[t - 1];
  for (int i = b0; i < b1; i++) { rowptr[i] = run; run += deg[i]; }
  if (b1 == N) rowptr[N] = run;
}

__global__ void k_fill_adj(const int* __restrict__ src0, const int* __restrict__ dst0,
                           const int* __restrict__ rowptr, int* __restrict__ cursor,
                           int* __restrict__ adj, int E) {
  int e = blockIdx.x * 256 + threadIdx.x;
  if (e >= E) return;
  int s = src0[e], d = dst0[e];
  if (s != d) {
    int pos = rowptr[d] + atomicAdd(&cursor[d], 1);
    adj[pos] = s;
  }
}

// ---------------- fused GAT aggregation: one wave per (node, head) ----------------
// segment softmax (incl. self loop) + weighted gather + bias + ELU, no atomics
__global__ void k_gat_gather(const int* __restrict__ rowptr, const int* __restrict__ adj,
                             const float* __restrict__ es, const float* __restrict__ ed,
                             const float* __restrict__ xh, const float* __restrict__ bias,
                             float* __restrict__ gout, int N, int H) {
  int wid = (blockIdx.x * blockDim.x + threadIdx.x) >> 6;
  int lane = threadIdx.x & 63;
  if (wid >= N * H) return;
  int n = wid / H, h = wid % H;
  int base = rowptr[n];
  int deg = rowptr[n + 1] - base;
  float edn = ed[n * H + h];
  float vself = es[n * H + h] + edn;
  vself = vself > 0.f ? vself : 0.2f * vself;
  // phase A: segment max
  float m = vself;
  for (int i = lane; i < deg; i += 64) {
    int s = adj[base + i];
    float v = es[s * H + h] + edn;
    v = v > 0.f ? v : 0.2f * v;
    m = fmaxf(m, v);
  }
#pragma unroll
  for (int off = 32; off; off >>= 1) m = fmaxf(m, __shfl_xor(m, off));
  // phase B: unnormalized accumulate + sum of exp
  float pself = __expf(vself - m);
  const float* xn = xh + ((size_t)n * H + h) * 128;
  float acc0 = pself * xn[lane];
  float acc1 = pself * xn[lane + 64];
  float psum = (lane == 0) ? pself : 0.f;
  for (int c = 0; c < deg; c += 64) {
    int i = c + lane;
    int s = 0;
    float p = 0.f;
    if (i < deg) {
      s = adj[base + i];
      float v = es[s * H + h] + edn;
      v = v > 0.f ? v : 0.2f * v;
      p = __expf(v - m);
      psum += p;
    }
    int cnt = min(64, deg - c);
    for (int j = 0; j < cnt; ++j) {
      float pj = __shfl(p, j);
      int sj = __shfl(s, j);
      const float* xs = xh + ((size_t)sj * H + h) * 128;
      acc0 += pj * xs[lane];
      acc1 += pj * xs[lane + 64];
    }
  }
#pragma unroll
  for (int off = 32; off; off >>= 1) psum += __shfl_xor(psum, off);
  float inv = 1.f / psum;
  float o0 = acc0 * inv + bias[h * 128 + lane];
  float o1 = acc1 * inv + bias[h * 128 + lane + 64];
  o0 = o0 > 0.f ? o0 : expm1f(o0);
  o1 = o1 > 0.f ? o1 : expm1f(o1);
  size_t o = ((size_t)n * H + h) * 128;
  gout[o + lane] = o0;
  gout[o + lane + 64] = o1;
}

// column sums of A[N x 128] accumulated into colsum[128]
__global__ void k_colsum(const float* __restrict__ A, float* __restrict__ colsum, int N) {
  int c = threadIdx.x;  // 128 threads
  int rows_per_block = CDIV(N, (int)gridDim.x);
  int r0 = blockIdx.x * rows_per_block;
  int r1 = min(N, r0 + rows_per_block);
  float acc = 0.f;
  for (int r = r0; r < r1; ++r) acc += A[(size_t)r * 128 + c];
  atomicAdd(&colsum[c], acc);
}

// single block: h = colsum/N; t1=relu(h@Wfc+bfc)[256]; hg=t1@Whg+bhg[128]; v_=relu(hg@Wv+bv)[384]
__global__ void k_head(const float* __restrict__ colsum, const float* __restrict__ Wfc,
                       const float* __restrict__ bfc, const float* __restrict__ Whg,
                       const float* __restrict__ bhg, const float* __restrict__ Wv,
                       const float* __restrict__ bv, float* __restrict__ vvec, float invN) {
  __shared__ float h[128], t1[256], hg[128];
  int t = threadIdx.x;  // 256
  if (t < 128) h[t] = colsum[t] * invN;
  __syncthreads();
  float acc = bfc[t];
  for (int k = 0; k < 128; k++) acc += h[k] * Wfc[k * 256 + t];
  t1[t] = fmaxf(acc, 0.f);
  __syncthreads();
  if (t < 128) {
    float a2 = bhg[t];
    for (int k = 0; k < 256; k++) a2 += t1[k] * Whg[k * 128 + t];
    hg[t] = a2;
  }
  __syncthreads();
  for (int j = t; j < 384; j += 256) {
    float a3 = bv[j];
    for (int k = 0; k < 128; k++) a3 += hg[k] * Wv[k * 384 + j];
    vvec[j] = fmaxf(a3, 0.f);
  }
}

// per-batch-row BAN tail
__global__ void k_fused(const float* __restrict__ vvec, const float* __restrict__ q,
                        const float* __restrict__ hmat, const float* __restrict__ hbias,
                        float* __restrict__ logits) {
  int b = blockIdx.x, c = threadIdx.x;  // 128 threads
  __shared__ float red[128];
  float t[3];
  float part = 0.f;
#pragma unroll
  for (int j = 0; j < 3; j++) {
    int k = c * 3 + j;
    float hs = hmat[k] + hmat[384 + k] + hmat[768 + k] + hmat[1152 + k];
    t[j] = vvec[k] * q[(size_t)b * 384 + k];
    part += hs * t[j];
  }
  red[c] = part;
  __syncthreads();
  for (int s = 64; s > 0; s >>= 1) {
    if (c < s) red[c] += red[c + s];
    __syncthreads();
  }
  float attsum = red[0] + (hbias[0] + hbias[1] + hbias[2] + hbias[3]);
  logits[(size_t)b * 128 + c] = attsum * (t[0] + t[1] + t[2]);
}

// batchnorm over batch dim (biased var), one block per channel c
__global__ void k_bn(const float* __restrict__ logits, const float* __restrict__ gamma,
                     const float* __restrict__ beta, float* __restrict__ out, int B) {
  int c = blockIdx.x, b = threadIdx.x;  // B threads
  __shared__ float s1[256], s2[256];
  float v = logits[(size_t)b * 128 + c];
  s1[b] = v; s2[b] = v * v;
  __syncthreads();
  for (int s = B / 2; s > 0; s >>= 1) {
    if (b < s) { s1[b] += s1[b + s]; s2[b] += s2[b + s]; }
    __syncthreads();
  }
  float mu = s1[0] / B;
  float var = s2[0] / B - mu * mu;
  out[(size_t)b * 128 + c] = (v - mu) * rsqrtf(var + 1e-5f) * gamma[c] + beta[c];
}

extern "C" void kernel_launch(void* const* d_in, const int* in_sizes, int n_in,
                              void* d_out, int out_size, void* d_ws, size_t ws_size,
                              hipStream_t stream) {
  const float* cell = (const float*)d_in[0];
  const float* Wd   = (const float*)d_in[1];
  const float* bd   = (const float*)d_in[2];
  const float* W1   = (const float*)d_in[3];
  const float* a1s  = (const float*)d_in[4];
  const float* a1d  = (const float*)d_in[5];
  const float* b1   = (const float*)d_in[6];
  const float* Wl1  = (const float*)d_in[7];
  const float* bl1  = (const float*)d_in[8];
  const float* W2   = (const float*)d_in[9];
  const float* a2s  = (const float*)d_in[10];
  const float* a2d  = (const float*)d_in[11];
  const float* b2   = (const float*)d_in[12];
  const float* Wl2  = (const float*)d_in[13];
  const float* bl2  = (const float*)d_in[14];
  const float* Wfc  = (const float*)d_in[15];
  const float* bfc  = (const float*)d_in[16];
  const float* Whg  = (const float*)d_in[17];
  const float* bhg  = (const float*)d_in[18];
  const float* Wc   = (const float*)d_in[19];
  const float* bc   = (const float*)d_in[20];
  const float* Wv   = (const float*)d_in[21];
  const float* bv   = (const float*)d_in[22];
  const float* Wq   = (const float*)d_in[23];
  const float* bq   = (const float*)d_in[24];
  const float* hmat = (const float*)d_in[25];
  const float* hbias= (const float*)d_in[26];
  const float* gamma= (const float*)d_in[27];
  const float* beta = (const float*)d_in[28];
  const int* trip   = (const int*)d_in[29];
  const int* eidx   = (const int*)d_in[30];

  const int N = in_sizes[29] / 4;     // 20000
  const int E = in_sizes[30] / 2;     // 500000
  const int B = in_sizes[0] / 954;    // 256
  float* out = (float*)d_out;

  // workspace layout
  float* ws     = (float*)d_ws;
  float* x      = ws;                          // N*128
  float* h1     = x + (size_t)N * 128;         // N*128
  float* h2     = h1 + (size_t)N * 128;        // N*128
  float* xh     = h2 + (size_t)N * 128;        // N*640
  float* gout   = xh + (size_t)N * 640;        // N*640
  float* es     = gout + (size_t)N * 640;      // N*5
  float* ed     = es + (size_t)N * 5;          // N*5
  float* colsum = ed + (size_t)N * 5;          // 128
  float* cbuf   = colsum + 128;                // B*128
  float* qbuf   = cbuf + (size_t)B * 128;      // B*384
  float* vvec   = qbuf + (size_t)B * 384;      // 384
  float* logits = vvec + 384;                  // B*128
  int* rowptr   = (int*)(logits + (size_t)B * 128);  // N+1
  int* degb     = rowptr + (N + 1);            // N
  int* cursor   = degb + N;                    // N
  int* adj      = cursor + N;                  // E

  const int* src0 = eidx;
  const int* dst0 = eidx + E;

  (void)hipMemsetAsync(colsum, 0, 128 * sizeof(float), stream);
  (void)hipMemsetAsync(degb, 0, (size_t)2 * N * sizeof(int), stream);

  // ---------------- CSR build (shared by both GAT layers) ----------------
  k_deg<<<CDIV(E, 256), 256, 0, stream>>>(src0, dst0, degb, E);
  k_scan<<<1, 1024, 0, stream>>>(degb, rowptr, N);
  k_fill_adj<<<CDIV(E, 256), 256, 0, stream>>>(src0, dst0, rowptr, cursor, adj, E);

  k_drug<<<CDIV(N * 128, 256), 256, 0, stream>>>(trip, Wd, bd, x, N);

  // ---------------- GAT1 (H=4) ----------------
  {
    dim3 g(CDIV(512, 64), CDIV(N, 64));
    k_gemm<false><<<g, 256, 0, stream>>>(x, W1, nullptr, xh, N, 128, 512);
  }
  k_coef<<<CDIV(N * 4, 4), 256, 0, stream>>>(xh, a1s, a1d, es, ed, N, 4);
  k_gat_gather<<<CDIV(N * 4, 4), 256, 0, stream>>>(rowptr, adj, es, ed, xh, b1, gout, N, 4);
  {
    dim3 g(CDIV(128, 64), CDIV(N, 64));
    k_gemm<false><<<g, 256, 0, stream>>>(gout, Wl1, bl1, h1, N, 512, 128);
  }
  k_colsum<<<256, 128, 0, stream>>>(h1, colsum, N);

  // ---------------- GAT2 (H=5) ----------------
  {
    dim3 g(CDIV(640, 64), CDIV(N, 64));
    k_gemm<false><<<g, 256, 0, stream>>>(h1, W2, nullptr, xh, N, 128, 640);
  }
  k_coef<<<CDIV(N * 5, 4), 256, 0, stream>>>(xh, a2s, a2d, es, ed, N, 5);
  k_gat_gather<<<CDIV(N * 5, 4), 256, 0, stream>>>(rowptr, adj, es, ed, xh, b2, gout, N, 5);
  {
    dim3 g(CDIV(128, 64), CDIV(N, 64));
    k_gemm<false><<<g, 256, 0, stream>>>(gout, Wl2, bl2, h2, N, 640, 128);
  }
  k_colsum<<<256, 128, 0, stream>>>(h2, colsum, N);

  // ---------------- head + BAN + BN ----------------
  k_head<<<1, 256, 0, stream>>>(colsum, Wfc, bfc, Whg, bhg, Wv, bv, vvec, 1.0f / N);
  {
    dim3 g(CDIV(128, 64), CDIV(B, 64));
    k_gemm<true><<<g, 256, 0, stream>>>(cell, Wc, bc, cbuf, B, 954, 128);
  }
  {
    dim3 g(CDIV(384, 64), CDIV(B, 64));
    k_gemm<true><<<g, 256, 0, stream>>>(cbuf, Wq, bq, qbuf, B, 128, 384);
  }
  k_fused<<<B, 128, 0, stream>>>(vvec, qbuf, hmat, hbias, logits);
  k_bn<<<128, B, 0, stream>>>(logits, gamma, beta, out, B);
}

// Round 5
// 939.804 us; speedup vs baseline: 3.1161x; 1.3424x over previous
//
#include <hip/hip_runtime.h>
#include <hip/hip_bf16.h>
#include <math.h>

#define CDIV(a,b) (((a)+(b)-1)/(b))

typedef __attribute__((ext_vector_type(8))) short short8v;   // 8 bf16
typedef __attribute__((ext_vector_type(4))) float f32x4;

// ---------------- weight transpose + bf16 convert: W[K][M] -> Wt[M][K] ----------------
__global__ void k_wconv(const float* __restrict__ W, __hip_bfloat16* __restrict__ Wt,
                        int K, int M) {
  int i = blockIdx.x * 256 + threadIdx.x;
  if (i >= K * M) return;
  int m = i / K, k = i % K;
  Wt[i] = __float2bfloat16(W[(size_t)k * M + m]);
}

// ---------------- x = triplets(float) @ Wd + bd  (bf16 out) ----------------
__global__ void k_drug(const int* __restrict__ trip, const float* __restrict__ Wd,
                       const float* __restrict__ bd, __hip_bfloat16* __restrict__ x, int N) {
  int i = blockIdx.x * 256 + threadIdx.x;
  if (i >= N * 128) return;
  int n = i >> 7, c = i & 127;
  const int* t = trip + n * 4;
  float acc = bd[c];
  acc += (float)t[0] * Wd[c] + (float)t[1] * Wd[128 + c] +
         (float)t[2] * Wd[256 + c] + (float)t[3] * Wd[384 + c];
  x[i] = __float2bfloat16(acc);
}

// ---------------- bf16 MFMA GEMM: C[Nr x M] = A[Nr x K](bf16) @ Bt[M x K](bf16)^T ------
// 64x64 tile, BK=32, 4 waves (2x2), each wave 32x32 via 4x mfma_f32_16x16x32_bf16
template <bool BIAS, bool DUAL>
__global__ void k_gemm_mfma(const __hip_bfloat16* __restrict__ A,
                            const __hip_bfloat16* __restrict__ Bt,
                            const float* __restrict__ bias,
                            float* __restrict__ C, __hip_bfloat16* __restrict__ Cb,
                            int Nr, int K, int M) {
  __shared__ short As[64 * 40];
  __shared__ short Bs[64 * 40];
  int tid = threadIdx.x;
  int lane = tid & 63, wid = tid >> 6;
  int wr = wid >> 1, wc = wid & 1;
  int lrow = lane & 15, lkc = lane >> 4;       // fragment row/col, k-chunk
  int row0 = blockIdx.y * 64, col0 = blockIdx.x * 64;

  // staging coords: each of 256 threads moves one 16B chunk per tile per matrix
  int arow = tid >> 2, akc = tid & 3;
  int grow = row0 + arow; if (grow >= Nr) grow = Nr - 1;
  const __hip_bfloat16* agp = A + (size_t)grow * K + akc * 8;
  const __hip_bfloat16* bgp = Bt + (size_t)(col0 + arow) * K + akc * 8;
  short* asp = &As[arow * 40 + akc * 8];
  short* bsp = &Bs[arow * 40 + akc * 8];

  f32x4 acc00 = {0.f,0.f,0.f,0.f}, acc01 = acc00, acc10 = acc00, acc11 = acc00;

  const short* a0p = &As[(wr * 32 + lrow) * 40 + lkc * 8];
  const short* a1p = &As[(wr * 32 + 16 + lrow) * 40 + lkc * 8];
  const short* b0p = &Bs[(wc * 32 + lrow) * 40 + lkc * 8];
  const short* b1p = &Bs[(wc * 32 + 16 + lrow) * 40 + lkc * 8];

  for (int k0 = 0; k0 < K; k0 += 32) {
    short8v av = *(const short8v*)(agp + k0);
    short8v bv = *(const short8v*)(bgp + k0);
    __syncthreads();
    *(short8v*)asp = av;
    *(short8v*)bsp = bv;
    __syncthreads();
    short8v a0 = *(const short8v*)a0p;
    short8v a1 = *(const short8v*)a1p;
    short8v b0 = *(const short8v*)b0p;
    short8v b1 = *(const short8v*)b1p;
    acc00 = __builtin_amdgcn_mfma_f32_16x16x32_bf16(a0, b0, acc00, 0, 0, 0);
    acc01 = __builtin_amdgcn_mfma_f32_16x16x32_bf16(a0, b1, acc01, 0, 0, 0);
    acc10 = __builtin_amdgcn_mfma_f32_16x16x32_bf16(a1, b0, acc10, 0, 0, 0);
    acc11 = __builtin_amdgcn_mfma_f32_16x16x32_bf16(a1, b1, acc11, 0, 0, 0);
  }

  // C/D layout (m89): col = lane&15, row = (lane>>4)*4 + r
  int rbase = row0 + wr * 32 + (lane >> 4) * 4;
  int cbase = col0 + wc * 32 + lrow;
#pragma unroll
  for (int m = 0; m < 2; ++m) {
#pragma unroll
    for (int n = 0; n < 2; ++n) {
      f32x4 acc = m == 0 ? (n == 0 ? acc00 : acc01) : (n == 0 ? acc10 : acc11);
      int col = cbase + n * 16;
      float bv = BIAS ? bias[col] : 0.f;
#pragma unroll
      for (int r = 0; r < 4; ++r) {
        int grow2 = rbase + m * 16 + r;
        if (grow2 >= Nr) continue;
        float v = acc[r] + bv;
        C[(size_t)grow2 * M + col] = v;
        if (DUAL) Cb[(size_t)grow2 * M + col] = __float2bfloat16(v);
      }
    }
  }
}

// ---------------- fp32 SIMT GEMM (small tail GEMMs only) ----------------
template <bool RELU>
__global__ void k_gemm(const float* __restrict__ A, const float* __restrict__ B,
                       const float* __restrict__ bias, float* __restrict__ C,
                       int N, int K, int M) {
  const int BM = 64, BN = 64, BK = 16;
  __shared__ float As[BK][BM + 1];
  __shared__ float Bs[BK][BN + 1];
  int tid = threadIdx.x;
  int tn = tid % 16, tm = tid / 16;
  int row0 = blockIdx.y * BM, col0 = blockIdx.x * BN;
  float acc[4][4] = {};
  for (int k0 = 0; k0 < K; k0 += BK) {
    for (int i = tid; i < BM * BK; i += 256) {
      int r = i / BK, kk = i % BK;
      int gr = row0 + r, gk = k0 + kk;
      As[kk][r] = (gr < N && gk < K) ? A[(size_t)gr * K + gk] : 0.f;
    }
    for (int i = tid; i < BK * BN; i += 256) {
      int kk = i / BN, cc = i % BN;
      int gk = k0 + kk, gc = col0 + cc;
      Bs[kk][cc] = (gk < K && gc < M) ? B[(size_t)gk * M + gc] : 0.f;
    }
    __syncthreads();
#pragma unroll
    for (int kk = 0; kk < BK; ++kk) {
      float a[4], b[4];
#pragma unroll
      for (int i = 0; i < 4; i++) a[i] = As[kk][tm * 4 + i];
#pragma unroll
      for (int j = 0; j < 4; j++) b[j] = Bs[kk][tn * 4 + j];
#pragma unroll
      for (int i = 0; i < 4; i++)
#pragma unroll
        for (int j = 0; j < 4; j++) acc[i][j] += a[i] * b[j];
    }
    __syncthreads();
  }
  for (int i = 0; i < 4; i++) {
    int gr = row0 + tm * 4 + i;
    if (gr >= N) continue;
    for (int j = 0; j < 4; j++) {
      int gc = col0 + tn * 4 + j;
      if (gc >= M) continue;
      float v = acc[i][j] + (bias ? bias[gc] : 0.f);
      if (RELU) v = fmaxf(v, 0.f);
      C[(size_t)gr * M + gc] = v;
    }
  }
}

// ---------------- es/ed per (node, head): dot(xh[n,h,:], a[h,:]) over C=128 ----------------
__global__ void k_coef(const float* __restrict__ xh, const float* __restrict__ as_,
                       const float* __restrict__ ad_, float* __restrict__ es,
                       float* __restrict__ ed, int N, int H) {
  int wid = (blockIdx.x * blockDim.x + threadIdx.x) >> 6;
  int lane = threadIdx.x & 63;
  if (wid >= N * H) return;
  int n = wid / H, h = wid % H;
  const float* xp = xh + ((size_t)n * H + h) * 128;
  const float* ap = as_ + h * 128;
  const float* bp = ad_ + h * 128;
  float x0 = xp[lane], x1 = xp[lane + 64];
  float e1 = x0 * ap[lane] + x1 * ap[lane + 64];
  float e2 = x0 * bp[lane] + x1 * bp[lane + 64];
  for (int off = 32; off; off >>= 1) {
    e1 += __shfl_xor(e1, off);
    e2 += __shfl_xor(e2, off);
  }
  if (lane == 0) { es[wid] = e1; ed[wid] = e2; }
}

// ---------------- CSR build (by destination; self loops excluded) ----------------
__global__ void k_deg(const int* __restrict__ src0, const int* __restrict__ dst0,
                      int* __restrict__ deg, int E) {
  int e = blockIdx.x * 256 + threadIdx.x;
  if (e >= E) return;
  int s = src0[e], d = dst0[e];
  if (s != d) atomicAdd(&deg[d], 1);
}

__global__ void k_scan(const int* __restrict__ deg, int* __restrict__ rowptr, int N) {
  __shared__ int part[1024];
  int t = threadIdx.x;
  int chunk = (N + 1023) >> 10;
  int b0 = t * chunk, b1 = min(N, b0 + chunk);
  int s = 0;
  for (int i = b0; i < b1; i++) s += deg[i];
  part[t] = s;
  __syncthreads();
  for (int off = 1; off < 1024; off <<= 1) {
    int v = (t >= off) ? part[t - off] : 0;
    __syncthreads();
    part[t] += v;
    __syncthreads();
  }
  int run = (t == 0) ? 0 : part[t - 1];
  for (int i = b0; i < b1; i++) { rowptr[i] = run; run += deg[i]; }
  if (b1 == N) rowptr[N] = run;
}

__global__ void k_fill_adj(const int* __restrict__ src0, const int* __restrict__ dst0,
                           const int* __restrict__ rowptr, int* __restrict__ cursor,
                           int* __restrict__ adj, int E) {
  int e = blockIdx.x * 256 + threadIdx.x;
  if (e >= E) return;
  int s = src0[e], d = dst0[e];
  if (s != d) {
    int pos = rowptr[d] + atomicAdd(&cursor[d], 1);
    adj[pos] = s;
  }
}

// ---------------- fused GAT aggregation: one wave per (node, head), bf16 out ----------------
__global__ void k_gat_gather(const int* __restrict__ rowptr, const int* __restrict__ adj,
                             const float* __restrict__ es, const float* __restrict__ ed,
                             const float* __restrict__ xh, const float* __restrict__ bias,
                             __hip_bfloat16* __restrict__ gout, int N, int H) {
  int wid = (blockIdx.x * blockDim.x + threadIdx.x) >> 6;
  int lane = threadIdx.x & 63;
  if (wid >= N * H) return;
  int n = wid / H, h = wid % H;
  int base = rowptr[n];
  int deg = rowptr[n + 1] - base;
  float edn = ed[n * H + h];
  float vself = es[n * H + h] + edn;
  vself = vself > 0.f ? vself : 0.2f * vself;
  // phase A: segment max
  float m = vself;
  for (int i = lane; i < deg; i += 64) {
    int s = adj[base + i];
    float v = es[s * H + h] + edn;
    v = v > 0.f ? v : 0.2f * v;
    m = fmaxf(m, v);
  }
#pragma unroll
  for (int off = 32; off; off >>= 1) m = fmaxf(m, __shfl_xor(m, off));
  // phase B: unnormalized accumulate + sum of exp
  float pself = __expf(vself - m);
  const float* xn = xh + ((size_t)n * H + h) * 128;
  float acc0 = pself * xn[lane];
  float acc1 = pself * xn[lane + 64];
  float psum = (lane == 0) ? pself : 0.f;
  for (int c = 0; c < deg; c += 64) {
    int i = c + lane;
    int s = 0;
    float p = 0.f;
    if (i < deg) {
      s = adj[base + i];
      float v = es[s * H + h] + edn;
      v = v > 0.f ? v : 0.2f * v;
      p = __expf(v - m);
      psum += p;
    }
    int cnt = min(64, deg - c);
    for (int j = 0; j < cnt; ++j) {
      float pj = __shfl(p, j);
      int sj = __shfl(s, j);
      const float* xs = xh + ((size_t)sj * H + h) * 128;
      acc0 += pj * xs[lane];
      acc1 += pj * xs[lane + 64];
    }
  }
#pragma unroll
  for (int off = 32; off; off >>= 1) psum += __shfl_xor(psum, off);
  float inv = 1.f / psum;
  float o0 = acc0 * inv + bias[h * 128 + lane];
  float o1 = acc1 * inv + bias[h * 128 + lane + 64];
  o0 = o0 > 0.f ? o0 : expm1f(o0);
  o1 = o1 > 0.f ? o1 : expm1f(o1);
  size_t o = ((size_t)n * H + h) * 128;
  gout[o + lane] = __float2bfloat16(o0);
  gout[o + lane + 64] = __float2bfloat16(o1);
}

// column sums of A[N x 128] accumulated into colsum[128]
__global__ void k_colsum(const float* __restrict__ A, float* __restrict__ colsum, int N) {
  int c = threadIdx.x;  // 128 threads
  int rows_per_block = CDIV(N, (int)gridDim.x);
  int r0 = blockIdx.x * rows_per_block;
  int r1 = min(N, r0 + rows_per_block);
  float acc = 0.f;
  for (int r = r0; r < r1; ++r) acc += A[(size_t)r * 128 + c];
  atomicAdd(&colsum[c], acc);
}

// single block head MLP -> vvec[384]
__global__ void k_head(const float* __restrict__ colsum, const float* __restrict__ Wfc,
                       const float* __restrict__ bfc, const float* __restrict__ Whg,
                       const float* __restrict__ bhg, const float* __restrict__ Wv,
                       const float* __restrict__ bv, float* __restrict__ vvec, float invN) {
  __shared__ float h[128], t1[256], hg[128];
  int t = threadIdx.x;  // 256
  if (t < 128) h[t] = colsum[t] * invN;
  __syncthreads();
  float acc = bfc[t];
  for (int k = 0; k < 128; k++) acc += h[k] * Wfc[k * 256 + t];
  t1[t] = fmaxf(acc, 0.f);
  __syncthreads();
  if (t < 128) {
    float a2 = bhg[t];
    for (int k = 0; k < 256; k++) a2 += t1[k] * Whg[k * 128 + t];
    hg[t] = a2;
  }
  __syncthreads();
  for (int j = t; j < 384; j += 256) {
    float a3 = bv[j];
    for (int k = 0; k < 128; k++) a3 += hg[k] * Wv[k * 384 + j];
    vvec[j] = fmaxf(a3, 0.f);
  }
}

// per-batch-row BAN tail
__global__ void k_fused(const float* __restrict__ vvec, const float* __restrict__ q,
                        const float* __restrict__ hmat, const float* __restrict__ hbias,
                        float* __restrict__ logits) {
  int b = blockIdx.x, c = threadIdx.x;  // 128 threads
  __shared__ float red[128];
  float t[3];
  float part = 0.f;
#pragma unroll
  for (int j = 0; j < 3; j++) {
    int k = c * 3 + j;
    float hs = hmat[k] + hmat[384 + k] + hmat[768 + k] + hmat[1152 + k];
    t[j] = vvec[k] * q[(size_t)b * 384 + k];
    part += hs * t[j];
  }
  red[c] = part;
  __syncthreads();
  for (int s = 64; s > 0; s >>= 1) {
    if (c < s) red[c] += red[c + s];
    __syncthreads();
  }
  float attsum = red[0] + (hbias[0] + hbias[1] + hbias[2] + hbias[3]);
  logits[(size_t)b * 128 + c] = attsum * (t[0] + t[1] + t[2]);
}

// batchnorm over batch dim (biased var), one block per channel c
__global__ void k_bn(const float* __restrict__ logits, const float* __restrict__ gamma,
                     const float* __restrict__ beta, float* __restrict__ out, int B) {
  int c = blockIdx.x, b = threadIdx.x;  // B threads
  __shared__ float s1[256], s2[256];
  float v = logits[(size_t)b * 128 + c];
  s1[b] = v; s2[b] = v * v;
  __syncthreads();
  for (int s = B / 2; s > 0; s >>= 1) {
    if (b < s) { s1[b] += s1[b + s]; s2[b] += s2[b + s]; }
    __syncthreads();
  }
  float mu = s1[0] / B;
  float var = s2[0] / B - mu * mu;
  out[(size_t)b * 128 + c] = (v - mu) * rsqrtf(var + 1e-5f) * gamma[c] + beta[c];
}

extern "C" void kernel_launch(void* const* d_in, const int* in_sizes, int n_in,
                              void* d_out, int out_size, void* d_ws, size_t ws_size,
                              hipStream_t stream) {
  const float* cell = (const float*)d_in[0];
  const float* Wd   = (const float*)d_in[1];
  const float* bd   = (const float*)d_in[2];
  const float* W1   = (const float*)d_in[3];
  const float* a1s  = (const float*)d_in[4];
  const float* a1d  = (const float*)d_in[5];
  const float* b1   = (const float*)d_in[6];
  const float* Wl1  = (const float*)d_in[7];
  const float* bl1  = (const float*)d_in[8];
  const float* W2   = (const float*)d_in[9];
  const float* a2s  = (const float*)d_in[10];
  const float* a2d  = (const float*)d_in[11];
  const float* b2   = (const float*)d_in[12];
  const float* Wl2  = (const float*)d_in[13];
  const float* bl2  = (const float*)d_in[14];
  const float* Wfc  = (const float*)d_in[15];
  const float* bfc  = (const float*)d_in[16];
  const float* Whg  = (const float*)d_in[17];
  const float* bhg  = (const float*)d_in[18];
  const float* Wc   = (const float*)d_in[19];
  const float* bc   = (const float*)d_in[20];
  const float* Wv   = (const float*)d_in[21];
  const float* bv   = (const float*)d_in[22];
  const float* Wq   = (const float*)d_in[23];
  const float* bq   = (const float*)d_in[24];
  const float* hmat = (const float*)d_in[25];
  const float* hbias= (const float*)d_in[26];
  const float* gamma= (const float*)d_in[27];
  const float* beta = (const float*)d_in[28];
  const int* trip   = (const int*)d_in[29];
  const int* eidx   = (const int*)d_in[30];

  const int N = in_sizes[29] / 4;     // 20000
  const int E = in_sizes[30] / 2;     // 500000
  const int B = in_sizes[0] / 954;    // 256
  float* out = (float*)d_out;

  // ---------------- workspace layout ----------------
  float* ws     = (float*)d_ws;
  float* xh     = ws;                          // N*640 f32
  float* h1     = xh + (size_t)N * 640;        // N*128 f32
  float* h2     = h1 + (size_t)N * 128;        // N*128 f32
  float* es     = h2 + (size_t)N * 128;        // N*5 f32
  float* ed     = es + (size_t)N * 5;          // N*5 f32
  float* colsum = ed + (size_t)N * 5;          // 128
  float* cbuf   = colsum + 128;                // B*128
  float* qbuf   = cbuf + (size_t)B * 128;      // B*384
  float* vvec   = qbuf + (size_t)B * 384;      // 384
  float* logits = vvec + 384;                  // B*128
  // bf16 region (2-byte elems), 16B-aligned since all prior sizes are even
  __hip_bfloat16* xb    = (__hip_bfloat16*)(logits + (size_t)B * 128);
  __hip_bfloat16* goutb = xb + (size_t)N * 128;       // N*640 bf16
  __hip_bfloat16* h1b   = goutb + (size_t)N * 640;    // N*128 bf16
  __hip_bfloat16* W1t   = h1b + (size_t)N * 128;      // 512*128
  __hip_bfloat16* Wl1t  = W1t + 512 * 128;            // 128*512
  __hip_bfloat16* W2t   = Wl1t + 128 * 512;           // 640*128
  __hip_bfloat16* Wl2t  = W2t + 640 * 128;            // 128*640
  // int region
  int* rowptr   = (int*)(Wl2t + 128 * 640);    // N+1
  int* degb     = rowptr + (N + 1);            // N
  int* cursor   = degb + N;                    // N
  int* adj      = cursor + N;                  // E

  const int* src0 = eidx;
  const int* dst0 = eidx + E;

  (void)hipMemsetAsync(colsum, 0, 128 * sizeof(float), stream);
  (void)hipMemsetAsync(degb, 0, (size_t)2 * N * sizeof(int), stream);

  // weight conversions (tiny)
  k_wconv<<<CDIV(128 * 512, 256), 256, 0, stream>>>(W1, W1t, 128, 512);
  k_wconv<<<CDIV(512 * 128, 256), 256, 0, stream>>>(Wl1, Wl1t, 512, 128);
  k_wconv<<<CDIV(128 * 640, 256), 256, 0, stream>>>(W2, W2t, 128, 640);
  k_wconv<<<CDIV(640 * 128, 256), 256, 0, stream>>>(Wl2, Wl2t, 640, 128);

  // CSR build (shared by both GAT layers)
  k_deg<<<CDIV(E, 256), 256, 0, stream>>>(src0, dst0, degb, E);
  k_scan<<<1, 1024, 0, stream>>>(degb, rowptr, N);
  k_fill_adj<<<CDIV(E, 256), 256, 0, stream>>>(src0, dst0, rowptr, cursor, adj, E);

  k_drug<<<CDIV(N * 128, 256), 256, 0, stream>>>(trip, Wd, bd, xb, N);

  // ---------------- GAT1 (H=4) ----------------
  {
    dim3 g(512 / 64, CDIV(N, 64));
    k_gemm_mfma<false, false><<<g, 256, 0, stream>>>(xb, W1t, nullptr, xh, nullptr, N, 128, 512);
  }
  k_coef<<<CDIV(N * 4, 4), 256, 0, stream>>>(xh, a1s, a1d, es, ed, N, 4);
  k_gat_gather<<<CDIV(N * 4, 4), 256, 0, stream>>>(rowptr, adj, es, ed, xh, b1, goutb, N, 4);
  {
    dim3 g(128 / 64, CDIV(N, 64));
    k_gemm_mfma<true, true><<<g, 256, 0, stream>>>(goutb, Wl1t, bl1, h1, h1b, N, 512, 128);
  }
  k_colsum<<<256, 128, 0, stream>>>(h1, colsum, N);

  // ---------------- GAT2 (H=5) ----------------
  {
    dim3 g(640 / 64, CDIV(N, 64));
    k_gemm_mfma<false, false><<<g, 256, 0, stream>>>(h1b, W2t, nullptr, xh, nullptr, N, 128, 640);
  }
  k_coef<<<CDIV(N * 5, 4), 256, 0, stream>>>(xh, a2s, a2d, es, ed, N, 5);
  k_gat_gather<<<CDIV(N * 5, 4), 256, 0, stream>>>(rowptr, adj, es, ed, xh, b2, goutb, N, 5);
  {
    dim3 g(128 / 64, CDIV(N, 64));
    k_gemm_mfma<true, false><<<g, 256, 0, stream>>>(goutb, Wl2t, bl2, h2, nullptr, N, 640, 128);
  }
  k_colsum<<<256, 128, 0, stream>>>(h2, colsum, N);

  // ---------------- head + BAN + BN ----------------
  k_head<<<1, 256, 0, stream>>>(colsum, Wfc, bfc, Whg, bhg, Wv, bv, vvec, 1.0f / N);
  {
    dim3 g(CDIV(128, 64), CDIV(B, 64));
    k_gemm<true><<<g, 256, 0, stream>>>(cell, Wc, bc, cbuf, B, 954, 128);
  }
  {
    dim3 g(CDIV(384, 64), CDIV(B, 64));
    k_gemm<true><<<g, 256, 0, stream>>>(cbuf, Wq, bq, qbuf, B, 128, 384);
  }
  k_fused<<<B, 128, 0, stream>>>(vvec, qbuf, hmat, hbias, logits);
  k_bn<<<128, B, 0, stream>>>(logits, gamma, beta, out, B);
}

// Round 6
// 698.757 us; speedup vs baseline: 4.1910x; 1.3450x over previous
//
#include <hip/hip_runtime.h>
#include <hip/hip_bf16.h>
#include <math.h>

#define CDIV(a,b) (((a)+(b)-1)/(b))

typedef __attribute__((ext_vector_type(8))) short short8v;   // 8 bf16
typedef __attribute__((ext_vector_type(4))) float f32x4;

// ---------------- weight transpose + bf16 convert: W[K][M] -> Wt[M][K] ----------------
__global__ void k_wconv(const float* __restrict__ W, __hip_bfloat16* __restrict__ Wt,
                        int K, int M) {
  int i = blockIdx.x * 256 + threadIdx.x;
  if (i >= K * M) return;
  int m = i / K, k = i % K;
  Wt[i] = __float2bfloat16(W[(size_t)k * M + m]);
}

// ---------------- weight transpose fp32: W[K][M] -> Wt[M][K] ----------------
__global__ void k_wtrans(const float* __restrict__ W, float* __restrict__ Wt, int K, int M) {
  int i = blockIdx.x * 256 + threadIdx.x;
  if (i >= K * M) return;
  int m = i / K, k = i % K;
  Wt[i] = W[(size_t)k * M + m];
}

// ---------------- x = triplets(float) @ Wd + bd  (bf16 out) ----------------
__global__ void k_drug(const int* __restrict__ trip, const float* __restrict__ Wd,
                       const float* __restrict__ bd, __hip_bfloat16* __restrict__ x, int N) {
  int i = blockIdx.x * 256 + threadIdx.x;
  if (i >= N * 128) return;
  int n = i >> 7, c = i & 127;
  const int* t = trip + n * 4;
  float acc = bd[c];
  acc += (float)t[0] * Wd[c] + (float)t[1] * Wd[128 + c] +
         (float)t[2] * Wd[256 + c] + (float)t[3] * Wd[384 + c];
  x[i] = __float2bfloat16(acc);
}

// ---------------- bf16 MFMA GEMM: Cb[Nr x M](bf16) = A[Nr x K](bf16) @ Bt[M x K]^T ------
// 64x64 tile, BK=32, 4 waves (2x2), each wave 32x32 via 4x mfma_f32_16x16x32_bf16
template <bool BIAS>
__global__ void k_gemm_mfma(const __hip_bfloat16* __restrict__ A,
                            const __hip_bfloat16* __restrict__ Bt,
                            const float* __restrict__ bias,
                            __hip_bfloat16* __restrict__ Cb,
                            int Nr, int K, int M) {
  __shared__ short As[64 * 40];
  __shared__ short Bs[64 * 40];
  int tid = threadIdx.x;
  int lane = tid & 63, wid = tid >> 6;
  int wr = wid >> 1, wc = wid & 1;
  int lrow = lane & 15, lkc = lane >> 4;
  int row0 = blockIdx.y * 64, col0 = blockIdx.x * 64;

  int arow = tid >> 2, akc = tid & 3;
  int grow = row0 + arow; if (grow >= Nr) grow = Nr - 1;
  const __hip_bfloat16* agp = A + (size_t)grow * K + akc * 8;
  const __hip_bfloat16* bgp = Bt + (size_t)(col0 + arow) * K + akc * 8;
  short* asp = &As[arow * 40 + akc * 8];
  short* bsp = &Bs[arow * 40 + akc * 8];

  f32x4 acc00 = {0.f,0.f,0.f,0.f}, acc01 = acc00, acc10 = acc00, acc11 = acc00;

  const short* a0p = &As[(wr * 32 + lrow) * 40 + lkc * 8];
  const short* a1p = &As[(wr * 32 + 16 + lrow) * 40 + lkc * 8];
  const short* b0p = &Bs[(wc * 32 + lrow) * 40 + lkc * 8];
  const short* b1p = &Bs[(wc * 32 + 16 + lrow) * 40 + lkc * 8];

  for (int k0 = 0; k0 < K; k0 += 32) {
    short8v av = *(const short8v*)(agp + k0);
    short8v bv = *(const short8v*)(bgp + k0);
    __syncthreads();
    *(short8v*)asp = av;
    *(short8v*)bsp = bv;
    __syncthreads();
    short8v a0 = *(const short8v*)a0p;
    short8v a1 = *(const short8v*)a1p;
    short8v b0 = *(const short8v*)b0p;
    short8v b1 = *(const short8v*)b1p;
    acc00 = __builtin_amdgcn_mfma_f32_16x16x32_bf16(a0, b0, acc00, 0, 0, 0);
    acc01 = __builtin_amdgcn_mfma_f32_16x16x32_bf16(a0, b1, acc01, 0, 0, 0);
    acc10 = __builtin_amdgcn_mfma_f32_16x16x32_bf16(a1, b0, acc10, 0, 0, 0);
    acc11 = __builtin_amdgcn_mfma_f32_16x16x32_bf16(a1, b1, acc11, 0, 0, 0);
  }

  // C/D layout (m89): col = lane&15, row = (lane>>4)*4 + r
  int rbase = row0 + wr * 32 + (lane >> 4) * 4;
  int cbase = col0 + wc * 32 + lrow;
#pragma unroll
  for (int m = 0; m < 2; ++m) {
#pragma unroll
    for (int n = 0; n < 2; ++n) {
      f32x4 acc = m == 0 ? (n == 0 ? acc00 : acc01) : (n == 0 ? acc10 : acc11);
      int col = cbase + n * 16;
      float bv = BIAS ? bias[col] : 0.f;
#pragma unroll
      for (int r = 0; r < 4; ++r) {
        int grow2 = rbase + m * 16 + r;
        if (grow2 >= Nr) continue;
        Cb[(size_t)grow2 * M + col] = __float2bfloat16(acc[r] + bv);
      }
    }
  }
}

// ---------------- wave-per-output GEMM: C[Nr x M] = relu(A[Nr x K] @ Bt[M x K]^T + bias) ---
__global__ void k_dotmm(const float* __restrict__ A, const float* __restrict__ Bt,
                        const float* __restrict__ bias, float* __restrict__ C,
                        int Nr, int K, int M) {
  int wid = (blockIdx.x * blockDim.x + threadIdx.x) >> 6;
  int lane = threadIdx.x & 63;
  if (wid >= Nr * M) return;
  int b = wid / M, m = wid % M;
  const float* ar = A + (size_t)b * K;
  const float* br = Bt + (size_t)m * K;
  float acc = 0.f;
  for (int k = lane * 2; k + 1 < K; k += 128) {
    float2 av = *(const float2*)(ar + k);
    float2 bv = *(const float2*)(br + k);
    acc += av.x * bv.x + av.y * bv.y;
  }
#pragma unroll
  for (int off = 32; off; off >>= 1) acc += __shfl_xor(acc, off);
  if (lane == 0) C[wid] = fmaxf(acc + bias[m], 0.f);
}

// ---------------- es/ed per (node, head): dot(xh[n,h,:], a[h,:]) over C=128 (bf16 in) ------
__global__ void k_coef(const __hip_bfloat16* __restrict__ xh, const float* __restrict__ as_,
                       const float* __restrict__ ad_, float* __restrict__ es,
                       float* __restrict__ ed, int N, int H) {
  int wid = (blockIdx.x * blockDim.x + threadIdx.x) >> 6;
  int lane = threadIdx.x & 63;
  if (wid >= N * H) return;
  int n = wid / H, h = wid % H;
  const __hip_bfloat162* xp = (const __hip_bfloat162*)(xh + ((size_t)n * H + h) * 128);
  __hip_bfloat162 xv = xp[lane];                // channels 2*lane, 2*lane+1
  float x0 = __bfloat162float(xv.x), x1 = __bfloat162float(xv.y);
  float2 a = ((const float2*)(as_ + h * 128))[lane];
  float2 d = ((const float2*)(ad_ + h * 128))[lane];
  float e1 = x0 * a.x + x1 * a.y;
  float e2 = x0 * d.x + x1 * d.y;
#pragma unroll
  for (int off = 32; off; off >>= 1) {
    e1 += __shfl_xor(e1, off);
    e2 += __shfl_xor(e2, off);
  }
  if (lane == 0) { es[wid] = e1; ed[wid] = e2; }
}

// ---------------- CSR build (by destination; self loops excluded) ----------------
__global__ void k_deg(const int* __restrict__ src0, const int* __restrict__ dst0,
                      int* __restrict__ deg, int E) {
  int e = blockIdx.x * 256 + threadIdx.x;
  if (e >= E) return;
  int s = src0[e], d = dst0[e];
  if (s != d) atomicAdd(&deg[d], 1);
}

__global__ void k_scan(const int* __restrict__ deg, int* __restrict__ rowptr, int N) {
  __shared__ int part[1024];
  int t = threadIdx.x;
  int chunk = (N + 1023) >> 10;
  int b0 = t * chunk, b1 = min(N, b0 + chunk);
  int s = 0;
  for (int i = b0; i < b1; i++) s += deg[i];
  part[t] = s;
  __syncthreads();
  for (int off = 1; off < 1024; off <<= 1) {
    int v = (t >= off) ? part[t - off] : 0;
    __syncthreads();
    part[t] += v;
    __syncthreads();
  }
  int run = (t == 0) ? 0 : part[t - 1];
  for (int i = b0; i < b1; i++) { rowptr[i] = run; run += deg[i]; }
  if (b1 == N) rowptr[N] = run;
}

__global__ void k_fill_adj(const int* __restrict__ src0, const int* __restrict__ dst0,
                           const int* __restrict__ rowptr, int* __restrict__ cursor,
                           int* __restrict__ adj, int E) {
  int e = blockIdx.x * 256 + threadIdx.x;
  if (e >= E) return;
  int s = src0[e], d = dst0[e];
  if (s != d) {
    int pos = rowptr[d] + atomicAdd(&cursor[d], 1);
    adj[pos] = s;
  }
}

// ---------------- fused GAT aggregation: one wave per (node, head), bf16 in/out ----------
__global__ void k_gat_gather(const int* __restrict__ rowptr, const int* __restrict__ adj,
                             const float* __restrict__ es, const float* __restrict__ ed,
                             const __hip_bfloat16* __restrict__ xh,
                             const float* __restrict__ bias,
                             __hip_bfloat16* __restrict__ gout, int N, int H) {
  int wid = (blockIdx.x * blockDim.x + threadIdx.x) >> 6;
  int lane = threadIdx.x & 63;
  if (wid >= N * H) return;
  int n = wid / H, h = wid % H;
  int base = rowptr[n];
  int deg = rowptr[n + 1] - base;
  float edn = ed[n * H + h];
  float vself = es[n * H + h] + edn;
  vself = vself > 0.f ? vself : 0.2f * vself;
  // phase A: segment max
  float m = vself;
  for (int i = lane; i < deg; i += 64) {
    int s = adj[base + i];
    float v = es[s * H + h] + edn;
    v = v > 0.f ? v : 0.2f * v;
    m = fmaxf(m, v);
  }
#pragma unroll
  for (int off = 32; off; off >>= 1) m = fmaxf(m, __shfl_xor(m, off));
  // phase B: unnormalized accumulate + sum of exp (channels 2*lane, 2*lane+1)
  float pself = __expf(vself - m);
  const __hip_bfloat162* xn = (const __hip_bfloat162*)(xh + ((size_t)n * H + h) * 128);
  __hip_bfloat162 xs0 = xn[lane];
  float acc0 = pself * __bfloat162float(xs0.x);
  float acc1 = pself * __bfloat162float(xs0.y);
  float psum = (lane == 0) ? pself : 0.f;
  for (int c = 0; c < deg; c += 64) {
    int i = c + lane;
    int s = 0;
    float p = 0.f;
    if (i < deg) {
      s = adj[base + i];
      float v = es[s * H + h] + edn;
      v = v > 0.f ? v : 0.2f * v;
      p = __expf(v - m);
      psum += p;
    }
    int cnt = min(64, deg - c);
    for (int j = 0; j < cnt; ++j) {
      float pj = __shfl(p, j);
      int sj = __shfl(s, j);
      const __hip_bfloat162* xs = (const __hip_bfloat162*)(xh + ((size_t)sj * H + h) * 128);
      __hip_bfloat162 v2 = xs[lane];
      acc0 += pj * __bfloat162float(v2.x);
      acc1 += pj * __bfloat162float(v2.y);
    }
  }
#pragma unroll
  for (int off = 32; off; off >>= 1) psum += __shfl_xor(psum, off);
  float inv = 1.f / psum;
  float2 bv = ((const float2*)(bias + h * 128))[lane];
  float o0 = acc0 * inv + bv.x;
  float o1 = acc1 * inv + bv.y;
  o0 = o0 > 0.f ? o0 : expm1f(o0);
  o1 = o1 > 0.f ? o1 : expm1f(o1);
  __hip_bfloat162 r;
  r.x = __float2bfloat16(o0);
  r.y = __float2bfloat16(o1);
  ((__hip_bfloat162*)(gout + ((size_t)n * H + h) * 128))[lane] = r;
}

// column sums of A[N x 128](bf16) accumulated into colsum[128]
__global__ void k_colsum(const __hip_bfloat16* __restrict__ A, float* __restrict__ colsum,
                         int N) {
  int c = threadIdx.x;  // 128 threads
  int rows_per_block = CDIV(N, (int)gridDim.x);
  int r0 = blockIdx.x * rows_per_block;
  int r1 = min(N, r0 + rows_per_block);
  float acc = 0.f;
  for (int r = r0; r < r1; ++r) acc += __bfloat162float(A[(size_t)r * 128 + c]);
  atomicAdd(&colsum[c], acc);
}

// single block head MLP -> vvec[384]
__global__ void k_head(const float* __restrict__ colsum, const float* __restrict__ Wfc,
                       const float* __restrict__ bfc, const float* __restrict__ Whg,
                       const float* __restrict__ bhg, const float* __restrict__ Wv,
                       const float* __restrict__ bv, float* __restrict__ vvec, float invN) {
  __shared__ float h[128], t1[256], hg[128];
  int t = threadIdx.x;  // 256
  if (t < 128) h[t] = colsum[t] * invN;
  __syncthreads();
  float acc = bfc[t];
  for (int k = 0; k < 128; k++) acc += h[k] * Wfc[k * 256 + t];
  t1[t] = fmaxf(acc, 0.f);
  __syncthreads();
  if (t < 128) {
    float a2 = bhg[t];
    for (int k = 0; k < 256; k++) a2 += t1[k] * Whg[k * 128 + t];
    hg[t] = a2;
  }
  __syncthreads();
  for (int j = t; j < 384; j += 256) {
    float a3 = bv[j];
    for (int k = 0; k < 128; k++) a3 += hg[k] * Wv[k * 384 + j];
    vvec[j] = fmaxf(a3, 0.f);
  }
}

// per-batch-row BAN tail
__global__ void k_fused(const float* __restrict__ vvec, const float* __restrict__ q,
                        const float* __restrict__ hmat, const float* __restrict__ hbias,
                        float* __restrict__ logits) {
  int b = blockIdx.x, c = threadIdx.x;  // 128 threads
  __shared__ float red[128];
  float t[3];
  float part = 0.f;
#pragma unroll
  for (int j = 0; j < 3; j++) {
    int k = c * 3 + j;
    float hs = hmat[k] + hmat[384 + k] + hmat[768 + k] + hmat[1152 + k];
    t[j] = vvec[k] * q[(size_t)b * 384 + k];
    part += hs * t[j];
  }
  red[c] = part;
  __syncthreads();
  for (int s = 64; s > 0; s >>= 1) {
    if (c < s) red[c] += red[c + s];
    __syncthreads();
  }
  float attsum = red[0] + (hbias[0] + hbias[1] + hbias[2] + hbias[3]);
  logits[(size_t)b * 128 + c] = attsum * (t[0] + t[1] + t[2]);
}

// batchnorm over batch dim (biased var), one block per channel c
__global__ void k_bn(const float* __restrict__ logits, const float* __restrict__ gamma,
                     const float* __restrict__ beta, float* __restrict__ out, int B) {
  int c = blockIdx.x, b = threadIdx.x;  // B threads
  __shared__ float s1[256], s2[256];
  float v = logits[(size_t)b * 128 + c];
  s1[b] = v; s2[b] = v * v;
  __syncthreads();
  for (int s = B / 2; s > 0; s >>= 1) {
    if (b < s) { s1[b] += s1[b + s]; s2[b] += s2[b + s]; }
    __syncthreads();
  }
  float mu = s1[0] / B;
  float var = s2[0] / B - mu * mu;
  out[(size_t)b * 128 + c] = (v - mu) * rsqrtf(var + 1e-5f) * gamma[c] + beta[c];
}

extern "C" void kernel_launch(void* const* d_in, const int* in_sizes, int n_in,
                              void* d_out, int out_size, void* d_ws, size_t ws_size,
                              hipStream_t stream) {
  const float* cell = (const float*)d_in[0];
  const float* Wd   = (const float*)d_in[1];
  const float* bd   = (const float*)d_in[2];
  const float* W1   = (const float*)d_in[3];
  const float* a1s  = (const float*)d_in[4];
  const float* a1d  = (const float*)d_in[5];
  const float* b1   = (const float*)d_in[6];
  const float* Wl1  = (const float*)d_in[7];
  const float* bl1  = (const float*)d_in[8];
  const float* W2   = (const float*)d_in[9];
  const float* a2s  = (const float*)d_in[10];
  const float* a2d  = (const float*)d_in[11];
  const float* b2   = (const float*)d_in[12];
  const float* Wl2  = (const float*)d_in[13];
  const float* bl2  = (const float*)d_in[14];
  const float* Wfc  = (const float*)d_in[15];
  const float* bfc  = (const float*)d_in[16];
  const float* Whg  = (const float*)d_in[17];
  const float* bhg  = (const float*)d_in[18];
  const float* Wc   = (const float*)d_in[19];
  const float* bc   = (const float*)d_in[20];
  const float* Wv   = (const float*)d_in[21];
  const float* bv   = (const float*)d_in[22];
  const float* Wq   = (const float*)d_in[23];
  const float* bq   = (const float*)d_in[24];
  const float* hmat = (const float*)d_in[25];
  const float* hbias= (const float*)d_in[26];
  const float* gamma= (const float*)d_in[27];
  const float* beta = (const float*)d_in[28];
  const int* trip   = (const int*)d_in[29];
  const int* eidx   = (const int*)d_in[30];

  const int N = in_sizes[29] / 4;     // 20000
  const int E = in_sizes[30] / 2;     // 500000
  const int B = in_sizes[0] / 954;    // 256
  float* out = (float*)d_out;

  // ---------------- workspace layout: bf16 region first (16B aligned) ----------------
  __hip_bfloat16* xb    = (__hip_bfloat16*)d_ws;      // N*128
  __hip_bfloat16* xhb   = xb + (size_t)N * 128;       // N*640
  __hip_bfloat16* goutb = xhb + (size_t)N * 640;      // N*640
  __hip_bfloat16* h1b   = goutb + (size_t)N * 640;    // N*128
  __hip_bfloat16* h2b   = h1b + (size_t)N * 128;      // N*128
  __hip_bfloat16* W1t   = h2b + (size_t)N * 128;      // 512*128
  __hip_bfloat16* Wl1t  = W1t + 512 * 128;            // 128*512
  __hip_bfloat16* W2t   = Wl1t + 128 * 512;           // 640*128
  __hip_bfloat16* Wl2t  = W2t + 640 * 128;            // 128*640
  // f32 region
  float* es     = (float*)(Wl2t + 128 * 640);
  float* ed     = es + (size_t)N * 5;
  float* colsum = ed + (size_t)N * 5;          // 128
  float* cbuf   = colsum + 128;                // B*128
  float* qbuf   = cbuf + (size_t)B * 128;      // B*384
  float* vvec   = qbuf + (size_t)B * 384;      // 384
  float* logits = vvec + 384;                  // B*128
  float* Wct    = logits + (size_t)B * 128;    // 128*954
  float* Wqt    = Wct + 128 * 954;             // 384*128
  // int region
  int* rowptr   = (int*)(Wqt + 384 * 128);     // N+1
  int* degb     = rowptr + (N + 1);            // N
  int* cursor   = degb + N;                    // N
  int* adj      = cursor + N;                  // E

  const int* src0 = eidx;
  const int* dst0 = eidx + E;

  (void)hipMemsetAsync(colsum, 0, 128 * sizeof(float), stream);
  (void)hipMemsetAsync(degb, 0, (size_t)2 * N * sizeof(int), stream);

  // weight conversions (tiny)
  k_wconv<<<CDIV(128 * 512, 256), 256, 0, stream>>>(W1, W1t, 128, 512);
  k_wconv<<<CDIV(512 * 128, 256), 256, 0, stream>>>(Wl1, Wl1t, 512, 128);
  k_wconv<<<CDIV(128 * 640, 256), 256, 0, stream>>>(W2, W2t, 128, 640);
  k_wconv<<<CDIV(640 * 128, 256), 256, 0, stream>>>(Wl2, Wl2t, 640, 128);
  k_wtrans<<<CDIV(954 * 128, 256), 256, 0, stream>>>(Wc, Wct, 954, 128);
  k_wtrans<<<CDIV(128 * 384, 256), 256, 0, stream>>>(Wq, Wqt, 128, 384);

  // CSR build (shared by both GAT layers)
  k_deg<<<CDIV(E, 256), 256, 0, stream>>>(src0, dst0, degb, E);
  k_scan<<<1, 1024, 0, stream>>>(degb, rowptr, N);
  k_fill_adj<<<CDIV(E, 256), 256, 0, stream>>>(src0, dst0, rowptr, cursor, adj, E);

  k_drug<<<CDIV(N * 128, 256), 256, 0, stream>>>(trip, Wd, bd, xb, N);

  // ---------------- GAT1 (H=4) ----------------
  {
    dim3 g(512 / 64, CDIV(N, 64));
    k_gemm_mfma<false><<<g, 256, 0, stream>>>(xb, W1t, nullptr, xhb, N, 128, 512);
  }
  k_coef<<<CDIV(N * 4, 4), 256, 0, stream>>>(xhb, a1s, a1d, es, ed, N, 4);
  k_gat_gather<<<CDIV(N * 4, 4), 256, 0, stream>>>(rowptr, adj, es, ed, xhb, b1, goutb, N, 4);
  {
    dim3 g(128 / 64, CDIV(N, 64));
    k_gemm_mfma<true><<<g, 256, 0, stream>>>(goutb, Wl1t, bl1, h1b, N, 512, 128);
  }
  k_colsum<<<256, 128, 0, stream>>>(h1b, colsum, N);

  // ---------------- GAT2 (H=5) ----------------
  {
    dim3 g(640 / 64, CDIV(N, 64));
    k_gemm_mfma<false><<<g, 256, 0, stream>>>(h1b, W2t, nullptr, xhb, N, 128, 640);
  }
  k_coef<<<CDIV(N * 5, 4), 256, 0, stream>>>(xhb, a2s, a2d, es, ed, N, 5);
  k_gat_gather<<<CDIV(N * 5, 4), 256, 0, stream>>>(rowptr, adj, es, ed, xhb, b2, goutb, N, 5);
  {
    dim3 g(128 / 64, CDIV(N, 64));
    k_gemm_mfma<true><<<g, 256, 0, stream>>>(goutb, Wl2t, bl2, h2b, N, 640, 128);
  }
  k_colsum<<<256, 128, 0, stream>>>(h2b, colsum, N);

  // ---------------- head + BAN + BN ----------------
  k_head<<<1, 256, 0, stream>>>(colsum, Wfc, bfc, Whg, bhg, Wv, bv, vvec, 1.0f / N);
  k_dotmm<<<CDIV(B * 128, 4), 256, 0, stream>>>(cell, Wct, bc, cbuf, B, 954, 128);
  k_dotmm<<<CDIV(B * 384, 4), 256, 0, stream>>>(cbuf, Wqt, bq, qbuf, B, 128, 384);
  k_fused<<<B, 128, 0, stream>>>(vvec, qbuf, hmat, hbias, logits);
  k_bn<<<128, B, 0, stream>>>(logits, gamma, beta, out, B);
}

// Round 7
// 573.288 us; speedup vs baseline: 5.1082x; 1.2189x over previous
//
#include <hip/hip_runtime.h>
#include <hip/hip_bf16.h>
#include <math.h>

#define CDIV(a,b) (((a)+(b)-1)/(b))

typedef __attribute__((ext_vector_type(8))) short short8v;   // 8 bf16
typedef __attribute__((ext_vector_type(4))) float f32x4;

// ---------------- all weight transposes in one launch ----------------
// bf16 targets: W1(128x512), Wl1(512x128), W2(128x640), Wl2(640x128)
// f32 targets: Wc(954x128), Wq(128x384)
__global__ void k_prep(const float* __restrict__ W1, __hip_bfloat16* __restrict__ W1t,
                       const float* __restrict__ Wl1, __hip_bfloat16* __restrict__ Wl1t,
                       const float* __restrict__ W2, __hip_bfloat16* __restrict__ W2t,
                       const float* __restrict__ Wl2, __hip_bfloat16* __restrict__ Wl2t,
                       const float* __restrict__ Wc, float* __restrict__ Wct,
                       const float* __restrict__ Wq, float* __restrict__ Wqt) {
  int i = blockIdx.x * 256 + threadIdx.x;
  const int n1 = 128 * 512, n2 = 512 * 128, n3 = 128 * 640, n4 = 640 * 128;
  const int n5 = 954 * 128, n6 = 128 * 384;
  if (i < n1) { int m = i / 128, k = i % 128; W1t[i] = __float2bfloat16(W1[(size_t)k * 512 + m]); return; }
  i -= n1;
  if (i < n2) { int m = i / 512, k = i % 512; Wl1t[i] = __float2bfloat16(Wl1[(size_t)k * 128 + m]); return; }
  i -= n2;
  if (i < n3) { int m = i / 128, k = i % 128; W2t[i] = __float2bfloat16(W2[(size_t)k * 640 + m]); return; }
  i -= n3;
  if (i < n4) { int m = i / 640, k = i % 640; Wl2t[i] = __float2bfloat16(Wl2[(size_t)k * 128 + m]); return; }
  i -= n4;
  if (i < n5) { int m = i / 954, k = i % 954; Wct[i] = Wc[(size_t)k * 128 + m]; return; }
  i -= n5;
  if (i < n6) { int m = i / 128, k = i % 128; Wqt[i] = Wq[(size_t)k * 384 + m]; return; }
}

// ---------------- x = triplets(float) @ Wd + bd  (bf16 out) ----------------
__global__ void k_drug(const int* __restrict__ trip, const float* __restrict__ Wd,
                       const float* __restrict__ bd, __hip_bfloat16* __restrict__ x, int N) {
  int i = blockIdx.x * 256 + threadIdx.x;
  if (i >= N * 128) return;
  int n = i >> 7, c = i & 127;
  const int* t = trip + n * 4;
  float acc = bd[c];
  acc += (float)t[0] * Wd[c] + (float)t[1] * Wd[128 + c] +
         (float)t[2] * Wd[256 + c] + (float)t[3] * Wd[384 + c];
  x[i] = __float2bfloat16(acc);
}

// ---------------- bf16 MFMA GEMM: Cb[Nr x M](bf16) = A[Nr x K](bf16) @ Bt[M x K]^T ------
template <bool BIAS>
__global__ void k_gemm_mfma(const __hip_bfloat16* __restrict__ A,
                            const __hip_bfloat16* __restrict__ Bt,
                            const float* __restrict__ bias,
                            __hip_bfloat16* __restrict__ Cb,
                            int Nr, int K, int M) {
  __shared__ short As[64 * 40];
  __shared__ short Bs[64 * 40];
  int tid = threadIdx.x;
  int lane = tid & 63, wid = tid >> 6;
  int wr = wid >> 1, wc = wid & 1;
  int lrow = lane & 15, lkc = lane >> 4;
  int row0 = blockIdx.y * 64, col0 = blockIdx.x * 64;

  int arow = tid >> 2, akc = tid & 3;
  int grow = row0 + arow; if (grow >= Nr) grow = Nr - 1;
  const __hip_bfloat16* agp = A + (size_t)grow * K + akc * 8;
  const __hip_bfloat16* bgp = Bt + (size_t)(col0 + arow) * K + akc * 8;
  short* asp = &As[arow * 40 + akc * 8];
  short* bsp = &Bs[arow * 40 + akc * 8];

  f32x4 acc00 = {0.f,0.f,0.f,0.f}, acc01 = acc00, acc10 = acc00, acc11 = acc00;

  const short* a0p = &As[(wr * 32 + lrow) * 40 + lkc * 8];
  const short* a1p = &As[(wr * 32 + 16 + lrow) * 40 + lkc * 8];
  const short* b0p = &Bs[(wc * 32 + lrow) * 40 + lkc * 8];
  const short* b1p = &Bs[(wc * 32 + 16 + lrow) * 40 + lkc * 8];

  for (int k0 = 0; k0 < K; k0 += 32) {
    short8v av = *(const short8v*)(agp + k0);
    short8v bv = *(const short8v*)(bgp + k0);
    __syncthreads();
    *(short8v*)asp = av;
    *(short8v*)bsp = bv;
    __syncthreads();
    short8v a0 = *(const short8v*)a0p;
    short8v a1 = *(const short8v*)a1p;
    short8v b0 = *(const short8v*)b0p;
    short8v b1 = *(const short8v*)b1p;
    acc00 = __builtin_amdgcn_mfma_f32_16x16x32_bf16(a0, b0, acc00, 0, 0, 0);
    acc01 = __builtin_amdgcn_mfma_f32_16x16x32_bf16(a0, b1, acc01, 0, 0, 0);
    acc10 = __builtin_amdgcn_mfma_f32_16x16x32_bf16(a1, b0, acc10, 0, 0, 0);
    acc11 = __builtin_amdgcn_mfma_f32_16x16x32_bf16(a1, b1, acc11, 0, 0, 0);
  }

  // C/D layout (m89): col = lane&15, row = (lane>>4)*4 + r
  int rbase = row0 + wr * 32 + (lane >> 4) * 4;
  int cbase = col0 + wc * 32 + lrow;
#pragma unroll
  for (int m = 0; m < 2; ++m) {
#pragma unroll
    for (int n = 0; n < 2; ++n) {
      f32x4 acc = m == 0 ? (n == 0 ? acc00 : acc01) : (n == 0 ? acc10 : acc11);
      int col = cbase + n * 16;
      float bv = BIAS ? bias[col] : 0.f;
#pragma unroll
      for (int r = 0; r < 4; ++r) {
        int grow2 = rbase + m * 16 + r;
        if (grow2 >= Nr) continue;
        Cb[(size_t)grow2 * M + col] = __float2bfloat16(acc[r] + bv);
      }
    }
  }
}

// ---------------- wave-per-output GEMM: C = relu(A @ Bt^T + bias) ----------------
__global__ void k_dotmm(const float* __restrict__ A, const float* __restrict__ Bt,
                        const float* __restrict__ bias, float* __restrict__ C,
                        int Nr, int K, int M) {
  int wid = (blockIdx.x * blockDim.x + threadIdx.x) >> 6;
  int lane = threadIdx.x & 63;
  if (wid >= Nr * M) return;
  int b = wid / M, m = wid % M;
  const float* ar = A + (size_t)b * K;
  const float* br = Bt + (size_t)m * K;
  float acc = 0.f;
  for (int k = lane * 2; k + 1 < K; k += 128) {
    float2 av = *(const float2*)(ar + k);
    float2 bv = *(const float2*)(br + k);
    acc += av.x * bv.x + av.y * bv.y;
  }
#pragma unroll
  for (int off = 32; off; off >>= 1) acc += __shfl_xor(acc, off);
  if (lane == 0) C[wid] = fmaxf(acc + bias[m], 0.f);
}

// ---------------- es/ed per (node, head) (bf16 in) ----------------
__global__ void k_coef(const __hip_bfloat16* __restrict__ xh, const float* __restrict__ as_,
                       const float* __restrict__ ad_, float* __restrict__ es,
                       float* __restrict__ ed, int N, int H) {
  int wid = (blockIdx.x * blockDim.x + threadIdx.x) >> 6;
  int lane = threadIdx.x & 63;
  if (wid >= N * H) return;
  int n = wid / H, h = wid % H;
  const __hip_bfloat162* xp = (const __hip_bfloat162*)(xh + ((size_t)n * H + h) * 128);
  __hip_bfloat162 xv = xp[lane];
  float x0 = __bfloat162float(xv.x), x1 = __bfloat162float(xv.y);
  float2 a = ((const float2*)(as_ + h * 128))[lane];
  float2 d = ((const float2*)(ad_ + h * 128))[lane];
  float e1 = x0 * a.x + x1 * a.y;
  float e2 = x0 * d.x + x1 * d.y;
#pragma unroll
  for (int off = 32; off; off >>= 1) {
    e1 += __shfl_xor(e1, off);
    e2 += __shfl_xor(e2, off);
  }
  if (lane == 0) { es[wid] = e1; ed[wid] = e2; }
}

// ---------------- CSR build ----------------
__global__ void k_deg(const int* __restrict__ src0, const int* __restrict__ dst0,
                      int* __restrict__ deg, int E) {
  int e = blockIdx.x * 256 + threadIdx.x;
  if (e >= E) return;
  int s = src0[e], d = dst0[e];
  if (s != d) atomicAdd(&deg[d], 1);
}

__global__ void k_scan(const int* __restrict__ deg, int* __restrict__ rowptr, int N) {
  __shared__ int part[1024];
  int t = threadIdx.x;
  int chunk = (N + 1023) >> 10;
  int b0 = t * chunk, b1 = min(N, b0 + chunk);
  int s = 0;
  for (int i = b0; i < b1; i++) s += deg[i];
  part[t] = s;
  __syncthreads();
  for (int off = 1; off < 1024; off <<= 1) {
    int v = (t >= off) ? part[t - off] : 0;
    __syncthreads();
    part[t] += v;
    __syncthreads();
  }
  int run = (t == 0) ? 0 : part[t - 1];
  for (int i = b0; i < b1; i++) { rowptr[i] = run; run += deg[i]; }
  if (b1 == N) rowptr[N] = run;
}

__global__ void k_fill_adj(const int* __restrict__ src0, const int* __restrict__ dst0,
                           const int* __restrict__ rowptr, int* __restrict__ cursor,
                           int* __restrict__ adj, int E) {
  int e = blockIdx.x * 256 + threadIdx.x;
  if (e >= E) return;
  int s = src0[e], d = dst0[e];
  if (s != d) {
    int pos = rowptr[d] + atomicAdd(&cursor[d], 1);
    adj[pos] = s;
  }
}

// ---------------- fused GAT aggregation: one wave per (node, head) ----------------
// scalarized inner loop: readlane -> SGPR row index & alpha, saddr loads, 4-deep MLP
__global__ void k_gat_gather(const int* __restrict__ rowptr, const int* __restrict__ adj,
                             const float* __restrict__ es, const float* __restrict__ ed,
                             const __hip_bfloat16* __restrict__ xh,
                             const float* __restrict__ bias,
                             __hip_bfloat16* __restrict__ gout, int N, int H) {
  int wid = (blockIdx.x * blockDim.x + threadIdx.x) >> 6;
  int lane = threadIdx.x & 63;
  if (wid >= N * H) return;
  int n = wid / H, h = wid % H;
  int base = rowptr[n];
  int deg = rowptr[n + 1] - base;
  float edn = ed[n * H + h];
  float vself = es[n * H + h] + edn;
  vself = vself > 0.f ? vself : 0.2f * vself;
  // phase A: segment max
  float m = vself;
  for (int i = lane; i < deg; i += 64) {
    int s = adj[base + i];
    float v = es[s * H + h] + edn;
    v = v > 0.f ? v : 0.2f * v;
    m = fmaxf(m, v);
  }
#pragma unroll
  for (int off = 32; off; off >>= 1) m = fmaxf(m, __shfl_xor(m, off));
  // phase B: unnormalized accumulate (channels 2*lane, 2*lane+1)
  const __hip_bfloat162* xh2 = (const __hip_bfloat162*)xh;
  const size_t rstride = (size_t)H * 64;             // bf162 units per node
  const int hoff = h * 64;
  float pself = __expf(vself - m);
  __hip_bfloat162 xs0 = xh2[(size_t)n * rstride + hoff + lane];
  float a0 = pself * __bfloat162float(xs0.x);
  float a1 = pself * __bfloat162float(xs0.y);
  float b0 = 0.f, b1 = 0.f, c0 = 0.f, c1 = 0.f, d0 = 0.f, d1 = 0.f;
  float psum = (lane == 0) ? pself : 0.f;
  for (int c = 0; c < deg; c += 64) {
    int i = c + lane;
    int s = 0;
    float p = 0.f;
    if (i < deg) {
      s = adj[base + i];
      float v = es[s * H + h] + edn;
      v = v > 0.f ? v : 0.2f * v;
      p = __expf(v - m);
      psum += p;
    }
    int cnt = min(64, deg - c);
    int j = 0;
    for (; j + 4 <= cnt; j += 4) {
      int s0 = __builtin_amdgcn_readlane(s, j);
      int s1 = __builtin_amdgcn_readlane(s, j + 1);
      int s2 = __builtin_amdgcn_readlane(s, j + 2);
      int s3 = __builtin_amdgcn_readlane(s, j + 3);
      float p0 = __int_as_float(__builtin_amdgcn_readlane(__float_as_int(p), j));
      float p1 = __int_as_float(__builtin_amdgcn_readlane(__float_as_int(p), j + 1));
      float p2 = __int_as_float(__builtin_amdgcn_readlane(__float_as_int(p), j + 2));
      float p3 = __int_as_float(__builtin_amdgcn_readlane(__float_as_int(p), j + 3));
      __hip_bfloat162 v0 = xh2[(size_t)s0 * rstride + hoff + lane];
      __hip_bfloat162 v1 = xh2[(size_t)s1 * rstride + hoff + lane];
      __hip_bfloat162 v2 = xh2[(size_t)s2 * rstride + hoff + lane];
      __hip_bfloat162 v3 = xh2[(size_t)s3 * rstride + hoff + lane];
      a0 += p0 * __bfloat162float(v0.x); a1 += p0 * __bfloat162float(v0.y);
      b0 += p1 * __bfloat162float(v1.x); b1 += p1 * __bfloat162float(v1.y);
      c0 += p2 * __bfloat162float(v2.x); c1 += p2 * __bfloat162float(v2.y);
      d0 += p3 * __bfloat162float(v3.x); d1 += p3 * __bfloat162float(v3.y);
    }
    for (; j < cnt; ++j) {
      int s0 = __builtin_amdgcn_readlane(s, j);
      float p0 = __int_as_float(__builtin_amdgcn_readlane(__float_as_int(p), j));
      __hip_bfloat162 v0 = xh2[(size_t)s0 * rstride + hoff + lane];
      a0 += p0 * __bfloat162float(v0.x); a1 += p0 * __bfloat162float(v0.y);
    }
  }
  a0 += b0 + c0 + d0;
  a1 += b1 + c1 + d1;
#pragma unroll
  for (int off = 32; off; off >>= 1) psum += __shfl_xor(psum, off);
  float inv = 1.f / psum;
  float2 bv = ((const float2*)(bias + h * 128))[lane];
  float o0 = a0 * inv + bv.x;
  float o1 = a1 * inv + bv.y;
  o0 = o0 > 0.f ? o0 : expm1f(o0);
  o1 = o1 > 0.f ? o1 : expm1f(o1);
  __hip_bfloat162 r;
  r.x = __float2bfloat16(o0);
  r.y = __float2bfloat16(o1);
  ((__hip_bfloat162*)gout)[(size_t)n * rstride + hoff + lane] = r;
}

// column sums of A[N x 128](bf16) accumulated into colsum[128]
__global__ void k_colsum(const __hip_bfloat16* __restrict__ A, float* __restrict__ colsum,
                         int N) {
  int c = threadIdx.x;  // 128 threads
  int rows_per_block = CDIV(N, (int)gridDim.x);
  int r0 = blockIdx.x * rows_per_block;
  int r1 = min(N, r0 + rows_per_block);
  float acc = 0.f;
  for (int r = r0; r < r1; ++r) acc += __bfloat162float(A[(size_t)r * 128 + c]);
  atomicAdd(&colsum[c], acc);
}

// single block head MLP -> vvec[384]
__global__ void k_head(const float* __restrict__ colsum, const float* __restrict__ Wfc,
                       const float* __restrict__ bfc, const float* __restrict__ Whg,
                       const float* __restrict__ bhg, const float* __restrict__ Wv,
                       const float* __restrict__ bv, float* __restrict__ vvec, float invN) {
  __shared__ float h[128], t1[256], hg[128];
  int t = threadIdx.x;  // 256
  if (t < 128) h[t] = colsum[t] * invN;
  __syncthreads();
  float acc = bfc[t];
  for (int k = 0; k < 128; k++) acc += h[k] * Wfc[k * 256 + t];
  t1[t] = fmaxf(acc, 0.f);
  __syncthreads();
  if (t < 128) {
    float a2 = bhg[t];
    for (int k = 0; k < 256; k++) a2 += t1[k] * Whg[k * 128 + t];
    hg[t] = a2;
  }
  __syncthreads();
  for (int j = t; j < 384; j += 256) {
    float a3 = bv[j];
    for (int k = 0; k < 128; k++) a3 += hg[k] * Wv[k * 384 + j];
    vvec[j] = fmaxf(a3, 0.f);
  }
}

// per-batch-row BAN tail
__global__ void k_fused(const float* __restrict__ vvec, const float* __restrict__ q,
                        const float* __restrict__ hmat, const float* __restrict__ hbias,
                        float* __restrict__ logits) {
  int b = blockIdx.x, c = threadIdx.x;  // 128 threads
  __shared__ float red[128];
  float t[3];
  float part = 0.f;
#pragma unroll
  for (int j = 0; j < 3; j++) {
    int k = c * 3 + j;
    float hs = hmat[k] + hmat[384 + k] + hmat[768 + k] + hmat[1152 + k];
    t[j] = vvec[k] * q[(size_t)b * 384 + k];
    part += hs * t[j];
  }
  red[c] = part;
  __syncthreads();
  for (int s = 64; s > 0; s >>= 1) {
    if (c < s) red[c] += red[c + s];
    __syncthreads();
  }
  float attsum = red[0] + (hbias[0] + hbias[1] + hbias[2] + hbias[3]);
  logits[(size_t)b * 128 + c] = attsum * (t[0] + t[1] + t[2]);
}

// batchnorm over batch dim (biased var), one block per channel c
__global__ void k_bn(const float* __restrict__ logits, const float* __restrict__ gamma,
                     const float* __restrict__ beta, float* __restrict__ out, int B) {
  int c = blockIdx.x, b = threadIdx.x;  // B threads
  __shared__ float s1[256], s2[256];
  float v = logits[(size_t)b * 128 + c];
  s1[b] = v; s2[b] = v * v;
  __syncthreads();
  for (int s = B / 2; s > 0; s >>= 1) {
    if (b < s) { s1[b] += s1[b + s]; s2[b] += s2[b + s]; }
    __syncthreads();
  }
  float mu = s1[0] / B;
  float var = s2[0] / B - mu * mu;
  out[(size_t)b * 128 + c] = (v - mu) * rsqrtf(var + 1e-5f) * gamma[c] + beta[c];
}

extern "C" void kernel_launch(void* const* d_in, const int* in_sizes, int n_in,
                              void* d_out, int out_size, void* d_ws, size_t ws_size,
                              hipStream_t stream) {
  const float* cell = (const float*)d_in[0];
  const float* Wd   = (const float*)d_in[1];
  const float* bd   = (const float*)d_in[2];
  const float* W1   = (const float*)d_in[3];
  const float* a1s  = (const float*)d_in[4];
  const float* a1d  = (const float*)d_in[5];
  const float* b1   = (const float*)d_in[6];
  const float* Wl1  = (const float*)d_in[7];
  const float* bl1  = (const float*)d_in[8];
  const float* W2   = (const float*)d_in[9];
  const float* a2s  = (const float*)d_in[10];
  const float* a2d  = (const float*)d_in[11];
  const float* b2   = (const float*)d_in[12];
  const float* Wl2  = (const float*)d_in[13];
  const float* bl2  = (const float*)d_in[14];
  const float* Wfc  = (const float*)d_in[15];
  const float* bfc  = (const float*)d_in[16];
  const float* Whg  = (const float*)d_in[17];
  const float* bhg  = (const float*)d_in[18];
  const float* Wc   = (const float*)d_in[19];
  const float* bc   = (const float*)d_in[20];
  const float* Wv   = (const float*)d_in[21];
  const float* bv   = (const float*)d_in[22];
  const float* Wq   = (const float*)d_in[23];
  const float* bq   = (const float*)d_in[24];
  const float* hmat = (const float*)d_in[25];
  const float* hbias= (const float*)d_in[26];
  const float* gamma= (const float*)d_in[27];
  const float* beta = (const float*)d_in[28];
  const int* trip   = (const int*)d_in[29];
  const int* eidx   = (const int*)d_in[30];

  const int N = in_sizes[29] / 4;     // 20000
  const int E = in_sizes[30] / 2;     // 500000
  const int B = in_sizes[0] / 954;    // 256
  float* out = (float*)d_out;

  // ---------------- workspace layout: bf16 region first (16B aligned) ----------------
  __hip_bfloat16* xb    = (__hip_bfloat16*)d_ws;      // N*128
  __hip_bfloat16* xhb   = xb + (size_t)N * 128;       // N*640
  __hip_bfloat16* goutb = xhb + (size_t)N * 640;      // N*640
  __hip_bfloat16* h1b   = goutb + (size_t)N * 640;    // N*128
  __hip_bfloat16* h2b   = h1b + (size_t)N * 128;      // N*128
  __hip_bfloat16* W1t   = h2b + (size_t)N * 128;      // 512*128
  __hip_bfloat16* Wl1t  = W1t + 512 * 128;            // 128*512
  __hip_bfloat16* W2t   = Wl1t + 128 * 512;           // 640*128
  __hip_bfloat16* Wl2t  = W2t + 640 * 128;            // 128*640
  // f32 region
  float* es     = (float*)(Wl2t + 128 * 640);
  float* ed     = es + (size_t)N * 5;
  float* colsum = ed + (size_t)N * 5;          // 128
  float* cbuf   = colsum + 128;                // B*128
  float* qbuf   = cbuf + (size_t)B * 128;      // B*384
  float* vvec   = qbuf + (size_t)B * 384;      // 384
  float* logits = vvec + 384;                  // B*128
  float* Wct    = logits + (size_t)B * 128;    // 128*954
  float* Wqt    = Wct + 128 * 954;             // 384*128
  // int region
  int* rowptr   = (int*)(Wqt + 384 * 128);     // N+1
  int* degb     = rowptr + (N + 1);            // N
  int* cursor   = degb + N;                    // N
  int* adj      = cursor + N;                  // E

  const int* src0 = eidx;
  const int* dst0 = eidx + E;

  (void)hipMemsetAsync(colsum, 0, 128 * sizeof(float), stream);
  (void)hipMemsetAsync(degb, 0, (size_t)2 * N * sizeof(int), stream);

  // all weight transposes in one launch
  {
    int tot = 128*512 + 512*128 + 128*640 + 640*128 + 954*128 + 128*384;
    k_prep<<<CDIV(tot, 256), 256, 0, stream>>>(W1, W1t, Wl1, Wl1t, W2, W2t, Wl2, Wl2t,
                                               Wc, Wct, Wq, Wqt);
  }

  // CSR build (shared by both GAT layers)
  k_deg<<<CDIV(E, 256), 256, 0, stream>>>(src0, dst0, degb, E);
  k_scan<<<1, 1024, 0, stream>>>(degb, rowptr, N);
  k_fill_adj<<<CDIV(E, 256), 256, 0, stream>>>(src0, dst0, rowptr, cursor, adj, E);

  k_drug<<<CDIV(N * 128, 256), 256, 0, stream>>>(trip, Wd, bd, xb, N);

  // ---------------- GAT1 (H=4) ----------------
  {
    dim3 g(512 / 64, CDIV(N, 64));
    k_gemm_mfma<false><<<g, 256, 0, stream>>>(xb, W1t, nullptr, xhb, N, 128, 512);
  }
  k_coef<<<CDIV(N * 4, 4), 256, 0, stream>>>(xhb, a1s, a1d, es, ed, N, 4);
  k_gat_gather<<<CDIV(N * 4, 4), 256, 0, stream>>>(rowptr, adj, es, ed, xhb, b1, goutb, N, 4);
  {
    dim3 g(128 / 64, CDIV(N, 64));
    k_gemm_mfma<true><<<g, 256, 0, stream>>>(goutb, Wl1t, bl1, h1b, N, 512, 128);
  }
  k_colsum<<<256, 128, 0, stream>>>(h1b, colsum, N);

  // ---------------- GAT2 (H=5) ----------------
  {
    dim3 g(640 / 64, CDIV(N, 64));
    k_gemm_mfma<false><<<g, 256, 0, stream>>>(h1b, W2t, nullptr, xhb, N, 128, 640);
  }
  k_coef<<<CDIV(N * 5, 4), 256, 0, stream>>>(xhb, a2s, a2d, es, ed, N, 5);
  k_gat_gather<<<CDIV(N * 5, 4), 256, 0, stream>>>(rowptr, adj, es, ed, xhb, b2, goutb, N, 5);
  {
    dim3 g(128 / 64, CDIV(N, 64));
    k_gemm_mfma<true><<<g, 256, 0, stream>>>(goutb, Wl2t, bl2, h2b, N, 640, 128);
  }
  k_colsum<<<256, 128, 0, stream>>>(h2b, colsum, N);

  // ---------------- head + BAN + BN ----------------
  k_head<<<1, 256, 0, stream>>>(colsum, Wfc, bfc, Whg, bhg, Wv, bv, vvec, 1.0f / N);
  k_dotmm<<<CDIV(B * 128, 4), 256, 0, stream>>>(cell, Wct, bc, cbuf, B, 954, 128);
  k_dotmm<<<CDIV(B * 384, 4), 256, 0, stream>>>(cbuf, Wqt, bq, qbuf, B, 128, 384);
  k_fused<<<B, 128, 0, stream>>>(vvec, qbuf, hmat, hbias, logits);
  k_bn<<<128, B, 0, stream>>>(logits, gamma, beta, out, B);
}

// Round 8
// 564.495 us; speedup vs baseline: 5.1878x; 1.0156x over previous
//
#include <hip/hip_runtime.h>
#include <hip/hip_bf16.h>
#include <math.h>

#define CDIV(a,b) (((a)+(b)-1)/(b))

typedef __attribute__((ext_vector_type(8))) short short8v;   // 8 bf16
typedef __attribute__((ext_vector_type(4))) float f32x4;

__device__ inline float bf2lo(unsigned u) { return __uint_as_float(u << 16); }
__device__ inline float bf2hi(unsigned u) { return __uint_as_float(u & 0xffff0000u); }

// ---------------- all weight transposes in one launch ----------------
__global__ void k_prep(const float* __restrict__ W1, __hip_bfloat16* __restrict__ W1t,
                       const float* __restrict__ Wl1, __hip_bfloat16* __restrict__ Wl1t,
                       const float* __restrict__ W2, __hip_bfloat16* __restrict__ W2t,
                       const float* __restrict__ Wl2, __hip_bfloat16* __restrict__ Wl2t,
                       const float* __restrict__ Wc, float* __restrict__ Wct,
                       const float* __restrict__ Wq, float* __restrict__ Wqt) {
  int i = blockIdx.x * 256 + threadIdx.x;
  const int n1 = 128 * 512, n2 = 512 * 128, n3 = 128 * 640, n4 = 640 * 128;
  const int n5 = 954 * 128, n6 = 128 * 384;
  if (i < n1) { int m = i / 128, k = i % 128; W1t[i] = __float2bfloat16(W1[(size_t)k * 512 + m]); return; }
  i -= n1;
  if (i < n2) { int m = i / 512, k = i % 512; Wl1t[i] = __float2bfloat16(Wl1[(size_t)k * 128 + m]); return; }
  i -= n2;
  if (i < n3) { int m = i / 128, k = i % 128; W2t[i] = __float2bfloat16(W2[(size_t)k * 640 + m]); return; }
  i -= n3;
  if (i < n4) { int m = i / 640, k = i % 640; Wl2t[i] = __float2bfloat16(Wl2[(size_t)k * 128 + m]); return; }
  i -= n4;
  if (i < n5) { int m = i / 954, k = i % 954; Wct[i] = Wc[(size_t)k * 128 + m]; return; }
  i -= n5;
  if (i < n6) { int m = i / 128, k = i % 128; Wqt[i] = Wq[(size_t)k * 384 + m]; return; }
}

// ---------------- x = triplets(float) @ Wd + bd  (bf16 out) ----------------
__global__ void k_drug(const int* __restrict__ trip, const float* __restrict__ Wd,
                       const float* __restrict__ bd, __hip_bfloat16* __restrict__ x, int N) {
  int i = blockIdx.x * 256 + threadIdx.x;
  if (i >= N * 128) return;
  int n = i >> 7, c = i & 127;
  const int* t = trip + n * 4;
  float acc = bd[c];
  acc += (float)t[0] * Wd[c] + (float)t[1] * Wd[128 + c] +
         (float)t[2] * Wd[256 + c] + (float)t[3] * Wd[384 + c];
  x[i] = __float2bfloat16(acc);
}

// ---------------- bf16 MFMA GEMM: head-major planed output -----------------------
// Cb[plane][Nr][128] where plane = col/128 (for M=128 this is plain row-major)
template <bool BIAS>
__global__ void k_gemm_mfma(const __hip_bfloat16* __restrict__ A,
                            const __hip_bfloat16* __restrict__ Bt,
                            const float* __restrict__ bias,
                            __hip_bfloat16* __restrict__ Cb,
                            int Nr, int K, int M) {
  __shared__ short As[64 * 40];
  __shared__ short Bs[64 * 40];
  int tid = threadIdx.x;
  int lane = tid & 63, wid = tid >> 6;
  int wr = wid >> 1, wc = wid & 1;
  int lrow = lane & 15, lkc = lane >> 4;
  int row0 = blockIdx.y * 64, col0 = blockIdx.x * 64;

  int arow = tid >> 2, akc = tid & 3;
  int grow = row0 + arow; if (grow >= Nr) grow = Nr - 1;
  const __hip_bfloat16* agp = A + (size_t)grow * K + akc * 8;
  const __hip_bfloat16* bgp = Bt + (size_t)(col0 + arow) * K + akc * 8;
  short* asp = &As[arow * 40 + akc * 8];
  short* bsp = &Bs[arow * 40 + akc * 8];

  f32x4 acc00 = {0.f,0.f,0.f,0.f}, acc01 = acc00, acc10 = acc00, acc11 = acc00;

  const short* a0p = &As[(wr * 32 + lrow) * 40 + lkc * 8];
  const short* a1p = &As[(wr * 32 + 16 + lrow) * 40 + lkc * 8];
  const short* b0p = &Bs[(wc * 32 + lrow) * 40 + lkc * 8];
  const short* b1p = &Bs[(wc * 32 + 16 + lrow) * 40 + lkc * 8];

  for (int k0 = 0; k0 < K; k0 += 32) {
    short8v av = *(const short8v*)(agp + k0);
    short8v bv = *(const short8v*)(bgp + k0);
    __syncthreads();
    *(short8v*)asp = av;
    *(short8v*)bsp = bv;
    __syncthreads();
    short8v a0 = *(const short8v*)a0p;
    short8v a1 = *(const short8v*)a1p;
    short8v b0 = *(const short8v*)b0p;
    short8v b1 = *(const short8v*)b1p;
    acc00 = __builtin_amdgcn_mfma_f32_16x16x32_bf16(a0, b0, acc00, 0, 0, 0);
    acc01 = __builtin_amdgcn_mfma_f32_16x16x32_bf16(a0, b1, acc01, 0, 0, 0);
    acc10 = __builtin_amdgcn_mfma_f32_16x16x32_bf16(a1, b0, acc10, 0, 0, 0);
    acc11 = __builtin_amdgcn_mfma_f32_16x16x32_bf16(a1, b1, acc11, 0, 0, 0);
  }

  // C/D layout (m89): col = lane&15, row = (lane>>4)*4 + r
  int rbase = row0 + wr * 32 + (lane >> 4) * 4;
  int cbase = col0 + wc * 32 + lrow;
#pragma unroll
  for (int m = 0; m < 2; ++m) {
#pragma unroll
    for (int n = 0; n < 2; ++n) {
      f32x4 acc = m == 0 ? (n == 0 ? acc00 : acc01) : (n == 0 ? acc10 : acc11);
      int col = cbase + n * 16;
      int plane = col >> 7, ch = col & 127;
      float bv = BIAS ? bias[col] : 0.f;
      __hip_bfloat16* cp = Cb + (size_t)plane * Nr * 128 + ch;
#pragma unroll
      for (int r = 0; r < 4; ++r) {
        int grow2 = rbase + m * 16 + r;
        if (grow2 >= Nr) continue;
        cp[(size_t)grow2 * 128] = __float2bfloat16(acc[r] + bv);
      }
    }
  }
}

// ---------------- wave-per-output GEMM: C = relu(A @ Bt^T + bias) ----------------
__global__ void k_dotmm(const float* __restrict__ A, const float* __restrict__ Bt,
                        const float* __restrict__ bias, float* __restrict__ C,
                        int Nr, int K, int M) {
  int wid = (blockIdx.x * blockDim.x + threadIdx.x) >> 6;
  int lane = threadIdx.x & 63;
  if (wid >= Nr * M) return;
  int b = wid / M, m = wid % M;
  const float* ar = A + (size_t)b * K;
  const float* br = Bt + (size_t)m * K;
  float acc = 0.f;
  for (int k = lane * 2; k + 1 < K; k += 128) {
    float2 av = *(const float2*)(ar + k);
    float2 bv = *(const float2*)(br + k);
    acc += av.x * bv.x + av.y * bv.y;
  }
#pragma unroll
  for (int off = 32; off; off >>= 1) acc += __shfl_xor(acc, off);
  if (lane == 0) C[wid] = fmaxf(acc + bias[m], 0.f);
}

// ---------------- es/ed per (node, head), head-major xh [H][N][128] ----------------
__global__ void k_coef(const __hip_bfloat16* __restrict__ xh, const float* __restrict__ as_,
                       const float* __restrict__ ad_, float* __restrict__ es,
                       float* __restrict__ ed, int N, int H) {
  int wid = (blockIdx.x * blockDim.x + threadIdx.x) >> 6;
  int lane = threadIdx.x & 63;
  if (wid >= N * H) return;
  int h = wid / N, n = wid - h * N;
  const __hip_bfloat162* xp = (const __hip_bfloat162*)xh + (size_t)h * N * 64 + (size_t)n * 64;
  __hip_bfloat162 xv = xp[lane];
  float x0 = __bfloat162float(xv.x), x1 = __bfloat162float(xv.y);
  float2 a = ((const float2*)(as_ + h * 128))[lane];
  float2 d = ((const float2*)(ad_ + h * 128))[lane];
  float e1 = x0 * a.x + x1 * a.y;
  float e2 = x0 * d.x + x1 * d.y;
#pragma unroll
  for (int off = 32; off; off >>= 1) {
    e1 += __shfl_xor(e1, off);
    e2 += __shfl_xor(e2, off);
  }
  if (lane == 0) { es[(size_t)h * N + n] = e1; ed[(size_t)h * N + n] = e2; }
}

// ---------------- CSR build ----------------
__global__ void k_deg(const int* __restrict__ src0, const int* __restrict__ dst0,
                      int* __restrict__ deg, int E) {
  int e = blockIdx.x * 256 + threadIdx.x;
  if (e >= E) return;
  int s = src0[e], d = dst0[e];
  if (s != d) atomicAdd(&deg[d], 1);
}

__global__ void k_scan(const int* __restrict__ deg, int* __restrict__ rowptr, int N) {
  __shared__ int part[1024];
  int t = threadIdx.x;
  int chunk = (N + 1023) >> 10;
  int b0 = t * chunk, b1 = min(N, b0 + chunk);
  int s = 0;
  for (int i = b0; i < b1; i++) s += deg[i];
  part[t] = s;
  __syncthreads();
  for (int off = 1; off < 1024; off <<= 1) {
    int v = (t >= off) ? part[t - off] : 0;
    __syncthreads();
    part[t] += v;
    __syncthreads();
  }
  int run = (t == 0) ? 0 : part[t - 1];
  for (int i = b0; i < b1; i++) { rowptr[i] = run; run += deg[i]; }
  if (b1 == N) rowptr[N] = run;
}

__global__ void k_fill_adj(const int* __restrict__ src0, const int* __restrict__ dst0,
                           const int* __restrict__ rowptr, int* __restrict__ cursor,
                           int* __restrict__ adj, int E) {
  int e = blockIdx.x * 256 + threadIdx.x;
  if (e >= E) return;
  int s = src0[e], d = dst0[e];
  if (s != d) {
    int pos = rowptr[d] + atomicAdd(&cursor[d], 1);
    adj[pos] = s;
  }
}

// ---------------- fused GAT aggregation: one wave per (node, head), head-major xh ----------
__global__ void k_gat_gather(const int* __restrict__ rowptr, const int* __restrict__ adj,
                             const float* __restrict__ es, const float* __restrict__ ed,
                             const __hip_bfloat16* __restrict__ xh,
                             const float* __restrict__ bias,
                             __hip_bfloat16* __restrict__ gout, int N, int H) {
  int wid = (blockIdx.x * blockDim.x + threadIdx.x) >> 6;
  int lane = threadIdx.x & 63;
  if (wid >= N * H) return;
  int h = wid / N, n = wid - h * N;
  int base = rowptr[n];
  int deg = rowptr[n + 1] - base;
  const float* esh = es + (size_t)h * N;
  float edn = ed[(size_t)h * N + n];
  float vself = esh[n] + edn;
  vself = vself > 0.f ? vself : 0.2f * vself;
  // phase A: segment max
  float m = vself;
  for (int i = lane; i < deg; i += 64) {
    int s = adj[base + i];
    float v = esh[s] + edn;
    v = v > 0.f ? v : 0.2f * v;
    m = fmaxf(m, v);
  }
#pragma unroll
  for (int off = 32; off; off >>= 1) m = fmaxf(m, __shfl_xor(m, off));
  // phase B: unnormalized accumulate (channels 2*lane, 2*lane+1)
  const unsigned* xph = (const unsigned*)xh + (size_t)h * N * 64;   // bf162 units, head plane
  float pself = __expf(vself - m);
  unsigned xs0 = xph[(size_t)n * 64 + lane];
  float a0 = pself * bf2lo(xs0);
  float a1 = pself * bf2hi(xs0);
  float b0 = 0.f, b1 = 0.f, c0 = 0.f, c1 = 0.f, d0 = 0.f, d1 = 0.f;
  float psum = (lane == 0) ? pself : 0.f;
  for (int c = 0; c < deg; c += 64) {
    int i = c + lane;
    int s = 0;
    float p = 0.f;
    if (i < deg) {
      s = adj[base + i];
      float v = esh[s] + edn;
      v = v > 0.f ? v : 0.2f * v;
      p = __expf(v - m);
      psum += p;
    }
    int cnt = min(64, deg - c);
    int j = 0;
    for (; j + 4 <= cnt; j += 4) {
      int s0 = __builtin_amdgcn_readlane(s, j);
      int s1 = __builtin_amdgcn_readlane(s, j + 1);
      int s2 = __builtin_amdgcn_readlane(s, j + 2);
      int s3 = __builtin_amdgcn_readlane(s, j + 3);
      float p0 = __int_as_float(__builtin_amdgcn_readlane(__float_as_int(p), j));
      float p1 = __int_as_float(__builtin_amdgcn_readlane(__float_as_int(p), j + 1));
      float p2 = __int_as_float(__builtin_amdgcn_readlane(__float_as_int(p), j + 2));
      float p3 = __int_as_float(__builtin_amdgcn_readlane(__float_as_int(p), j + 3));
      unsigned v0 = xph[(size_t)s0 * 64 + lane];
      unsigned v1 = xph[(size_t)s1 * 64 + lane];
      unsigned v2 = xph[(size_t)s2 * 64 + lane];
      unsigned v3 = xph[(size_t)s3 * 64 + lane];
      a0 += p0 * bf2lo(v0); a1 += p0 * bf2hi(v0);
      b0 += p1 * bf2lo(v1); b1 += p1 * bf2hi(v1);
      c0 += p2 * bf2lo(v2); c1 += p2 * bf2hi(v2);
      d0 += p3 * bf2lo(v3); d1 += p3 * bf2hi(v3);
    }
    for (; j < cnt; ++j) {
      int s0 = __builtin_amdgcn_readlane(s, j);
      float p0 = __int_as_float(__builtin_amdgcn_readlane(__float_as_int(p), j));
      unsigned v0 = xph[(size_t)s0 * 64 + lane];
      a0 += p0 * bf2lo(v0); a1 += p0 * bf2hi(v0);
    }
  }
  a0 += b0 + c0 + d0;
  a1 += b1 + c1 + d1;
#pragma unroll
  for (int off = 32; off; off >>= 1) psum += __shfl_xor(psum, off);
  float inv = 1.f / psum;
  float2 bv = ((const float2*)(bias + h * 128))[lane];
  float o0 = a0 * inv + bv.x;
  float o1 = a1 * inv + bv.y;
  o0 = o0 > 0.f ? o0 : expm1f(o0);
  o1 = o1 > 0.f ? o1 : expm1f(o1);
  __hip_bfloat162 r;
  r.x = __float2bfloat16(o0);
  r.y = __float2bfloat16(o1);
  ((__hip_bfloat162*)gout)[(size_t)n * (H * 64) + h * 64 + lane] = r;   // row-major out
}

// column sums of A[N x 128](bf16) accumulated into colsum[128]
__global__ void k_colsum(const __hip_bfloat16* __restrict__ A, float* __restrict__ colsum,
                         int N) {
  int c = threadIdx.x;  // 128 threads
  int rows_per_block = CDIV(N, (int)gridDim.x);
  int r0 = blockIdx.x * rows_per_block;
  int r1 = min(N, r0 + rows_per_block);
  float acc = 0.f;
  for (int r = r0; r < r1; ++r) acc += __bfloat162float(A[(size_t)r * 128 + c]);
  atomicAdd(&colsum[c], acc);
}

// single block head MLP -> vvec[384]
__global__ void k_head(const float* __restrict__ colsum, const float* __restrict__ Wfc,
                       const float* __restrict__ bfc, const float* __restrict__ Whg,
                       const float* __restrict__ bhg, const float* __restrict__ Wv,
                       const float* __restrict__ bv, float* __restrict__ vvec, float invN) {
  __shared__ float h[128], t1[256], hg[128];
  int t = threadIdx.x;  // 256
  if (t < 128) h[t] = colsum[t] * invN;
  __syncthreads();
  float acc = bfc[t];
  for (int k = 0; k < 128; k++) acc += h[k] * Wfc[k * 256 + t];
  t1[t] = fmaxf(acc, 0.f);
  __syncthreads();
  if (t < 128) {
    float a2 = bhg[t];
    for (int k = 0; k < 256; k++) a2 += t1[k] * Whg[k * 128 + t];
    hg[t] = a2;
  }
  __syncthreads();
  for (int j = t; j < 384; j += 256) {
    float a3 = bv[j];
    for (int k = 0; k < 128; k++) a3 += hg[k] * Wv[k * 384 + j];
    vvec[j] = fmaxf(a3, 0.f);
  }
}

// per-batch-row BAN tail
__global__ void k_fused(const float* __restrict__ vvec, const float* __restrict__ q,
                        const float* __restrict__ hmat, const float* __restrict__ hbias,
                        float* __restrict__ logits) {
  int b = blockIdx.x, c = threadIdx.x;  // 128 threads
  __shared__ float red[128];
  float t[3];
  float part = 0.f;
#pragma unroll
  for (int j = 0; j < 3; j++) {
    int k = c * 3 + j;
    float hs = hmat[k] + hmat[384 + k] + hmat[768 + k] + hmat[1152 + k];
    t[j] = vvec[k] * q[(size_t)b * 384 + k];
    part += hs * t[j];
  }
  red[c] = part;
  __syncthreads();
  for (int s = 64; s > 0; s >>= 1) {
    if (c < s) red[c] += red[c + s];
    __syncthreads();
  }
  float attsum = red[0] + (hbias[0] + hbias[1] + hbias[2] + hbias[3]);
  logits[(size_t)b * 128 + c] = attsum * (t[0] + t[1] + t[2]);
}

// batchnorm over batch dim (biased var), one block per channel c
__global__ void k_bn(const float* __restrict__ logits, const float* __restrict__ gamma,
                     const float* __restrict__ beta, float* __restrict__ out, int B) {
  int c = blockIdx.x, b = threadIdx.x;  // B threads
  __shared__ float s1[256], s2[256];
  float v = logits[(size_t)b * 128 + c];
  s1[b] = v; s2[b] = v * v;
  __syncthreads();
  for (int s = B / 2; s > 0; s >>= 1) {
    if (b < s) { s1[b] += s1[b + s]; s2[b] += s2[b + s]; }
    __syncthreads();
  }
  float mu = s1[0] / B;
  float var = s2[0] / B - mu * mu;
  out[(size_t)b * 128 + c] = (v - mu) * rsqrtf(var + 1e-5f) * gamma[c] + beta[c];
}

extern "C" void kernel_launch(void* const* d_in, const int* in_sizes, int n_in,
                              void* d_out, int out_size, void* d_ws, size_t ws_size,
                              hipStream_t stream) {
  const float* cell = (const float*)d_in[0];
  const float* Wd   = (const float*)d_in[1];
  const float* bd   = (const float*)d_in[2];
  const float* W1   = (const float*)d_in[3];
  const float* a1s  = (const float*)d_in[4];
  const float* a1d  = (const float*)d_in[5];
  const float* b1   = (const float*)d_in[6];
  const float* Wl1  = (const float*)d_in[7];
  const float* bl1  = (const float*)d_in[8];
  const float* W2   = (const float*)d_in[9];
  const float* a2s  = (const float*)d_in[10];
  const float* a2d  = (const float*)d_in[11];
  const float* b2   = (const float*)d_in[12];
  const float* Wl2  = (const float*)d_in[13];
  const float* bl2  = (const float*)d_in[14];
  const float* Wfc  = (const float*)d_in[15];
  const float* bfc  = (const float*)d_in[16];
  const float* Whg  = (const float*)d_in[17];
  const float* bhg  = (const float*)d_in[18];
  const float* Wc   = (const float*)d_in[19];
  const float* bc   = (const float*)d_in[20];
  const float* Wv   = (const float*)d_in[21];
  const float* bv   = (const float*)d_in[22];
  const float* Wq   = (const float*)d_in[23];
  const float* bq   = (const float*)d_in[24];
  const float* hmat = (const float*)d_in[25];
  const float* hbias= (const float*)d_in[26];
  const float* gamma= (const float*)d_in[27];
  const float* beta = (const float*)d_in[28];
  const int* trip   = (const int*)d_in[29];
  const int* eidx   = (const int*)d_in[30];

  const int N = in_sizes[29] / 4;     // 20000
  const int E = in_sizes[30] / 2;     // 500000
  const int B = in_sizes[0] / 954;    // 256
  float* out = (float*)d_out;

  // ---------------- workspace layout: bf16 region first (16B aligned) ----------------
  __hip_bfloat16* xb    = (__hip_bfloat16*)d_ws;      // N*128
  __hip_bfloat16* xhb   = xb + (size_t)N * 128;       // N*640  (head-major [H][N][128])
  __hip_bfloat16* goutb = xhb + (size_t)N * 640;      // N*640  (row-major [N][H*128])
  __hip_bfloat16* h1b   = goutb + (size_t)N * 640;    // N*128
  __hip_bfloat16* h2b   = h1b + (size_t)N * 128;      // N*128
  __hip_bfloat16* W1t   = h2b + (size_t)N * 128;      // 512*128
  __hip_bfloat16* Wl1t  = W1t + 512 * 128;            // 128*512
  __hip_bfloat16* W2t   = Wl1t + 128 * 512;           // 640*128
  __hip_bfloat16* Wl2t  = W2t + 640 * 128;            // 128*640
  // f32 region
  float* es     = (float*)(Wl2t + 128 * 640);          // N*5 (head-major [H][N])
  float* ed     = es + (size_t)N * 5;                  // N*5
  float* colsum = ed + (size_t)N * 5;          // 128
  float* cbuf   = colsum + 128;                // B*128
  float* qbuf   = cbuf + (size_t)B * 128;      // B*384
  float* vvec   = qbuf + (size_t)B * 384;      // 384
  float* logits = vvec + 384;                  // B*128
  float* Wct    = logits + (size_t)B * 128;    // 128*954
  float* Wqt    = Wct + 128 * 954;             // 384*128
  // int region
  int* rowptr   = (int*)(Wqt + 384 * 128);     // N+1
  int* degb     = rowptr + (N + 1);            // N
  int* cursor   = degb + N;                    // N
  int* adj      = cursor + N;                  // E

  const int* src0 = eidx;
  const int* dst0 = eidx + E;

  (void)hipMemsetAsync(colsum, 0, 128 * sizeof(float), stream);
  (void)hipMemsetAsync(degb, 0, (size_t)2 * N * sizeof(int), stream);

  // all weight transposes in one launch
  {
    int tot = 128*512 + 512*128 + 128*640 + 640*128 + 954*128 + 128*384;
    k_prep<<<CDIV(tot, 256), 256, 0, stream>>>(W1, W1t, Wl1, Wl1t, W2, W2t, Wl2, Wl2t,
                                               Wc, Wct, Wq, Wqt);
  }

  // CSR build (shared by both GAT layers)
  k_deg<<<CDIV(E, 256), 256, 0, stream>>>(src0, dst0, degb, E);
  k_scan<<<1, 1024, 0, stream>>>(degb, rowptr, N);
  k_fill_adj<<<CDIV(E, 256), 256, 0, stream>>>(src0, dst0, rowptr, cursor, adj, E);

  k_drug<<<CDIV(N * 128, 256), 256, 0, stream>>>(trip, Wd, bd, xb, N);

  // ---------------- GAT1 (H=4) ----------------
  {
    dim3 g(512 / 64, CDIV(N, 64));
    k_gemm_mfma<false><<<g, 256, 0, stream>>>(xb, W1t, nullptr, xhb, N, 128, 512);
  }
  k_coef<<<CDIV(N * 4, 4), 256, 0, stream>>>(xhb, a1s, a1d, es, ed, N, 4);
  k_gat_gather<<<CDIV(N * 4, 4), 256, 0, stream>>>(rowptr, adj, es, ed, xhb, b1, goutb, N, 4);
  {
    dim3 g(128 / 64, CDIV(N, 64));
    k_gemm_mfma<true><<<g, 256, 0, stream>>>(goutb, Wl1t, bl1, h1b, N, 512, 128);
  }
  k_colsum<<<256, 128, 0, stream>>>(h1b, colsum, N);

  // ---------------- GAT2 (H=5) ----------------
  {
    dim3 g(640 / 64, CDIV(N, 64));
    k_gemm_mfma<false><<<g, 256, 0, stream>>>(h1b, W2t, nullptr, xhb, N, 128, 640);
  }
  k_coef<<<CDIV(N * 5, 4), 256, 0, stream>>>(xhb, a2s, a2d, es, ed, N, 5);
  k_gat_gather<<<CDIV(N * 5, 4), 256, 0, stream>>>(rowptr, adj, es, ed, xhb, b2, goutb, N, 5);
  {
    dim3 g(128 / 64, CDIV(N, 64));
    k_gemm_mfma<true><<<g, 256, 0, stream>>>(goutb, Wl2t, bl2, h2b, N, 640, 128);
  }
  k_colsum<<<256, 128, 0, stream>>>(h2b, colsum, N);

  // ---------------- head + BAN + BN ----------------
  k_head<<<1, 256, 0, stream>>>(colsum, Wfc, bfc, Whg, bhg, Wv, bv, vvec, 1.0f / N);
  k_dotmm<<<CDIV(B * 128, 4), 256, 0, stream>>>(cell, Wct, bc, cbuf, B, 954, 128);
  k_dotmm<<<CDIV(B * 384, 4), 256, 0, stream>>>(cbuf, Wqt, bq, qbuf, B, 128, 384);
  k_fused<<<B, 128, 0, stream>>>(vvec, qbuf, hmat, hbias, logits);
  k_bn<<<128, B, 0, stream>>>(logits, gamma, beta, out, B);
}

// Round 9
// 554.313 us; speedup vs baseline: 5.2831x; 1.0184x over previous
//
#include <hip/hip_runtime.h>
#include <hip/hip_bf16.h>
#include <math.h>

#define CDIV(a,b) (((a)+(b)-1)/(b))

typedef __attribute__((ext_vector_type(8))) short short8v;   // 8 bf16
typedef __attribute__((ext_vector_type(4))) float f32x4;
typedef __attribute__((ext_vector_type(2))) unsigned int uint2v;

__device__ inline float bf2lo(unsigned u) { return __uint_as_float(u << 16); }
__device__ inline float bf2hi(unsigned u) { return __uint_as_float(u & 0xffff0000u); }
__device__ inline float leaky(float v) { return v > 0.f ? v : 0.2f * v; }
__device__ inline float rlanef(float p, int j) {
  return __int_as_float(__builtin_amdgcn_readlane(__float_as_int(p), j));
}

// ---------------- all weight transposes in one launch ----------------
__global__ void k_prep(const float* __restrict__ W1, __hip_bfloat16* __restrict__ W1t,
                       const float* __restrict__ Wl1, __hip_bfloat16* __restrict__ Wl1t,
                       const float* __restrict__ W2, __hip_bfloat16* __restrict__ W2t,
                       const float* __restrict__ Wl2, __hip_bfloat16* __restrict__ Wl2t,
                       const float* __restrict__ Wc, float* __restrict__ Wct,
                       const float* __restrict__ Wq, float* __restrict__ Wqt) {
  int i = blockIdx.x * 256 + threadIdx.x;
  const int n1 = 128 * 512, n2 = 512 * 128, n3 = 128 * 640, n4 = 640 * 128;
  const int n5 = 954 * 128, n6 = 128 * 384;
  if (i < n1) { int m = i / 128, k = i % 128; W1t[i] = __float2bfloat16(W1[(size_t)k * 512 + m]); return; }
  i -= n1;
  if (i < n2) { int m = i / 512, k = i % 512; Wl1t[i] = __float2bfloat16(Wl1[(size_t)k * 128 + m]); return; }
  i -= n2;
  if (i < n3) { int m = i / 128, k = i % 128; W2t[i] = __float2bfloat16(W2[(size_t)k * 640 + m]); return; }
  i -= n3;
  if (i < n4) { int m = i / 640, k = i % 640; Wl2t[i] = __float2bfloat16(Wl2[(size_t)k * 128 + m]); return; }
  i -= n4;
  if (i < n5) { int m = i / 954, k = i % 954; Wct[i] = Wc[(size_t)k * 128 + m]; return; }
  i -= n5;
  if (i < n6) { int m = i / 128, k = i % 128; Wqt[i] = Wq[(size_t)k * 384 + m]; return; }
}

// ---------------- x = triplets(float) @ Wd + bd  (bf16 out) ----------------
__global__ void k_drug(const int* __restrict__ trip, const float* __restrict__ Wd,
                       const float* __restrict__ bd, __hip_bfloat16* __restrict__ x, int N) {
  int i = blockIdx.x * 256 + threadIdx.x;
  if (i >= N * 128) return;
  int n = i >> 7, c = i & 127;
  const int* t = trip + n * 4;
  float acc = bd[c];
  acc += (float)t[0] * Wd[c] + (float)t[1] * Wd[128 + c] +
         (float)t[2] * Wd[256 + c] + (float)t[3] * Wd[384 + c];
  x[i] = __float2bfloat16(acc);
}

// ---------------- bf16 MFMA GEMM: head-major planed output -----------------------
template <bool BIAS>
__global__ void k_gemm_mfma(const __hip_bfloat16* __restrict__ A,
                            const __hip_bfloat16* __restrict__ Bt,
                            const float* __restrict__ bias,
                            __hip_bfloat16* __restrict__ Cb,
                            int Nr, int K, int M) {
  __shared__ short As[64 * 40];
  __shared__ short Bs[64 * 40];
  int tid = threadIdx.x;
  int lane = tid & 63, wid = tid >> 6;
  int wr = wid >> 1, wc = wid & 1;
  int lrow = lane & 15, lkc = lane >> 4;
  int row0 = blockIdx.y * 64, col0 = blockIdx.x * 64;

  int arow = tid >> 2, akc = tid & 3;
  int grow = row0 + arow; if (grow >= Nr) grow = Nr - 1;
  const __hip_bfloat16* agp = A + (size_t)grow * K + akc * 8;
  const __hip_bfloat16* bgp = Bt + (size_t)(col0 + arow) * K + akc * 8;
  short* asp = &As[arow * 40 + akc * 8];
  short* bsp = &Bs[arow * 40 + akc * 8];

  f32x4 acc00 = {0.f,0.f,0.f,0.f}, acc01 = acc00, acc10 = acc00, acc11 = acc00;

  const short* a0p = &As[(wr * 32 + lrow) * 40 + lkc * 8];
  const short* a1p = &As[(wr * 32 + 16 + lrow) * 40 + lkc * 8];
  const short* b0p = &Bs[(wc * 32 + lrow) * 40 + lkc * 8];
  const short* b1p = &Bs[(wc * 32 + 16 + lrow) * 40 + lkc * 8];

  for (int k0 = 0; k0 < K; k0 += 32) {
    short8v av = *(const short8v*)(agp + k0);
    short8v bv = *(const short8v*)(bgp + k0);
    __syncthreads();
    *(short8v*)asp = av;
    *(short8v*)bsp = bv;
    __syncthreads();
    short8v a0 = *(const short8v*)a0p;
    short8v a1 = *(const short8v*)a1p;
    short8v b0 = *(const short8v*)b0p;
    short8v b1 = *(const short8v*)b1p;
    acc00 = __builtin_amdgcn_mfma_f32_16x16x32_bf16(a0, b0, acc00, 0, 0, 0);
    acc01 = __builtin_amdgcn_mfma_f32_16x16x32_bf16(a0, b1, acc01, 0, 0, 0);
    acc10 = __builtin_amdgcn_mfma_f32_16x16x32_bf16(a1, b0, acc10, 0, 0, 0);
    acc11 = __builtin_amdgcn_mfma_f32_16x16x32_bf16(a1, b1, acc11, 0, 0, 0);
  }

  // C/D layout (m89): col = lane&15, row = (lane>>4)*4 + r
  int rbase = row0 + wr * 32 + (lane >> 4) * 4;
  int cbase = col0 + wc * 32 + lrow;
#pragma unroll
  for (int m = 0; m < 2; ++m) {
#pragma unroll
    for (int n = 0; n < 2; ++n) {
      f32x4 acc = m == 0 ? (n == 0 ? acc00 : acc01) : (n == 0 ? acc10 : acc11);
      int col = cbase + n * 16;
      int plane = col >> 7, ch = col & 127;
      float bv = BIAS ? bias[col] : 0.f;
      __hip_bfloat16* cp = Cb + (size_t)plane * Nr * 128 + ch;
#pragma unroll
      for (int r = 0; r < 4; ++r) {
        int grow2 = rbase + m * 16 + r;
        if (grow2 >= Nr) continue;
        cp[(size_t)grow2 * 128] = __float2bfloat16(acc[r] + bv);
      }
    }
  }
}

// ---------------- wave-per-output GEMM: C = relu(A @ Bt^T + bias) ----------------
__global__ void k_dotmm(const float* __restrict__ A, const float* __restrict__ Bt,
                        const float* __restrict__ bias, float* __restrict__ C,
                        int Nr, int K, int M) {
  int wid = (blockIdx.x * blockDim.x + threadIdx.x) >> 6;
  int lane = threadIdx.x & 63;
  if (wid >= Nr * M) return;
  int b = wid / M, m = wid % M;
  const float* ar = A + (size_t)b * K;
  const float* br = Bt + (size_t)m * K;
  float acc = 0.f;
  for (int k = lane * 2; k + 1 < K; k += 128) {
    float2 av = *(const float2*)(ar + k);
    float2 bv = *(const float2*)(br + k);
    acc += av.x * bv.x + av.y * bv.y;
  }
#pragma unroll
  for (int off = 32; off; off >>= 1) acc += __shfl_xor(acc, off);
  if (lane == 0) C[wid] = fmaxf(acc + bias[m], 0.f);
}

// ---------------- es/ed per (node, head), head-major xh [H][N][128] ----------------
__global__ void k_coef(const __hip_bfloat16* __restrict__ xh, const float* __restrict__ as_,
                       const float* __restrict__ ad_, float* __restrict__ es,
                       float* __restrict__ ed, int N, int H) {
  int wid = (blockIdx.x * blockDim.x + threadIdx.x) >> 6;
  int lane = threadIdx.x & 63;
  if (wid >= N * H) return;
  int h = wid / N, n = wid - h * N;
  const __hip_bfloat162* xp = (const __hip_bfloat162*)xh + (size_t)h * N * 64 + (size_t)n * 64;
  __hip_bfloat162 xv = xp[lane];
  float x0 = __bfloat162float(xv.x), x1 = __bfloat162float(xv.y);
  float2 a = ((const float2*)(as_ + h * 128))[lane];
  float2 d = ((const float2*)(ad_ + h * 128))[lane];
  float e1 = x0 * a.x + x1 * a.y;
  float e2 = x0 * d.x + x1 * d.y;
#pragma unroll
  for (int off = 32; off; off >>= 1) {
    e1 += __shfl_xor(e1, off);
    e2 += __shfl_xor(e2, off);
  }
  if (lane == 0) { es[(size_t)h * N + n] = e1; ed[(size_t)h * N + n] = e2; }
}

// ---------------- CSR build ----------------
__global__ void k_deg(const int* __restrict__ src0, const int* __restrict__ dst0,
                      int* __restrict__ deg, int E) {
  int e = blockIdx.x * 256 + threadIdx.x;
  if (e >= E) return;
  int s = src0[e], d = dst0[e];
  if (s != d) atomicAdd(&deg[d], 1);
}

__global__ void k_scan(const int* __restrict__ deg, int* __restrict__ rowptr, int N) {
  __shared__ int part[1024];
  int t = threadIdx.x;
  int chunk = (N + 1023) >> 10;
  int b0 = t * chunk, b1 = min(N, b0 + chunk);
  int s = 0;
  for (int i = b0; i < b1; i++) s += deg[i];
  part[t] = s;
  __syncthreads();
  for (int off = 1; off < 1024; off <<= 1) {
    int v = (t >= off) ? part[t - off] : 0;
    __syncthreads();
    part[t] += v;
    __syncthreads();
  }
  int run = (t == 0) ? 0 : part[t - 1];
  for (int i = b0; i < b1; i++) { rowptr[i] = run; run += deg[i]; }
  if (b1 == N) rowptr[N] = run;
}

__global__ void k_fill_adj(const int* __restrict__ src0, const int* __restrict__ dst0,
                           const int* __restrict__ rowptr, int* __restrict__ cursor,
                           int* __restrict__ adj, int E) {
  int e = blockIdx.x * 256 + threadIdx.x;
  if (e >= E) return;
  int s = src0[e], d = dst0[e];
  if (s != d) {
    int pos = rowptr[d] + atomicAdd(&cursor[d], 1);
    adj[pos] = s;
  }
}

// ---------------- pair-gather inner loop: 2 edges per iteration (half-wave split) -------
// lanes 0-31 accumulate even edges, lanes 32-63 odd edges; each lane owns 4 channels.
// requires: for lanes >= cnt within the chunk, s==0 and p==0.  cnt <= 64.
__device__ __forceinline__ void pair_accum(const char* xbase, int loff, int half,
                                           int s, float p, int cnt,
                                           float& a0, float& a1, float& a2, float& a3,
                                           float& b0, float& b1, float& b2, float& b3) {
  int j = 0;
  for (; j + 4 <= cnt; j += 4) {
    int sL0 = __builtin_amdgcn_readlane(s, j);
    int sH0 = __builtin_amdgcn_readlane(s, j + 1);
    int sL1 = __builtin_amdgcn_readlane(s, j + 2);
    int sH1 = __builtin_amdgcn_readlane(s, j + 3);
    float pL0 = rlanef(p, j), pH0 = rlanef(p, j + 1);
    float pL1 = rlanef(p, j + 2), pH1 = rlanef(p, j + 3);
    int r0 = half ? sH0 : sL0;
    int r1 = half ? sH1 : sL1;
    float q0 = half ? pH0 : pL0;
    float q1 = half ? pH1 : pL1;
    uint2v u0 = *(const uint2v*)(xbase + (size_t)r0 * 256 + loff);
    uint2v u1 = *(const uint2v*)(xbase + (size_t)r1 * 256 + loff);
    a0 += q0 * bf2lo(u0.x); a1 += q0 * bf2hi(u0.x);
    a2 += q0 * bf2lo(u0.y); a3 += q0 * bf2hi(u0.y);
    b0 += q1 * bf2lo(u1.x); b1 += q1 * bf2hi(u1.x);
    b2 += q1 * bf2lo(u1.y); b3 += q1 * bf2hi(u1.y);
  }
  // remainder: only runs when cnt < 64 (cnt==64 is divisible by 4), so j+1 <= cnt < 64
  // is a valid lane, and p there is 0 when j+1 == cnt.
  for (; j < cnt; j += 2) {
    int sL = __builtin_amdgcn_readlane(s, j);
    int sH = __builtin_amdgcn_readlane(s, j + 1);
    float pL = rlanef(p, j);
    float pH = rlanef(p, j + 1);
    int r0 = half ? sH : sL;
    float q0 = half ? pH : pL;
    uint2v u0 = *(const uint2v*)(xbase + (size_t)r0 * 256 + loff);
    a0 += q0 * bf2lo(u0.x); a1 += q0 * bf2hi(u0.x);
    a2 += q0 * bf2lo(u0.y); a3 += q0 * bf2hi(u0.y);
  }
}

// ---------------- fused GAT aggregation: one wave per (node, head), head-major xh ----------
__global__ void k_gat_gather(const int* __restrict__ rowptr, const int* __restrict__ adj,
                             const float* __restrict__ es, const float* __restrict__ ed,
                             const __hip_bfloat16* __restrict__ xh,
                             const float* __restrict__ bias,
                             __hip_bfloat16* __restrict__ gout, int N, int H) {
  // XCD-aware block swizzle (bijective when grid % 8 == 0)
  int nb = gridDim.x, bx = blockIdx.x;
  int sb = ((nb & 7) == 0) ? ((bx & 7) * (nb >> 3) + (bx >> 3)) : bx;
  int wid = sb * 4 + (threadIdx.x >> 6);
  int lane = threadIdx.x & 63;
  if (wid >= N * H) return;
  int h = wid / N, n = wid - h * N;
  int base = rowptr[n];
  int deg = rowptr[n + 1] - base;
  const float* esh = es + (size_t)h * N;
  float edn = ed[(size_t)h * N + n];
  float vself = leaky(esh[n] + edn);
  const char* xbase = (const char*)xh + (size_t)h * N * 256;   // head plane, bytes
  int half = lane >> 5, l5 = lane & 31, loff = l5 * 8;

  float a0 = 0.f, a1 = 0.f, a2 = 0.f, a3 = 0.f;
  float b0 = 0.f, b1 = 0.f, b2 = 0.f, b3 = 0.f;
  float psum, pself, m;

  if (deg <= 64) {
    // fast path: single fused pass (covers ~all nodes at avg degree 25)
    int s = 0; float v = -1e30f;
    if (lane < deg) { s = adj[base + lane]; v = leaky(esh[s] + edn); }
    m = fmaxf(vself, v);
#pragma unroll
    for (int off = 32; off; off >>= 1) m = fmaxf(m, __shfl_xor(m, off));
    float p = (lane < deg) ? __expf(v - m) : 0.f;
    pself = __expf(vself - m);
    psum = p;
    pair_accum(xbase, loff, half, s, p, deg, a0, a1, a2, a3, b0, b1, b2, b3);
  } else {
    m = vself;
    for (int i = lane; i < deg; i += 64) {
      int s = adj[base + i];
      m = fmaxf(m, leaky(esh[s] + edn));
    }
#pragma unroll
    for (int off = 32; off; off >>= 1) m = fmaxf(m, __shfl_xor(m, off));
    pself = __expf(vself - m);
    psum = 0.f;
    for (int c = 0; c < deg; c += 64) {
      int i = c + lane;
      int s = 0; float p = 0.f;
      if (i < deg) {
        s = adj[base + i];
        p = __expf(leaky(esh[s] + edn) - m);
        psum += p;
      }
      pair_accum(xbase, loff, half, s, p, min(64, deg - c), a0, a1, a2, a3, b0, b1, b2, b3);
    }
  }

  // self-loop contribution (half 0 only; half 1 multiplies by 0)
  {
    uint2v u = *(const uint2v*)(xbase + (size_t)n * 256 + loff);
    float q = half ? 0.f : pself;
    a0 += q * bf2lo(u.x); a1 += q * bf2hi(u.x);
    a2 += q * bf2lo(u.y); a3 += q * bf2hi(u.y);
  }
#pragma unroll
  for (int off = 32; off; off >>= 1) psum += __shfl_xor(psum, off);
  psum += pself;
  a0 += b0; a1 += b1; a2 += b2; a3 += b3;
  a0 += __shfl_xor(a0, 32);
  a1 += __shfl_xor(a1, 32);
  a2 += __shfl_xor(a2, 32);
  a3 += __shfl_xor(a3, 32);
  float inv = 1.f / psum;
  float4 bv = ((const float4*)(bias + h * 128))[l5];
  float o0 = a0 * inv + bv.x;
  float o1 = a1 * inv + bv.y;
  float o2 = a2 * inv + bv.z;
  float o3 = a3 * inv + bv.w;
  o0 = o0 > 0.f ? o0 : expm1f(o0);
  o1 = o1 > 0.f ? o1 : expm1f(o1);
  o2 = o2 > 0.f ? o2 : expm1f(o2);
  o3 = o3 > 0.f ? o3 : expm1f(o3);
  if (half == 0) {
    __hip_bfloat162 r01, r23;
    r01.x = __float2bfloat16(o0); r01.y = __float2bfloat16(o1);
    r23.x = __float2bfloat16(o2); r23.y = __float2bfloat16(o3);
    __hip_bfloat162* gp = (__hip_bfloat162*)(gout + (size_t)n * (H * 128) + h * 128 + l5 * 4);
    gp[0] = r01;
    gp[1] = r23;
  }
}

// column sums of A[N x 128](bf16) accumulated into colsum[128]
__global__ void k_colsum(const __hip_bfloat16* __restrict__ A, float* __restrict__ colsum,
                         int N) {
  int c = threadIdx.x;  // 128 threads
  int rows_per_block = CDIV(N, (int)gridDim.x);
  int r0 = blockIdx.x * rows_per_block;
  int r1 = min(N, r0 + rows_per_block);
  float acc = 0.f;
  for (int r = r0; r < r1; ++r) acc += __bfloat162float(A[(size_t)r * 128 + c]);
  atomicAdd(&colsum[c], acc);
}

// single block head MLP -> vvec[384]
__global__ void k_head(const float* __restrict__ colsum, const float* __restrict__ Wfc,
                       const float* __restrict__ bfc, const float* __restrict__ Whg,
                       const float* __restrict__ bhg, const float* __restrict__ Wv,
                       const float* __restrict__ bv, float* __restrict__ vvec, float invN) {
  __shared__ float h[128], t1[256], hg[128];
  int t = threadIdx.x;  // 256
  if (t < 128) h[t] = colsum[t] * invN;
  __syncthreads();
  float acc = bfc[t];
  for (int k = 0; k < 128; k++) acc += h[k] * Wfc[k * 256 + t];
  t1[t] = fmaxf(acc, 0.f);
  __syncthreads();
  if (t < 128) {
    float a2 = bhg[t];
    for (int k = 0; k < 256; k++) a2 += t1[k] * Whg[k * 128 + t];
    hg[t] = a2;
  }
  __syncthreads();
  for (int j = t; j < 384; j += 256) {
    float a3 = bv[j];
    for (int k = 0; k < 128; k++) a3 += hg[k] * Wv[k * 384 + j];
    vvec[j] = fmaxf(a3, 0.f);
  }
}

// per-batch-row BAN tail
__global__ void k_fused(const float* __restrict__ vvec, const float* __restrict__ q,
                        const float* __restrict__ hmat, const float* __restrict__ hbias,
                        float* __restrict__ logits) {
  int b = blockIdx.x, c = threadIdx.x;  // 128 threads
  __shared__ float red[128];
  float t[3];
  float part = 0.f;
#pragma unroll
  for (int j = 0; j < 3; j++) {
    int k = c * 3 + j;
    float hs = hmat[k] + hmat[384 + k] + hmat[768 + k] + hmat[1152 + k];
    t[j] = vvec[k] * q[(size_t)b * 384 + k];
    part += hs * t[j];
  }
  red[c] = part;
  __syncthreads();
  for (int s = 64; s > 0; s >>= 1) {
    if (c < s) red[c] += red[c + s];
    __syncthreads();
  }
  float attsum = red[0] + (hbias[0] + hbias[1] + hbias[2] + hbias[3]);
  logits[(size_t)b * 128 + c] = attsum * (t[0] + t[1] + t[2]);
}

// batchnorm over batch dim (biased var), one block per channel c
__global__ void k_bn(const float* __restrict__ logits, const float* __restrict__ gamma,
                     const float* __restrict__ beta, float* __restrict__ out, int B) {
  int c = blockIdx.x, b = threadIdx.x;  // B threads
  __shared__ float s1[256], s2[256];
  float v = logits[(size_t)b * 128 + c];
  s1[b] = v; s2[b] = v * v;
  __syncthreads();
  for (int s = B / 2; s > 0; s >>= 1) {
    if (b < s) { s1[b] += s1[b + s]; s2[b] += s2[b + s]; }
    __syncthreads();
  }
  float mu = s1[0] / B;
  float var = s2[0] / B - mu * mu;
  out[(size_t)b * 128 + c] = (v - mu) * rsqrtf(var + 1e-5f) * gamma[c] + beta[c];
}

extern "C" void kernel_launch(void* const* d_in, const int* in_sizes, int n_in,
                              void* d_out, int out_size, void* d_ws, size_t ws_size,
                              hipStream_t stream) {
  const float* cell = (const float*)d_in[0];
  const float* Wd   = (const float*)d_in[1];
  const float* bd   = (const float*)d_in[2];
  const float* W1   = (const float*)d_in[3];
  const float* a1s  = (const float*)d_in[4];
  const float* a1d  = (const float*)d_in[5];
  const float* b1   = (const float*)d_in[6];
  const float* Wl1  = (const float*)d_in[7];
  const float* bl1  = (const float*)d_in[8];
  const float* W2   = (const float*)d_in[9];
  const float* a2s  = (const float*)d_in[10];
  const float* a2d  = (const float*)d_in[11];
  const float* b2   = (const float*)d_in[12];
  const float* Wl2  = (const float*)d_in[13];
  const float* bl2  = (const float*)d_in[14];
  const float* Wfc  = (const float*)d_in[15];
  const float* bfc  = (const float*)d_in[16];
  const float* Whg  = (const float*)d_in[17];
  const float* bhg  = (const float*)d_in[18];
  const float* Wc   = (const float*)d_in[19];
  const float* bc   = (const float*)d_in[20];
  const float* Wv   = (const float*)d_in[21];
  const float* bv   = (const float*)d_in[22];
  const float* Wq   = (const float*)d_in[23];
  const float* bq   = (const float*)d_in[24];
  const float* hmat = (const float*)d_in[25];
  const float* hbias= (const float*)d_in[26];
  const float* gamma= (const float*)d_in[27];
  const float* beta = (const float*)d_in[28];
  const int* trip   = (const int*)d_in[29];
  const int* eidx   = (const int*)d_in[30];

  const int N = in_sizes[29] / 4;     // 20000
  const int E = in_sizes[30] / 2;     // 500000
  const int B = in_sizes[0] / 954;    // 256
  float* out = (float*)d_out;

  // ---------------- workspace layout: bf16 region first (16B aligned) ----------------
  __hip_bfloat16* xb    = (__hip_bfloat16*)d_ws;      // N*128
  __hip_bfloat16* xhb   = xb + (size_t)N * 128;       // N*640  (head-major [H][N][128])
  __hip_bfloat16* goutb = xhb + (size_t)N * 640;      // N*640  (row-major [N][H*128])
  __hip_bfloat16* h1b   = goutb + (size_t)N * 640;    // N*128
  __hip_bfloat16* h2b   = h1b + (size_t)N * 128;      // N*128
  __hip_bfloat16* W1t   = h2b + (size_t)N * 128;      // 512*128
  __hip_bfloat16* Wl1t  = W1t + 512 * 128;            // 128*512
  __hip_bfloat16* W2t   = Wl1t + 128 * 512;           // 640*128
  __hip_bfloat16* Wl2t  = W2t + 640 * 128;            // 128*640
  // f32 region
  float* es     = (float*)(Wl2t + 128 * 640);          // N*5 (head-major [H][N])
  float* ed     = es + (size_t)N * 5;                  // N*5
  float* colsum = ed + (size_t)N * 5;          // 128
  float* cbuf   = colsum + 128;                // B*128
  float* qbuf   = cbuf + (size_t)B * 128;      // B*384
  float* vvec   = qbuf + (size_t)B * 384;      // 384
  float* logits = vvec + 384;                  // B*128
  float* Wct    = logits + (size_t)B * 128;    // 128*954
  float* Wqt    = Wct + 128 * 954;             // 384*128
  // int region
  int* rowptr   = (int*)(Wqt + 384 * 128);     // N+1
  int* degb     = rowptr + (N + 1);            // N
  int* cursor   = degb + N;                    // N
  int* adj      = cursor + N;                  // E

  const int* src0 = eidx;
  const int* dst0 = eidx + E;

  (void)hipMemsetAsync(colsum, 0, 128 * sizeof(float), stream);
  (void)hipMemsetAsync(degb, 0, (size_t)2 * N * sizeof(int), stream);

  // all weight transposes in one launch
  {
    int tot = 128*512 + 512*128 + 128*640 + 640*128 + 954*128 + 128*384;
    k_prep<<<CDIV(tot, 256), 256, 0, stream>>>(W1, W1t, Wl1, Wl1t, W2, W2t, Wl2, Wl2t,
                                               Wc, Wct, Wq, Wqt);
  }

  // CSR build (shared by both GAT layers)
  k_deg<<<CDIV(E, 256), 256, 0, stream>>>(src0, dst0, degb, E);
  k_scan<<<1, 1024, 0, stream>>>(degb, rowptr, N);
  k_fill_adj<<<CDIV(E, 256), 256, 0, stream>>>(src0, dst0, rowptr, cursor, adj, E);

  k_drug<<<CDIV(N * 128, 256), 256, 0, stream>>>(trip, Wd, bd, xb, N);

  // ---------------- GAT1 (H=4) ----------------
  {
    dim3 g(512 / 64, CDIV(N, 64));
    k_gemm_mfma<false><<<g, 256, 0, stream>>>(xb, W1t, nullptr, xhb, N, 128, 512);
  }
  k_coef<<<CDIV(N * 4, 4), 256, 0, stream>>>(xhb, a1s, a1d, es, ed, N, 4);
  k_gat_gather<<<CDIV(N * 4, 4), 256, 0, stream>>>(rowptr, adj, es, ed, xhb, b1, goutb, N, 4);
  {
    dim3 g(128 / 64, CDIV(N, 64));
    k_gemm_mfma<true><<<g, 256, 0, stream>>>(goutb, Wl1t, bl1, h1b, N, 512, 128);
  }
  k_colsum<<<256, 128, 0, stream>>>(h1b, colsum, N);

  // ---------------- GAT2 (H=5) ----------------
  {
    dim3 g(640 / 64, CDIV(N, 64));
    k_gemm_mfma<false><<<g, 256, 0, stream>>>(h1b, W2t, nullptr, xhb, N, 128, 640);
  }
  k_coef<<<CDIV(N * 5, 4), 256, 0, stream>>>(xhb, a2s, a2d, es, ed, N, 5);
  k_gat_gather<<<CDIV(N * 5, 4), 256, 0, stream>>>(rowptr, adj, es, ed, xhb, b2, goutb, N, 5);
  {
    dim3 g(128 / 64, CDIV(N, 64));
    k_gemm_mfma<true><<<g, 256, 0, stream>>>(goutb, Wl2t, bl2, h2b, N, 640, 128);
  }
  k_colsum<<<256, 128, 0, stream>>>(h2b, colsum, N);

  // ---------------- head + BAN + BN ----------------
  k_head<<<1, 256, 0, stream>>>(colsum, Wfc, bfc, Whg, bhg, Wv, bv, vvec, 1.0f / N);
  k_dotmm<<<CDIV(B * 128, 4), 256, 0, stream>>>(cell, Wct, bc, cbuf, B, 954, 128);
  k_dotmm<<<CDIV(B * 384, 4), 256, 0, stream>>>(cbuf, Wqt, bq, qbuf, B, 128, 384);
  k_fused<<<B, 128, 0, stream>>>(vvec, qbuf, hmat, hbias, logits);
  k_bn<<<128, B, 0, stream>>>(logits, gamma, beta, out, B);
}

// Round 10
// 499.403 us; speedup vs baseline: 5.8640x; 1.1100x over previous
//
#include <hip/hip_runtime.h>
#include <hip/hip_bf16.h>
#include <math.h>

#define CDIV(a,b) (((a)+(b)-1)/(b))

typedef __attribute__((ext_vector_type(8))) short short8v;   // 8 bf16
typedef __attribute__((ext_vector_type(4))) float f32x4;

__device__ inline float bf2lo(unsigned u) { return __uint_as_float(u << 16); }
__device__ inline float bf2hi(unsigned u) { return __uint_as_float(u & 0xffff0000u); }
__device__ inline float leaky(float v) { return v > 0.f ? v : 0.2f * v; }
__device__ inline float rlanef(float p, int j) {
  return __int_as_float(__builtin_amdgcn_readlane(__float_as_int(p), j));
}

// ---------------- weight transposes + buffer zeroing in one launch ----------------
__global__ void k_prep(const float* __restrict__ W1, __hip_bfloat16* __restrict__ W1t,
                       const float* __restrict__ Wl1, __hip_bfloat16* __restrict__ Wl1t,
                       const float* __restrict__ W2, __hip_bfloat16* __restrict__ W2t,
                       const float* __restrict__ Wl2, __hip_bfloat16* __restrict__ Wl2t,
                       const float* __restrict__ Wc, float* __restrict__ Wct,
                       const float* __restrict__ Wq, float* __restrict__ Wqt,
                       float* __restrict__ colsum, int* __restrict__ degz, int N) {
  int i = blockIdx.x * 256 + threadIdx.x;
  const int n1 = 128 * 512, n2 = 512 * 128, n3 = 128 * 640, n4 = 640 * 128;
  const int n5 = 954 * 128, n6 = 128 * 384;
  if (i < n1) { int m = i / 128, k = i % 128; W1t[i] = __float2bfloat16(W1[(size_t)k * 512 + m]); return; }
  i -= n1;
  if (i < n2) { int m = i / 512, k = i % 512; Wl1t[i] = __float2bfloat16(Wl1[(size_t)k * 128 + m]); return; }
  i -= n2;
  if (i < n3) { int m = i / 128, k = i % 128; W2t[i] = __float2bfloat16(W2[(size_t)k * 640 + m]); return; }
  i -= n3;
  if (i < n4) { int m = i / 640, k = i % 640; Wl2t[i] = __float2bfloat16(Wl2[(size_t)k * 128 + m]); return; }
  i -= n4;
  if (i < n5) { int m = i / 954, k = i % 954; Wct[i] = Wc[(size_t)k * 128 + m]; return; }
  i -= n5;
  if (i < n6) { int m = i / 128, k = i % 128; Wqt[i] = Wq[(size_t)k * 384 + m]; return; }
  i -= n6;
  if (i < 128) { colsum[i] = 0.f; return; }
  i -= 128;
  if (i < 2 * N) { degz[i] = 0; return; }   // degb and cursor are contiguous
}

// ---------------- x = triplets(float) @ Wd + bd  (bf16 out) ----------------
__global__ void k_drug(const int* __restrict__ trip, const float* __restrict__ Wd,
                       const float* __restrict__ bd, __hip_bfloat16* __restrict__ x, int N) {
  int i = blockIdx.x * 256 + threadIdx.x;
  if (i >= N * 128) return;
  int n = i >> 7, c = i & 127;
  const int* t = trip + n * 4;
  float acc = bd[c];
  acc += (float)t[0] * Wd[c] + (float)t[1] * Wd[128 + c] +
         (float)t[2] * Wd[256 + c] + (float)t[3] * Wd[384 + c];
  x[i] = __float2bfloat16(acc);
}

// ---------------- bf16 MFMA GEMM: head-major planed output -----------------------
// optional fused column-sum (valid only for M=128 outputs)
template <bool BIAS, bool COLSUM>
__global__ void k_gemm_mfma(const __hip_bfloat16* __restrict__ A,
                            const __hip_bfloat16* __restrict__ Bt,
                            const float* __restrict__ bias,
                            __hip_bfloat16* __restrict__ Cb,
                            float* __restrict__ colsum,
                            int Nr, int K, int M) {
  __shared__ short As[64 * 40];
  __shared__ short Bs[64 * 40];
  int tid = threadIdx.x;
  int lane = tid & 63, wid = tid >> 6;
  int wr = wid >> 1, wc = wid & 1;
  int lrow = lane & 15;
  int row0 = blockIdx.y * 64, col0 = blockIdx.x * 64;

  int arow = tid >> 2, akc = tid & 3;
  int grow = row0 + arow; if (grow >= Nr) grow = Nr - 1;
  const __hip_bfloat16* agp = A + (size_t)grow * K + akc * 8;
  const __hip_bfloat16* bgp = Bt + (size_t)(col0 + arow) * K + akc * 8;
  short* asp = &As[arow * 40 + akc * 8];
  short* bsp = &Bs[arow * 40 + akc * 8];

  f32x4 acc00 = {0.f,0.f,0.f,0.f}, acc01 = acc00, acc10 = acc00, acc11 = acc00;

  int lkc = lane >> 4;
  const short* a0p = &As[(wr * 32 + lrow) * 40 + lkc * 8];
  const short* a1p = &As[(wr * 32 + 16 + lrow) * 40 + lkc * 8];
  const short* b0p = &Bs[(wc * 32 + lrow) * 40 + lkc * 8];
  const short* b1p = &Bs[(wc * 32 + 16 + lrow) * 40 + lkc * 8];

  for (int k0 = 0; k0 < K; k0 += 32) {
    short8v av = *(const short8v*)(agp + k0);
    short8v bv = *(const short8v*)(bgp + k0);
    __syncthreads();
    *(short8v*)asp = av;
    *(short8v*)bsp = bv;
    __syncthreads();
    short8v a0 = *(const short8v*)a0p;
    short8v a1 = *(const short8v*)a1p;
    short8v b0 = *(const short8v*)b0p;
    short8v b1 = *(const short8v*)b1p;
    acc00 = __builtin_amdgcn_mfma_f32_16x16x32_bf16(a0, b0, acc00, 0, 0, 0);
    acc01 = __builtin_amdgcn_mfma_f32_16x16x32_bf16(a0, b1, acc01, 0, 0, 0);
    acc10 = __builtin_amdgcn_mfma_f32_16x16x32_bf16(a1, b0, acc10, 0, 0, 0);
    acc11 = __builtin_amdgcn_mfma_f32_16x16x32_bf16(a1, b1, acc11, 0, 0, 0);
  }

  // C/D layout (m89): col = lane&15, row = (lane>>4)*4 + r
  int rbase = row0 + wr * 32 + (lane >> 4) * 4;
  int cbase = col0 + wc * 32 + lrow;
  float part0 = 0.f, part1 = 0.f;   // column partial sums (n=0, n=1)
#pragma unroll
  for (int m = 0; m < 2; ++m) {
#pragma unroll
    for (int n = 0; n < 2; ++n) {
      f32x4 acc = m == 0 ? (n == 0 ? acc00 : acc01) : (n == 0 ? acc10 : acc11);
      int col = cbase + n * 16;
      int plane = col >> 7, ch = col & 127;
      float bv = BIAS ? bias[col] : 0.f;
      __hip_bfloat16* cp = Cb + (size_t)plane * Nr * 128 + ch;
#pragma unroll
      for (int r = 0; r < 4; ++r) {
        int grow2 = rbase + m * 16 + r;
        if (grow2 >= Nr) continue;
        float v = acc[r] + bv;
        cp[(size_t)grow2 * 128] = __float2bfloat16(v);
        if (COLSUM) { if (n == 0) part0 += v; else part1 += v; }
      }
    }
  }
  if (COLSUM) {
    // reduce across the 4 lanes sharing the same lrow (lane ^ 16, ^ 32)
    part0 += __shfl_xor(part0, 16); part0 += __shfl_xor(part0, 32);
    part1 += __shfl_xor(part1, 16); part1 += __shfl_xor(part1, 32);
    if (lane < 16) {
      atomicAdd(&colsum[cbase], part0);
      atomicAdd(&colsum[cbase + 16], part1);
    }
  }
}

// ---------------- wave-per-output GEMM: C = relu(A @ Bt^T + bias) ----------------
__global__ void k_dotmm(const float* __restrict__ A, const float* __restrict__ Bt,
                        const float* __restrict__ bias, float* __restrict__ C,
                        int Nr, int K, int M) {
  int wid = (blockIdx.x * blockDim.x + threadIdx.x) >> 6;
  int lane = threadIdx.x & 63;
  if (wid >= Nr * M) return;
  int b = wid / M, m = wid % M;
  const float* ar = A + (size_t)b * K;
  const float* br = Bt + (size_t)m * K;
  float acc = 0.f;
  for (int k = lane * 2; k + 1 < K; k += 128) {
    float2 av = *(const float2*)(ar + k);
    float2 bv = *(const float2*)(br + k);
    acc += av.x * bv.x + av.y * bv.y;
  }
#pragma unroll
  for (int off = 32; off; off >>= 1) acc += __shfl_xor(acc, off);
  if (lane == 0) C[wid] = fmaxf(acc + bias[m], 0.f);
}

// ---------------- es/ed per (node, head), head-major xh [H][N][128] ----------------
__global__ void k_coef(const __hip_bfloat16* __restrict__ xh, const float* __restrict__ as_,
                       const float* __restrict__ ad_, float* __restrict__ es,
                       float* __restrict__ ed, int N, int H) {
  int wid = (blockIdx.x * blockDim.x + threadIdx.x) >> 6;
  int lane = threadIdx.x & 63;
  if (wid >= N * H) return;
  int h = wid / N, n = wid - h * N;
  const __hip_bfloat162* xp = (const __hip_bfloat162*)xh + (size_t)h * N * 64 + (size_t)n * 64;
  __hip_bfloat162 xv = xp[lane];
  float x0 = __bfloat162float(xv.x), x1 = __bfloat162float(xv.y);
  float2 a = ((const float2*)(as_ + h * 128))[lane];
  float2 d = ((const float2*)(ad_ + h * 128))[lane];
  float e1 = x0 * a.x + x1 * a.y;
  float e2 = x0 * d.x + x1 * d.y;
#pragma unroll
  for (int off = 32; off; off >>= 1) {
    e1 += __shfl_xor(e1, off);
    e2 += __shfl_xor(e2, off);
  }
  if (lane == 0) { es[(size_t)h * N + n] = e1; ed[(size_t)h * N + n] = e2; }
}

// ---------------- CSR build ----------------
__global__ void k_deg(const int* __restrict__ src0, const int* __restrict__ dst0,
                      int* __restrict__ deg, int E) {
  int e = blockIdx.x * 256 + threadIdx.x;
  if (e >= E) return;
  int s = src0[e], d = dst0[e];
  if (s != d) atomicAdd(&deg[d], 1);
}

__global__ void k_scan(const int* __restrict__ deg, int* __restrict__ rowptr, int N) {
  __shared__ int part[1024];
  int t = threadIdx.x;
  int chunk = (N + 1023) >> 10;
  int b0 = t * chunk, b1 = min(N, b0 + chunk);
  int s = 0;
  for (int i = b0; i < b1; i++) s += deg[i];
  part[t] = s;
  __syncthreads();
  for (int off = 1; off < 1024; off <<= 1) {
    int v = (t >= off) ? part[t - off] : 0;
    __syncthreads();
    part[t] += v;
    __syncthreads();
  }
  int run = (t == 0) ? 0 : part[t - 1];
  for (int i = b0; i < b1; i++) { rowptr[i] = run; run += deg[i]; }
  if (b1 == N) rowptr[N] = run;
}

__global__ void k_fill_adj(const int* __restrict__ src0, const int* __restrict__ dst0,
                           const int* __restrict__ rowptr, int* __restrict__ cursor,
                           int* __restrict__ adj, int E) {
  int e = blockIdx.x * 256 + threadIdx.x;
  if (e >= E) return;
  int s = src0[e], d = dst0[e];
  if (s != d) {
    int pos = rowptr[d] + atomicAdd(&cursor[d], 1);
    adj[pos] = s;
  }
}

// 8-edge broadcast accumulate: uniform row per edge (readlane -> SGPR -> saddr load).
// requires lanes with index >= valid count to carry s==0, p==0.
__device__ __forceinline__ void acc8(const char* xbase, int loff, int s, float p, int j,
                                     float& a0, float& a1) {
  int s0 = __builtin_amdgcn_readlane(s, j);
  int s1 = __builtin_amdgcn_readlane(s, j + 1);
  int s2 = __builtin_amdgcn_readlane(s, j + 2);
  int s3 = __builtin_amdgcn_readlane(s, j + 3);
  int s4 = __builtin_amdgcn_readlane(s, j + 4);
  int s5 = __builtin_amdgcn_readlane(s, j + 5);
  int s6 = __builtin_amdgcn_readlane(s, j + 6);
  int s7 = __builtin_amdgcn_readlane(s, j + 7);
  unsigned u0 = *(const unsigned*)(xbase + (size_t)s0 * 256 + loff);
  unsigned u1 = *(const unsigned*)(xbase + (size_t)s1 * 256 + loff);
  unsigned u2 = *(const unsigned*)(xbase + (size_t)s2 * 256 + loff);
  unsigned u3 = *(const unsigned*)(xbase + (size_t)s3 * 256 + loff);
  unsigned u4 = *(const unsigned*)(xbase + (size_t)s4 * 256 + loff);
  unsigned u5 = *(const unsigned*)(xbase + (size_t)s5 * 256 + loff);
  unsigned u6 = *(const unsigned*)(xbase + (size_t)s6 * 256 + loff);
  unsigned u7 = *(const unsigned*)(xbase + (size_t)s7 * 256 + loff);
  float p0 = rlanef(p, j),     p1 = rlanef(p, j + 1);
  float p2 = rlanef(p, j + 2), p3 = rlanef(p, j + 3);
  float p4 = rlanef(p, j + 4), p5 = rlanef(p, j + 5);
  float p6 = rlanef(p, j + 6), p7 = rlanef(p, j + 7);
  a0 += p0 * bf2lo(u0); a1 += p0 * bf2hi(u0);
  a0 += p1 * bf2lo(u1); a1 += p1 * bf2hi(u1);
  a0 += p2 * bf2lo(u2); a1 += p2 * bf2hi(u2);
  a0 += p3 * bf2lo(u3); a1 += p3 * bf2hi(u3);
  a0 += p4 * bf2lo(u4); a1 += p4 * bf2hi(u4);
  a0 += p5 * bf2lo(u5); a1 += p5 * bf2hi(u5);
  a0 += p6 * bf2lo(u6); a1 += p6 * bf2hi(u6);
  a0 += p7 * bf2lo(u7); a1 += p7 * bf2hi(u7);
}

// ---------------- fused GAT aggregation: one wave per (node, head), head-major xh ----------
__global__ void k_gat_gather(const int* __restrict__ rowptr, const int* __restrict__ adj,
                             const float* __restrict__ es, const float* __restrict__ ed,
                             const __hip_bfloat16* __restrict__ xh,
                             const float* __restrict__ bias,
                             __hip_bfloat16* __restrict__ gout, int N, int H) {
  // XCD-aware block swizzle (bijective when grid % 8 == 0)
  int nb = gridDim.x, bx = blockIdx.x;
  int sb = ((nb & 7) == 0) ? ((bx & 7) * (nb >> 3) + (bx >> 3)) : bx;
  int wid = sb * 4 + (threadIdx.x >> 6);
  int lane = threadIdx.x & 63;
  if (wid >= N * H) return;
  int h = wid / N, n = wid - h * N;
  int base = rowptr[n];
  int deg = rowptr[n + 1] - base;
  const float* esh = es + (size_t)h * N;
  float edn = ed[(size_t)h * N + n];
  float vself = leaky(esh[n] + edn);
  const char* xbase = (const char*)xh + (size_t)h * N * 256;   // head plane, bytes
  int loff = lane * 4;                                         // channels 2*lane, 2*lane+1

  float a0 = 0.f, a1 = 0.f;
  float psum = 0.f, pself, m;

  if (deg <= 64) {
    // fast path: single fused pass (covers nearly all nodes at avg degree 25)
    int s = 0; float v = -3e38f;
    if (lane < deg) { s = adj[base + lane]; v = leaky(esh[s] + edn); }
    m = fmaxf(vself, v);
#pragma unroll
    for (int off = 32; off; off >>= 1) m = fmaxf(m, __shfl_xor(m, off));
    float p = (lane < deg) ? __expf(v - m) : 0.f;
    pself = __expf(vself - m);
    psum = p;
    for (int j = 0; j < deg; j += 8) acc8(xbase, loff, s, p, j, a0, a1);
  } else {
    m = vself;
    for (int i = lane; i < deg; i += 64) {
      int s = adj[base + i];
      m = fmaxf(m, leaky(esh[s] + edn));
    }
#pragma unroll
    for (int off = 32; off; off >>= 1) m = fmaxf(m, __shfl_xor(m, off));
    pself = __expf(vself - m);
    for (int c = 0; c < deg; c += 64) {
      int i = c + lane;
      int s = 0; float p = 0.f;
      if (i < deg) {
        s = adj[base + i];
        p = __expf(leaky(esh[s] + edn) - m);
        psum += p;
      }
      int cnt = min(64, deg - c);
      for (int j = 0; j < cnt; j += 8) acc8(xbase, loff, s, p, j, a0, a1);
    }
  }

  // self-loop contribution
  {
    unsigned u = *(const unsigned*)(xbase + (size_t)n * 256 + loff);
    a0 += pself * bf2lo(u);
    a1 += pself * bf2hi(u);
  }
#pragma unroll
  for (int off = 32; off; off >>= 1) psum += __shfl_xor(psum, off);
  psum += pself;
  float inv = 1.f / psum;
  float2 bv = ((const float2*)(bias + h * 128))[lane];
  float o0 = a0 * inv + bv.x;
  float o1 = a1 * inv + bv.y;
  o0 = o0 > 0.f ? o0 : expm1f(o0);
  o1 = o1 > 0.f ? o1 : expm1f(o1);
  __hip_bfloat162 r;
  r.x = __float2bfloat16(o0);
  r.y = __float2bfloat16(o1);
  ((__hip_bfloat162*)(gout + (size_t)n * (H * 128) + h * 128))[lane] = r;  // row-major out
}

// single block head MLP -> vvec[384]
__global__ void k_head(const float* __restrict__ colsum, const float* __restrict__ Wfc,
                       const float* __restrict__ bfc, const float* __restrict__ Whg,
                       const float* __restrict__ bhg, const float* __restrict__ Wv,
                       const float* __restrict__ bv, float* __restrict__ vvec, float invN) {
  __shared__ float h[128], t1[256], hg[128];
  int t = threadIdx.x;  // 256
  if (t < 128) h[t] = colsum[t] * invN;
  __syncthreads();
  float acc = bfc[t];
  for (int k = 0; k < 128; k++) acc += h[k] * Wfc[k * 256 + t];
  t1[t] = fmaxf(acc, 0.f);
  __syncthreads();
  if (t < 128) {
    float a2 = bhg[t];
    for (int k = 0; k < 256; k++) a2 += t1[k] * Whg[k * 128 + t];
    hg[t] = a2;
  }
  __syncthreads();
  for (int j = t; j < 384; j += 256) {
    float a3 = bv[j];
    for (int k = 0; k < 128; k++) a3 += hg[k] * Wv[k * 384 + j];
    vvec[j] = fmaxf(a3, 0.f);
  }
}

// per-batch-row BAN tail
__global__ void k_fused(const float* __restrict__ vvec, const float* __restrict__ q,
                        const float* __restrict__ hmat, const float* __restrict__ hbias,
                        float* __restrict__ logits) {
  int b = blockIdx.x, c = threadIdx.x;  // 128 threads
  __shared__ float red[128];
  float t[3];
  float part = 0.f;
#pragma unroll
  for (int j = 0; j < 3; j++) {
    int k = c * 3 + j;
    float hs = hmat[k] + hmat[384 + k] + hmat[768 + k] + hmat[1152 + k];
    t[j] = vvec[k] * q[(size_t)b * 384 + k];
    part += hs * t[j];
  }
  red[c] = part;
  __syncthreads();
  for (int s = 64; s > 0; s >>= 1) {
    if (c < s) red[c] += red[c + s];
    __syncthreads();
  }
  float attsum = red[0] + (hbias[0] + hbias[1] + hbias[2] + hbias[3]);
  logits[(size_t)b * 128 + c] = attsum * (t[0] + t[1] + t[2]);
}

// batchnorm over batch dim (biased var), one block per channel c
__global__ void k_bn(const float* __restrict__ logits, const float* __restrict__ gamma,
                     const float* __restrict__ beta, float* __restrict__ out, int B) {
  int c = blockIdx.x, b = threadIdx.x;  // B threads
  __shared__ float s1[256], s2[256];
  float v = logits[(size_t)b * 128 + c];
  s1[b] = v; s2[b] = v * v;
  __syncthreads();
  for (int s = B / 2; s > 0; s >>= 1) {
    if (b < s) { s1[b] += s1[b + s]; s2[b] += s2[b + s]; }
    __syncthreads();
  }
  float mu = s1[0] / B;
  float var = s2[0] / B - mu * mu;
  out[(size_t)b * 128 + c] = (v - mu) * rsqrtf(var + 1e-5f) * gamma[c] + beta[c];
}

extern "C" void kernel_launch(void* const* d_in, const int* in_sizes, int n_in,
                              void* d_out, int out_size, void* d_ws, size_t ws_size,
                              hipStream_t stream) {
  const float* cell = (const float*)d_in[0];
  const float* Wd   = (const float*)d_in[1];
  const float* bd   = (const float*)d_in[2];
  const float* W1   = (const float*)d_in[3];
  const float* a1s  = (const float*)d_in[4];
  const float* a1d  = (const float*)d_in[5];
  const float* b1   = (const float*)d_in[6];
  const float* Wl1  = (const float*)d_in[7];
  const float* bl1  = (const float*)d_in[8];
  const float* W2   = (const float*)d_in[9];
  const float* a2s  = (const float*)d_in[10];
  const float* a2d  = (const float*)d_in[11];
  const float* b2   = (const float*)d_in[12];
  const float* Wl2  = (const float*)d_in[13];
  const float* bl2  = (const float*)d_in[14];
  const float* Wfc  = (const float*)d_in[15];
  const float* bfc  = (const float*)d_in[16];
  const float* Whg  = (const float*)d_in[17];
  const float* bhg  = (const float*)d_in[18];
  const float* Wc   = (const float*)d_in[19];
  const float* bc   = (const float*)d_in[20];
  const float* Wv   = (const float*)d_in[21];
  const float* bv   = (const float*)d_in[22];
  const float* Wq   = (const float*)d_in[23];
  const float* bq   = (const float*)d_in[24];
  const float* hmat = (const float*)d_in[25];
  const float* hbias= (const float*)d_in[26];
  const float* gamma= (const float*)d_in[27];
  const float* beta = (const float*)d_in[28];
  const int* trip   = (const int*)d_in[29];
  const int* eidx   = (const int*)d_in[30];

  const int N = in_sizes[29] / 4;     // 20000
  const int E = in_sizes[30] / 2;     // 500000
  const int B = in_sizes[0] / 954;    // 256
  float* out = (float*)d_out;

  // ---------------- workspace layout: bf16 region first (16B aligned) ----------------
  __hip_bfloat16* xb    = (__hip_bfloat16*)d_ws;      // N*128
  __hip_bfloat16* xhb   = xb + (size_t)N * 128;       // N*640  (head-major [H][N][128])
  __hip_bfloat16* goutb = xhb + (size_t)N * 640;      // N*640  (row-major [N][H*128])
  __hip_bfloat16* h1b   = goutb + (size_t)N * 640;    // N*128
  __hip_bfloat16* h2b   = h1b + (size_t)N * 128;      // N*128
  __hip_bfloat16* W1t   = h2b + (size_t)N * 128;      // 512*128
  __hip_bfloat16* Wl1t  = W1t + 512 * 128;            // 128*512
  __hip_bfloat16* W2t   = Wl1t + 128 * 512;           // 640*128
  __hip_bfloat16* Wl2t  = W2t + 640 * 128;            // 128*640
  // f32 region
  float* es     = (float*)(Wl2t + 128 * 640);          // N*5 (head-major [H][N])
  float* ed     = es + (size_t)N * 5;                  // N*5
  float* colsum = ed + (size_t)N * 5;          // 128
  float* cbuf   = colsum + 128;                // B*128
  float* qbuf   = cbuf + (size_t)B * 128;      // B*384
  float* vvec   = qbuf + (size_t)B * 384;      // 384
  float* logits = vvec + 384;                  // B*128
  float* Wct    = logits + (size_t)B * 128;    // 128*954
  float* Wqt    = Wct + 128 * 954;             // 384*128
  // int region
  int* rowptr   = (int*)(Wqt + 384 * 128);     // N+1
  int* degb     = rowptr + (N + 1);            // N
  int* cursor   = degb + N;                    // N (contiguous after degb)
  int* adj      = cursor + N;                  // E

  const int* src0 = eidx;
  const int* dst0 = eidx + E;

  // weight transposes + zeroing of colsum/degb/cursor in one launch
  {
    int tot = 128*512 + 512*128 + 128*640 + 640*128 + 954*128 + 128*384 + 128 + 2 * N;
    k_prep<<<CDIV(tot, 256), 256, 0, stream>>>(W1, W1t, Wl1, Wl1t, W2, W2t, Wl2, Wl2t,
                                               Wc, Wct, Wq, Wqt, colsum, degb, N);
  }

  // CSR build (shared by both GAT layers)
  k_deg<<<CDIV(E, 256), 256, 0, stream>>>(src0, dst0, degb, E);
  k_scan<<<1, 1024, 0, stream>>>(degb, rowptr, N);
  k_fill_adj<<<CDIV(E, 256), 256, 0, stream>>>(src0, dst0, rowptr, cursor, adj, E);

  k_drug<<<CDIV(N * 128, 256), 256, 0, stream>>>(trip, Wd, bd, xb, N);

  // ---------------- GAT1 (H=4) ----------------
  {
    dim3 g(512 / 64, CDIV(N, 64));
    k_gemm_mfma<false, false><<<g, 256, 0, stream>>>(xb, W1t, nullptr, xhb, nullptr, N, 128, 512);
  }
  k_coef<<<CDIV(N * 4, 4), 256, 0, stream>>>(xhb, a1s, a1d, es, ed, N, 4);
  k_gat_gather<<<CDIV(N * 4, 4), 256, 0, stream>>>(rowptr, adj, es, ed, xhb, b1, goutb, N, 4);
  {
    dim3 g(128 / 64, CDIV(N, 64));
    k_gemm_mfma<true, true><<<g, 256, 0, stream>>>(goutb, Wl1t, bl1, h1b, colsum, N, 512, 128);
  }

  // ---------------- GAT2 (H=5) ----------------
  {
    dim3 g(640 / 64, CDIV(N, 64));
    k_gemm_mfma<false, false><<<g, 256, 0, stream>>>(h1b, W2t, nullptr, xhb, nullptr, N, 128, 640);
  }
  k_coef<<<CDIV(N * 5, 4), 256, 0, stream>>>(xhb, a2s, a2d, es, ed, N, 5);
  k_gat_gather<<<CDIV(N * 5, 4), 256, 0, stream>>>(rowptr, adj, es, ed, xhb, b2, goutb, N, 5);
  {
    dim3 g(128 / 64, CDIV(N, 64));
    k_gemm_mfma<true, true><<<g, 256, 0, stream>>>(goutb, Wl2t, bl2, h2b, colsum, N, 640, 128);
  }

  // ---------------- head + BAN + BN ----------------
  k_head<<<1, 256, 0, stream>>>(colsum, Wfc, bfc, Whg, bhg, Wv, bv, vvec, 1.0f / N);
  k_dotmm<<<CDIV(B * 128, 4), 256, 0, stream>>>(cell, Wct, bc, cbuf, B, 954, 128);
  k_dotmm<<<CDIV(B * 384, 4), 256, 0, stream>>>(cbuf, Wqt, bq, qbuf, B, 128, 384);
  k_fused<<<B, 128, 0, stream>>>(vvec, qbuf, hmat, hbias, logits);
  k_bn<<<128, B, 0, stream>>>(logits, gamma, beta, out, B);
}

// Round 11
// 483.638 us; speedup vs baseline: 6.0551x; 1.0326x over previous
//
#include <hip/hip_runtime.h>
#include <hip/hip_bf16.h>
#include <math.h>

#define CDIV(a,b) (((a)+(b)-1)/(b))

typedef __attribute__((ext_vector_type(8))) short short8v;   // 8 bf16
typedef __attribute__((ext_vector_type(4))) float f32x4;

__device__ inline float bf2lo(unsigned u) { return __uint_as_float(u << 16); }
__device__ inline float bf2hi(unsigned u) { return __uint_as_float(u & 0xffff0000u); }
__device__ inline float leaky(float v) { return v > 0.f ? v : 0.2f * v; }

// ---------------- weight transposes + buffer zeroing in one launch ----------------
__global__ void k_prep(const float* __restrict__ W1, __hip_bfloat16* __restrict__ W1t,
                       const float* __restrict__ Wl1, __hip_bfloat16* __restrict__ Wl1t,
                       const float* __restrict__ W2, __hip_bfloat16* __restrict__ W2t,
                       const float* __restrict__ Wl2, __hip_bfloat16* __restrict__ Wl2t,
                       const float* __restrict__ Wc, float* __restrict__ Wct,
                       const float* __restrict__ Wq, float* __restrict__ Wqt,
                       float* __restrict__ colsum, int* __restrict__ degz, int N) {
  int i = blockIdx.x * 256 + threadIdx.x;
  const int n1 = 128 * 512, n2 = 512 * 128, n3 = 128 * 640, n4 = 640 * 128;
  const int n5 = 954 * 128, n6 = 128 * 384;
  if (i < n1) { int m = i / 128, k = i % 128; W1t[i] = __float2bfloat16(W1[(size_t)k * 512 + m]); return; }
  i -= n1;
  if (i < n2) { int m = i / 512, k = i % 512; Wl1t[i] = __float2bfloat16(Wl1[(size_t)k * 128 + m]); return; }
  i -= n2;
  if (i < n3) { int m = i / 128, k = i % 128; W2t[i] = __float2bfloat16(W2[(size_t)k * 640 + m]); return; }
  i -= n3;
  if (i < n4) { int m = i / 640, k = i % 640; Wl2t[i] = __float2bfloat16(Wl2[(size_t)k * 128 + m]); return; }
  i -= n4;
  if (i < n5) { int m = i / 954, k = i % 954; Wct[i] = Wc[(size_t)k * 128 + m]; return; }
  i -= n5;
  if (i < n6) { int m = i / 128, k = i % 128; Wqt[i] = Wq[(size_t)k * 384 + m]; return; }
  i -= n6;
  if (i < 128) { colsum[i] = 0.f; return; }
  i -= 128;
  if (i < 2 * N) { degz[i] = 0; return; }   // degb and cursor are contiguous
}

// ---------------- fused: degree count (first E threads) + drug linear (rest) ----------
__global__ void k_degdrug(const int* __restrict__ src0, const int* __restrict__ dst0,
                          int* __restrict__ deg, int E,
                          const int* __restrict__ trip, const float* __restrict__ Wd,
                          const float* __restrict__ bd, __hip_bfloat16* __restrict__ x,
                          int N) {
  int i = blockIdx.x * 256 + threadIdx.x;
  if (i < E) {
    int s = src0[i], d = dst0[i];
    if (s != d) atomicAdd(&deg[d], 1);
    return;
  }
  i -= E;
  if (i >= N * 128) return;
  int n = i >> 7, c = i & 127;
  const int* t = trip + n * 4;
  float acc = bd[c];
  acc += (float)t[0] * Wd[c] + (float)t[1] * Wd[128 + c] +
         (float)t[2] * Wd[256 + c] + (float)t[3] * Wd[384 + c];
  x[i] = __float2bfloat16(acc);
}

// ---------------- bf16 MFMA GEMM: head-major planed output -----------------------
// optional fused column-sum (valid only for M=128 outputs)
template <bool BIAS, bool COLSUM>
__global__ void k_gemm_mfma(const __hip_bfloat16* __restrict__ A,
                            const __hip_bfloat16* __restrict__ Bt,
                            const float* __restrict__ bias,
                            __hip_bfloat16* __restrict__ Cb,
                            float* __restrict__ colsum,
                            int Nr, int K, int M) {
  __shared__ short As[64 * 40];
  __shared__ short Bs[64 * 40];
  int tid = threadIdx.x;
  int lane = tid & 63, wid = tid >> 6;
  int wr = wid >> 1, wc = wid & 1;
  int lrow = lane & 15;
  int row0 = blockIdx.y * 64, col0 = blockIdx.x * 64;

  int arow = tid >> 2, akc = tid & 3;
  int grow = row0 + arow; if (grow >= Nr) grow = Nr - 1;
  const __hip_bfloat16* agp = A + (size_t)grow * K + akc * 8;
  const __hip_bfloat16* bgp = Bt + (size_t)(col0 + arow) * K + akc * 8;
  short* asp = &As[arow * 40 + akc * 8];
  short* bsp = &Bs[arow * 40 + akc * 8];

  f32x4 acc00 = {0.f,0.f,0.f,0.f}, acc01 = acc00, acc10 = acc00, acc11 = acc00;

  int lkc = lane >> 4;
  const short* a0p = &As[(wr * 32 + lrow) * 40 + lkc * 8];
  const short* a1p = &As[(wr * 32 + 16 + lrow) * 40 + lkc * 8];
  const short* b0p = &Bs[(wc * 32 + lrow) * 40 + lkc * 8];
  const short* b1p = &Bs[(wc * 32 + 16 + lrow) * 40 + lkc * 8];

  for (int k0 = 0; k0 < K; k0 += 32) {
    short8v av = *(const short8v*)(agp + k0);
    short8v bv = *(const short8v*)(bgp + k0);
    __syncthreads();
    *(short8v*)asp = av;
    *(short8v*)bsp = bv;
    __syncthreads();
    short8v a0 = *(const short8v*)a0p;
    short8v a1 = *(const short8v*)a1p;
    short8v b0 = *(const short8v*)b0p;
    short8v b1 = *(const short8v*)b1p;
    acc00 = __builtin_amdgcn_mfma_f32_16x16x32_bf16(a0, b0, acc00, 0, 0, 0);
    acc01 = __builtin_amdgcn_mfma_f32_16x16x32_bf16(a0, b1, acc01, 0, 0, 0);
    acc10 = __builtin_amdgcn_mfma_f32_16x16x32_bf16(a1, b0, acc10, 0, 0, 0);
    acc11 = __builtin_amdgcn_mfma_f32_16x16x32_bf16(a1, b1, acc11, 0, 0, 0);
  }

  // C/D layout (m89): col = lane&15, row = (lane>>4)*4 + r
  int rbase = row0 + wr * 32 + (lane >> 4) * 4;
  int cbase = col0 + wc * 32 + lrow;
  float part0 = 0.f, part1 = 0.f;   // column partial sums (n=0, n=1)
#pragma unroll
  for (int m = 0; m < 2; ++m) {
#pragma unroll
    for (int n = 0; n < 2; ++n) {
      f32x4 acc = m == 0 ? (n == 0 ? acc00 : acc01) : (n == 0 ? acc10 : acc11);
      int col = cbase + n * 16;
      int plane = col >> 7, ch = col & 127;
      float bv = BIAS ? bias[col] : 0.f;
      __hip_bfloat16* cp = Cb + (size_t)plane * Nr * 128 + ch;
#pragma unroll
      for (int r = 0; r < 4; ++r) {
        int grow2 = rbase + m * 16 + r;
        if (grow2 >= Nr) continue;
        float v = acc[r] + bv;
        cp[(size_t)grow2 * 128] = __float2bfloat16(v);
        if (COLSUM) { if (n == 0) part0 += v; else part1 += v; }
      }
    }
  }
  if (COLSUM) {
    part0 += __shfl_xor(part0, 16); part0 += __shfl_xor(part0, 32);
    part1 += __shfl_xor(part1, 16); part1 += __shfl_xor(part1, 32);
    if (lane < 16) {
      atomicAdd(&colsum[cbase], part0);
      atomicAdd(&colsum[cbase + 16], part1);
    }
  }
}

// ---------------- wave-per-output GEMM: C = relu(A @ Bt^T + bias) ----------------
__global__ void k_dotmm(const float* __restrict__ A, const float* __restrict__ Bt,
                        const float* __restrict__ bias, float* __restrict__ C,
                        int Nr, int K, int M) {
  int wid = (blockIdx.x * blockDim.x + threadIdx.x) >> 6;
  int lane = threadIdx.x & 63;
  if (wid >= Nr * M) return;
  int b = wid / M, m = wid % M;
  const float* ar = A + (size_t)b * K;
  const float* br = Bt + (size_t)m * K;
  float acc = 0.f;
  for (int k = lane * 2; k + 1 < K; k += 128) {
    float2 av = *(const float2*)(ar + k);
    float2 bv = *(const float2*)(br + k);
    acc += av.x * bv.x + av.y * bv.y;
  }
#pragma unroll
  for (int off = 32; off; off >>= 1) acc += __shfl_xor(acc, off);
  if (lane == 0) C[wid] = fmaxf(acc + bias[m], 0.f);
}

// ---------------- es/ed per (node, head), head-major xh [H][N][128], 2D grid ------
__global__ void k_coef(const __hip_bfloat16* __restrict__ xh, const float* __restrict__ as_,
                       const float* __restrict__ ad_, float* __restrict__ es,
                       float* __restrict__ ed, int N) {
  int h = blockIdx.y;
  int n = blockIdx.x * 4 + (threadIdx.x >> 6);
  int lane = threadIdx.x & 63;
  if (n >= N) return;
  const __hip_bfloat162* xp = (const __hip_bfloat162*)xh + ((size_t)h * N + n) * 64;
  __hip_bfloat162 xv = xp[lane];
  float x0 = __bfloat162float(xv.x), x1 = __bfloat162float(xv.y);
  float2 a = ((const float2*)(as_ + h * 128))[lane];
  float2 d = ((const float2*)(ad_ + h * 128))[lane];
  float e1 = x0 * a.x + x1 * a.y;
  float e2 = x0 * d.x + x1 * d.y;
#pragma unroll
  for (int off = 32; off; off >>= 1) {
    e1 += __shfl_xor(e1, off);
    e2 += __shfl_xor(e2, off);
  }
  if (lane == 0) { es[(size_t)h * N + n] = e1; ed[(size_t)h * N + n] = e2; }
}

// ---------------- CSR build ----------------
__global__ void k_scan(const int* __restrict__ deg, int* __restrict__ rowptr, int N) {
  __shared__ int part[1024];
  int t = threadIdx.x;
  int chunk = (N + 1023) >> 10;
  int b0 = t * chunk, b1 = min(N, b0 + chunk);
  int s = 0;
  for (int i = b0; i < b1; i++) s += deg[i];
  part[t] = s;
  __syncthreads();
  for (int off = 1; off < 1024; off <<= 1) {
    int v = (t >= off) ? part[t - off] : 0;
    __syncthreads();
    part[t] += v;
    __syncthreads();
  }
  int run = (t == 0) ? 0 : part[t - 1];
  for (int i = b0; i < b1; i++) { rowptr[i] = run; run += deg[i]; }
  if (b1 == N) rowptr[N] = run;
}

__global__ void k_fill_adj(const int* __restrict__ src0, const int* __restrict__ dst0,
                           const int* __restrict__ rowptr, int* __restrict__ cursor,
                           int* __restrict__ adj, int E) {
  int e = blockIdx.x * 256 + threadIdx.x;
  if (e >= E) return;
  int s = src0[e], d = dst0[e];
  if (s != d) {
    int pos = rowptr[d] + atomicAdd(&cursor[d], 1);
    adj[pos] = s;
  }
}

// 8-edge broadcast accumulate with (s,p) PACKED per lane:
//   pk = (bf16bits(p) << 16) | s,  requires s < 32768 and p >= 0.
// readlane -> SGPR; s-extract and p-extract are SALU; FMA takes p as SGPR operand.
// lanes with index >= valid count must carry pk == 0 (p=0, s=0).
__device__ __forceinline__ void acc8p(const char* xbase, int loff, unsigned pk, int j,
                                      float& a0, float& a1) {
  unsigned k0 = __builtin_amdgcn_readlane(pk, j);
  unsigned k1 = __builtin_amdgcn_readlane(pk, j + 1);
  unsigned k2 = __builtin_amdgcn_readlane(pk, j + 2);
  unsigned k3 = __builtin_amdgcn_readlane(pk, j + 3);
  unsigned k4 = __builtin_amdgcn_readlane(pk, j + 4);
  unsigned k5 = __builtin_amdgcn_readlane(pk, j + 5);
  unsigned k6 = __builtin_amdgcn_readlane(pk, j + 6);
  unsigned k7 = __builtin_amdgcn_readlane(pk, j + 7);
  unsigned u0 = *(const unsigned*)(xbase + (size_t)(k0 & 0x7FFFu) * 256 + loff);
  unsigned u1 = *(const unsigned*)(xbase + (size_t)(k1 & 0x7FFFu) * 256 + loff);
  unsigned u2 = *(const unsigned*)(xbase + (size_t)(k2 & 0x7FFFu) * 256 + loff);
  unsigned u3 = *(const unsigned*)(xbase + (size_t)(k3 & 0x7FFFu) * 256 + loff);
  unsigned u4 = *(const unsigned*)(xbase + (size_t)(k4 & 0x7FFFu) * 256 + loff);
  unsigned u5 = *(const unsigned*)(xbase + (size_t)(k5 & 0x7FFFu) * 256 + loff);
  unsigned u6 = *(const unsigned*)(xbase + (size_t)(k6 & 0x7FFFu) * 256 + loff);
  unsigned u7 = *(const unsigned*)(xbase + (size_t)(k7 & 0x7FFFu) * 256 + loff);
  float p0 = __uint_as_float(k0 & 0xFFFF0000u);
  float p1 = __uint_as_float(k1 & 0xFFFF0000u);
  float p2 = __uint_as_float(k2 & 0xFFFF0000u);
  float p3 = __uint_as_float(k3 & 0xFFFF0000u);
  float p4 = __uint_as_float(k4 & 0xFFFF0000u);
  float p5 = __uint_as_float(k5 & 0xFFFF0000u);
  float p6 = __uint_as_float(k6 & 0xFFFF0000u);
  float p7 = __uint_as_float(k7 & 0xFFFF0000u);
  a0 += p0 * bf2lo(u0); a1 += p0 * bf2hi(u0);
  a0 += p1 * bf2lo(u1); a1 += p1 * bf2hi(u1);
  a0 += p2 * bf2lo(u2); a1 += p2 * bf2hi(u2);
  a0 += p3 * bf2lo(u3); a1 += p3 * bf2hi(u3);
  a0 += p4 * bf2lo(u4); a1 += p4 * bf2hi(u4);
  a0 += p5 * bf2lo(u5); a1 += p5 * bf2hi(u5);
  a0 += p6 * bf2lo(u6); a1 += p6 * bf2hi(u6);
  a0 += p7 * bf2lo(u7); a1 += p7 * bf2hi(u7);
}

// ---------------- fused GAT aggregation: one wave per (node, head), 2D grid ----------
// NOTE: requires N < 32768 (15-bit packed row index); harness N = 20000.
__global__ void k_gat_gather(const int* __restrict__ rowptr, const int* __restrict__ adj,
                             const float* __restrict__ es, const float* __restrict__ ed,
                             const __hip_bfloat16* __restrict__ xh,
                             const float* __restrict__ bias,
                             __hip_bfloat16* __restrict__ gout, int N, int H) {
  // XCD-aware swizzle on x (bijective when gridDim.x % 8 == 0)
  int nb = gridDim.x, bx = blockIdx.x;
  int sb = ((nb & 7) == 0) ? ((bx & 7) * (nb >> 3) + (bx >> 3)) : bx;
  int h = blockIdx.y;
  int n = sb * 4 + (threadIdx.x >> 6);
  int lane = threadIdx.x & 63;
  if (n >= N) return;
  int base = rowptr[n];
  int deg = rowptr[n + 1] - base;
  const float* esh = es + (size_t)h * N;
  float edn = ed[(size_t)h * N + n];
  float vself = leaky(esh[n] + edn);
  const char* xbase = (const char*)xh + (size_t)h * N * 256;   // head plane, bytes
  int loff = lane * 4;                                         // channels 2*lane, 2*lane+1

  float a0 = 0.f, a1 = 0.f;
  float psum = 0.f, pself, m;

  if (deg <= 64) {
    // fast path: single fused pass
    int s = 0; float v = -3e38f;
    if (lane < deg) { s = adj[base + lane]; v = leaky(esh[s] + edn); }
    m = fmaxf(vself, v);
#pragma unroll
    for (int off = 32; off; off >>= 1) m = fmaxf(m, __shfl_xor(m, off));
    float p = (lane < deg) ? __expf(v - m) : 0.f;
    pself = __expf(vself - m);
    psum = p;
    unsigned pk = (__float_as_uint(p) & 0xFFFF0000u) | (unsigned)s;
    for (int j = 0; j < deg; j += 8) acc8p(xbase, loff, pk, j, a0, a1);
  } else {
    m = vself;
    for (int i = lane; i < deg; i += 64) {
      int s = adj[base + i];
      m = fmaxf(m, leaky(esh[s] + edn));
    }
#pragma unroll
    for (int off = 32; off; off >>= 1) m = fmaxf(m, __shfl_xor(m, off));
    pself = __expf(vself - m);
    for (int c = 0; c < deg; c += 64) {
      int i = c + lane;
      int s = 0; float p = 0.f;
      if (i < deg) {
        s = adj[base + i];
        p = __expf(leaky(esh[s] + edn) - m);
        psum += p;
      }
      unsigned pk = (__float_as_uint(p) & 0xFFFF0000u) | (unsigned)s;
      int cnt = min(64, deg - c);
      for (int j = 0; j < cnt; j += 8) acc8p(xbase, loff, pk, j, a0, a1);
    }
  }

  // self-loop contribution (full-precision pself)
  {
    unsigned u = *(const unsigned*)(xbase + (size_t)n * 256 + loff);
    a0 += pself * bf2lo(u);
    a1 += pself * bf2hi(u);
  }
#pragma unroll
  for (int off = 32; off; off >>= 1) psum += __shfl_xor(psum, off);
  psum += pself;
  float inv = 1.f / psum;
  float2 bv = ((const float2*)(bias + h * 128))[lane];
  float o0 = a0 * inv + bv.x;
  float o1 = a1 * inv + bv.y;
  o0 = o0 > 0.f ? o0 : __expf(o0) - 1.f;
  o1 = o1 > 0.f ? o1 : __expf(o1) - 1.f;
  __hip_bfloat162 r;
  r.x = __float2bfloat16(o0);
  r.y = __float2bfloat16(o1);
  ((__hip_bfloat162*)(gout + (size_t)n * (H * 128) + h * 128))[lane] = r;  // row-major out
}

// single block head MLP -> vvec[384]
__global__ void k_head(const float* __restrict__ colsum, const float* __restrict__ Wfc,
                       const float* __restrict__ bfc, const float* __restrict__ Whg,
                       const float* __restrict__ bhg, const float* __restrict__ Wv,
                       const float* __restrict__ bv, float* __restrict__ vvec, float invN) {
  __shared__ float h[128], t1[256], hg[128];
  int t = threadIdx.x;  // 256
  if (t < 128) h[t] = colsum[t] * invN;
  __syncthreads();
  float acc = bfc[t];
  for (int k = 0; k < 128; k++) acc += h[k] * Wfc[k * 256 + t];
  t1[t] = fmaxf(acc, 0.f);
  __syncthreads();
  if (t < 128) {
    float a2 = bhg[t];
    for (int k = 0; k < 256; k++) a2 += t1[k] * Whg[k * 128 + t];
    hg[t] = a2;
  }
  __syncthreads();
  for (int j = t; j < 384; j += 256) {
    float a3 = bv[j];
    for (int k = 0; k < 128; k++) a3 += hg[k] * Wv[k * 384 + j];
    vvec[j] = fmaxf(a3, 0.f);
  }
}

// per-batch-row BAN tail
__global__ void k_fused(const float* __restrict__ vvec, const float* __restrict__ q,
                        const float* __restrict__ hmat, const float* __restrict__ hbias,
                        float* __restrict__ logits) {
  int b = blockIdx.x, c = threadIdx.x;  // 128 threads
  __shared__ float red[128];
  float t[3];
  float part = 0.f;
#pragma unroll
  for (int j = 0; j < 3; j++) {
    int k = c * 3 + j;
    float hs = hmat[k] + hmat[384 + k] + hmat[768 + k] + hmat[1152 + k];
    t[j] = vvec[k] * q[(size_t)b * 384 + k];
    part += hs * t[j];
  }
  red[c] = part;
  __syncthreads();
  for (int s = 64; s > 0; s >>= 1) {
    if (c < s) red[c] += red[c + s];
    __syncthreads();
  }
  float attsum = red[0] + (hbias[0] + hbias[1] + hbias[2] + hbias[3]);
  logits[(size_t)b * 128 + c] = attsum * (t[0] + t[1] + t[2]);
}

// batchnorm over batch dim (biased var), one block per channel c
__global__ void k_bn(const float* __restrict__ logits, const float* __restrict__ gamma,
                     const float* __restrict__ beta, float* __restrict__ out, int B) {
  int c = blockIdx.x, b = threadIdx.x;  // B threads
  __shared__ float s1[256], s2[256];
  float v = logits[(size_t)b * 128 + c];
  s1[b] = v; s2[b] = v * v;
  __syncthreads();
  for (int s = B / 2; s > 0; s >>= 1) {
    if (b < s) { s1[b] += s1[b + s]; s2[b] += s2[b + s]; }
    __syncthreads();
  }
  float mu = s1[0] / B;
  float var = s2[0] / B - mu * mu;
  out[(size_t)b * 128 + c] = (v - mu) * rsqrtf(var + 1e-5f) * gamma[c] + beta[c];
}

extern "C" void kernel_launch(void* const* d_in, const int* in_sizes, int n_in,
                              void* d_out, int out_size, void* d_ws, size_t ws_size,
                              hipStream_t stream) {
  const float* cell = (const float*)d_in[0];
  const float* Wd   = (const float*)d_in[1];
  const float* bd   = (const float*)d_in[2];
  const float* W1   = (const float*)d_in[3];
  const float* a1s  = (const float*)d_in[4];
  const float* a1d  = (const float*)d_in[5];
  const float* b1   = (const float*)d_in[6];
  const float* Wl1  = (const float*)d_in[7];
  const float* bl1  = (const float*)d_in[8];
  const float* W2   = (const float*)d_in[9];
  const float* a2s  = (const float*)d_in[10];
  const float* a2d  = (const float*)d_in[11];
  const float* b2   = (const float*)d_in[12];
  const float* Wl2  = (const float*)d_in[13];
  const float* bl2  = (const float*)d_in[14];
  const float* Wfc  = (const float*)d_in[15];
  const float* bfc  = (const float*)d_in[16];
  const float* Whg  = (const float*)d_in[17];
  const float* bhg  = (const float*)d_in[18];
  const float* Wc   = (const float*)d_in[19];
  const float* bc   = (const float*)d_in[20];
  const float* Wv   = (const float*)d_in[21];
  const float* bv   = (const float*)d_in[22];
  const float* Wq   = (const float*)d_in[23];
  const float* bq   = (const float*)d_in[24];
  const float* hmat = (const float*)d_in[25];
  const float* hbias= (const float*)d_in[26];
  const float* gamma= (const float*)d_in[27];
  const float* beta = (const float*)d_in[28];
  const int* trip   = (const int*)d_in[29];
  const int* eidx   = (const int*)d_in[30];

  const int N = in_sizes[29] / 4;     // 20000
  const int E = in_sizes[30] / 2;     // 500000
  const int B = in_sizes[0] / 954;    // 256
  float* out = (float*)d_out;

  // ---------------- workspace layout: bf16 region first (16B aligned) ----------------
  __hip_bfloat16* xb    = (__hip_bfloat16*)d_ws;      // N*128
  __hip_bfloat16* xhb   = xb + (size_t)N * 128;       // N*640  (head-major [H][N][128])
  __hip_bfloat16* goutb = xhb + (size_t)N * 640;      // N*640  (row-major [N][H*128])
  __hip_bfloat16* h1b   = goutb + (size_t)N * 640;    // N*128
  __hip_bfloat16* h2b   = h1b + (size_t)N * 128;      // N*128
  __hip_bfloat16* W1t   = h2b + (size_t)N * 128;      // 512*128
  __hip_bfloat16* Wl1t  = W1t + 512 * 128;            // 128*512
  __hip_bfloat16* W2t   = Wl1t + 128 * 512;           // 640*128
  __hip_bfloat16* Wl2t  = W2t + 640 * 128;            // 128*640
  // f32 region
  float* es     = (float*)(Wl2t + 128 * 640);          // N*5 (head-major [H][N])
  float* ed     = es + (size_t)N * 5;                  // N*5
  float* colsum = ed + (size_t)N * 5;          // 128
  float* cbuf   = colsum + 128;                // B*128
  float* qbuf   = cbuf + (size_t)B * 128;      // B*384
  float* vvec   = qbuf + (size_t)B * 384;      // 384
  float* logits = vvec + 384;                  // B*128
  float* Wct    = logits + (size_t)B * 128;    // 128*954
  float* Wqt    = Wct + 128 * 954;             // 384*128
  // int region
  int* rowptr   = (int*)(Wqt + 384 * 128);     // N+1
  int* degb     = rowptr + (N + 1);            // N
  int* cursor   = degb + N;                    // N (contiguous after degb)
  int* adj      = cursor + N;                  // E

  const int* src0 = eidx;
  const int* dst0 = eidx + E;

  // weight transposes + zeroing of colsum/degb/cursor in one launch
  {
    int tot = 128*512 + 512*128 + 128*640 + 640*128 + 954*128 + 128*384 + 128 + 2 * N;
    k_prep<<<CDIV(tot, 256), 256, 0, stream>>>(W1, W1t, Wl1, Wl1t, W2, W2t, Wl2, Wl2t,
                                               Wc, Wct, Wq, Wqt, colsum, degb, N);
  }

  // degree count + drug linear in one dispatch
  k_degdrug<<<CDIV(E + N * 128, 256), 256, 0, stream>>>(src0, dst0, degb, E,
                                                        trip, Wd, bd, xb, N);
  k_scan<<<1, 1024, 0, stream>>>(degb, rowptr, N);
  k_fill_adj<<<CDIV(E, 256), 256, 0, stream>>>(src0, dst0, rowptr, cursor, adj, E);

  // ---------------- GAT1 (H=4) ----------------
  {
    dim3 g(512 / 64, CDIV(N, 64));
    k_gemm_mfma<false, false><<<g, 256, 0, stream>>>(xb, W1t, nullptr, xhb, nullptr, N, 128, 512);
  }
  {
    dim3 g(CDIV(N, 4), 4);
    k_coef<<<g, 256, 0, stream>>>(xhb, a1s, a1d, es, ed, N);
    k_gat_gather<<<g, 256, 0, stream>>>(rowptr, adj, es, ed, xhb, b1, goutb, N, 4);
  }
  {
    dim3 g(128 / 64, CDIV(N, 64));
    k_gemm_mfma<true, true><<<g, 256, 0, stream>>>(goutb, Wl1t, bl1, h1b, colsum, N, 512, 128);
  }

  // ---------------- GAT2 (H=5) ----------------
  {
    dim3 g(640 / 64, CDIV(N, 64));
    k_gemm_mfma<false, false><<<g, 256, 0, stream>>>(h1b, W2t, nullptr, xhb, nullptr, N, 128, 640);
  }
  {
    dim3 g(CDIV(N, 4), 5);
    k_coef<<<g, 256, 0, stream>>>(xhb, a2s, a2d, es, ed, N);
    k_gat_gather<<<g, 256, 0, stream>>>(rowptr, adj, es, ed, xhb, b2, goutb, N, 5);
  }
  {
    dim3 g(128 / 64, CDIV(N, 64));
    k_gemm_mfma<true, true><<<g, 256, 0, stream>>>(goutb, Wl2t, bl2, h2b, colsum, N, 640, 128);
  }

  // ---------------- head + BAN + BN ----------------
  k_head<<<1, 256, 0, stream>>>(colsum, Wfc, bfc, Whg, bhg, Wv, bv, vvec, 1.0f / N);
  k_dotmm<<<CDIV(B * 128, 4), 256, 0, stream>>>(cell, Wct, bc, cbuf, B, 954, 128);
  k_dotmm<<<CDIV(B * 384, 4), 256, 0, stream>>>(cbuf, Wqt, bq, qbuf, B, 128, 384);
  k_fused<<<B, 128, 0, stream>>>(vvec, qbuf, hmat, hbias, logits);
  k_bn<<<128, B, 0, stream>>>(logits, gamma, beta, out, B);
}

// Round 12
// 475.551 us; speedup vs baseline: 6.1581x; 1.0170x over previous
//
#include <hip/hip_runtime.h>
#include <hip/hip_bf16.h>
#include <math.h>

#define CDIV(a,b) (((a)+(b)-1)/(b))

typedef __attribute__((ext_vector_type(8))) short short8v;   // 8 bf16
typedef __attribute__((ext_vector_type(4))) float f32x4;

__device__ inline float bf2lo(unsigned u) { return __uint_as_float(u << 16); }
__device__ inline float bf2hi(unsigned u) { return __uint_as_float(u & 0xffff0000u); }
__device__ inline float leaky(float v) { return v > 0.f ? v : 0.2f * v; }

// ---------------- weight transposes + buffer zeroing in one launch ----------------
__global__ void k_prep(const float* __restrict__ W1, __hip_bfloat16* __restrict__ W1t,
                       const float* __restrict__ Wl1, __hip_bfloat16* __restrict__ Wl1t,
                       const float* __restrict__ W2, __hip_bfloat16* __restrict__ W2t,
                       const float* __restrict__ Wl2, __hip_bfloat16* __restrict__ Wl2t,
                       const float* __restrict__ Wc, float* __restrict__ Wct,
                       const float* __restrict__ Wq, float* __restrict__ Wqt,
                       float* __restrict__ colsum, int* __restrict__ degz,
                       float* __restrict__ esz, int N) {
  int i = blockIdx.x * 256 + threadIdx.x;
  const int n1 = 128 * 512, n2 = 512 * 128, n3 = 128 * 640, n4 = 640 * 128;
  const int n5 = 954 * 128, n6 = 128 * 384;
  if (i < n1) { int m = i / 128, k = i % 128; W1t[i] = __float2bfloat16(W1[(size_t)k * 512 + m]); return; }
  i -= n1;
  if (i < n2) { int m = i / 512, k = i % 512; Wl1t[i] = __float2bfloat16(Wl1[(size_t)k * 128 + m]); return; }
  i -= n2;
  if (i < n3) { int m = i / 128, k = i % 128; W2t[i] = __float2bfloat16(W2[(size_t)k * 640 + m]); return; }
  i -= n3;
  if (i < n4) { int m = i / 640, k = i % 640; Wl2t[i] = __float2bfloat16(Wl2[(size_t)k * 128 + m]); return; }
  i -= n4;
  if (i < n5) { int m = i / 954, k = i % 954; Wct[i] = Wc[(size_t)k * 128 + m]; return; }
  i -= n5;
  if (i < n6) { int m = i / 128, k = i % 128; Wqt[i] = Wq[(size_t)k * 384 + m]; return; }
  i -= n6;
  if (i < 128) { colsum[i] = 0.f; return; }
  i -= 128;
  if (i < 2 * N) { degz[i] = 0; return; }   // degb and cursor contiguous
  i -= 2 * N;
  if (i < 18 * N) { esz[i] = 0.f; return; } // es1(4N) ed1(4N) es2(5N) ed2(5N) contiguous
}

// ---------------- fused: degree count (first E threads) + drug linear (rest) ----------
__global__ void k_degdrug(const int* __restrict__ src0, const int* __restrict__ dst0,
                          int* __restrict__ deg, int E,
                          const int* __restrict__ trip, const float* __restrict__ Wd,
                          const float* __restrict__ bd, __hip_bfloat16* __restrict__ x,
                          int N) {
  int i = blockIdx.x * 256 + threadIdx.x;
  if (i < E) {
    int s = src0[i], d = dst0[i];
    if (s != d) atomicAdd(&deg[d], 1);
    return;
  }
  i -= E;
  if (i >= N * 128) return;
  int n = i >> 7, c = i & 127;
  const int* t = trip + n * 4;
  float acc = bd[c];
  acc += (float)t[0] * Wd[c] + (float)t[1] * Wd[128 + c] +
         (float)t[2] * Wd[256 + c] + (float)t[3] * Wd[384 + c];
  x[i] = __float2bfloat16(acc);
}

// ---------------- bf16 MFMA GEMM: head-major planed output -----------------------
// COLSUM: fused column-sum (M=128 only).  COEF: fused es/ed attention coefficients
// (atomics into head-major es/ed, requires pre-zeroed buffers).
template <bool BIAS, bool COLSUM, bool COEF>
__global__ void k_gemm_mfma(const __hip_bfloat16* __restrict__ A,
                            const __hip_bfloat16* __restrict__ Bt,
                            const float* __restrict__ bias,
                            __hip_bfloat16* __restrict__ Cb,
                            float* __restrict__ colsum,
                            const float* __restrict__ as_, const float* __restrict__ ad_,
                            float* __restrict__ es, float* __restrict__ ed,
                            int Nr, int K, int M) {
  __shared__ short As[64 * 40];
  __shared__ short Bs[64 * 40];
  int tid = threadIdx.x;
  int lane = tid & 63, wid = tid >> 6;
  int wr = wid >> 1, wc = wid & 1;
  int lrow = lane & 15;
  int row0 = blockIdx.y * 64, col0 = blockIdx.x * 64;

  int arow = tid >> 2, akc = tid & 3;
  int grow = row0 + arow; if (grow >= Nr) grow = Nr - 1;
  const __hip_bfloat16* agp = A + (size_t)grow * K + akc * 8;
  const __hip_bfloat16* bgp = Bt + (size_t)(col0 + arow) * K + akc * 8;
  short* asp = &As[arow * 40 + akc * 8];
  short* bsp = &Bs[arow * 40 + akc * 8];

  f32x4 acc00 = {0.f,0.f,0.f,0.f}, acc01 = acc00, acc10 = acc00, acc11 = acc00;

  int lkc = lane >> 4;
  const short* a0p = &As[(wr * 32 + lrow) * 40 + lkc * 8];
  const short* a1p = &As[(wr * 32 + 16 + lrow) * 40 + lkc * 8];
  const short* b0p = &Bs[(wc * 32 + lrow) * 40 + lkc * 8];
  const short* b1p = &Bs[(wc * 32 + 16 + lrow) * 40 + lkc * 8];

  // software-pipelined: prefetch next tile before compute
  short8v av = *(const short8v*)agp;
  short8v bv = *(const short8v*)bgp;
  for (int k0 = 0; k0 < K; k0 += 32) {
    __syncthreads();
    *(short8v*)asp = av;
    *(short8v*)bsp = bv;
    __syncthreads();
    if (k0 + 32 < K) {
      av = *(const short8v*)(agp + k0 + 32);
      bv = *(const short8v*)(bgp + k0 + 32);
    }
    short8v a0 = *(const short8v*)a0p;
    short8v a1 = *(const short8v*)a1p;
    short8v b0 = *(const short8v*)b0p;
    short8v b1 = *(const short8v*)b1p;
    acc00 = __builtin_amdgcn_mfma_f32_16x16x32_bf16(a0, b0, acc00, 0, 0, 0);
    acc01 = __builtin_amdgcn_mfma_f32_16x16x32_bf16(a0, b1, acc01, 0, 0, 0);
    acc10 = __builtin_amdgcn_mfma_f32_16x16x32_bf16(a1, b0, acc10, 0, 0, 0);
    acc11 = __builtin_amdgcn_mfma_f32_16x16x32_bf16(a1, b1, acc11, 0, 0, 0);
  }

  // C/D layout (m89): col = lane&15, row = (lane>>4)*4 + r
  int rbase = row0 + wr * 32 + (lane >> 4) * 4;
  int cbase = col0 + wc * 32 + lrow;
  int hplane = col0 >> 7;
  float part0 = 0.f, part1 = 0.f;   // colsum partials (n=0, n=1)
  float esp[2][4], edp[2][4];       // coef partials per (m, r)
  float as0, as1, ad0, ad1;
  if (COEF) {
#pragma unroll
    for (int m = 0; m < 2; ++m)
#pragma unroll
      for (int r = 0; r < 4; ++r) { esp[m][r] = 0.f; edp[m][r] = 0.f; }
    int ch0 = (cbase & 127);
    as0 = as_[hplane * 128 + ch0];
    as1 = as_[hplane * 128 + ch0 + 16];
    ad0 = ad_[hplane * 128 + ch0];
    ad1 = ad_[hplane * 128 + ch0 + 16];
  }
#pragma unroll
  for (int m = 0; m < 2; ++m) {
#pragma unroll
    for (int n = 0; n < 2; ++n) {
      f32x4 acc = m == 0 ? (n == 0 ? acc00 : acc01) : (n == 0 ? acc10 : acc11);
      int col = cbase + n * 16;
      int plane = col >> 7, ch = col & 127;
      float bv2 = BIAS ? bias[col] : 0.f;
      __hip_bfloat16* cp = Cb + (size_t)plane * Nr * 128 + ch;
#pragma unroll
      for (int r = 0; r < 4; ++r) {
        int grow2 = rbase + m * 16 + r;
        if (grow2 >= Nr) continue;
        float v = acc[r] + bv2;
        cp[(size_t)grow2 * 128] = __float2bfloat16(v);
        if (COLSUM) { if (n == 0) part0 += v; else part1 += v; }
        if (COEF) {
          esp[m][r] += v * (n == 0 ? as0 : as1);
          edp[m][r] += v * (n == 0 ? ad0 : ad1);
        }
      }
    }
  }
  if (COLSUM) {
    part0 += __shfl_xor(part0, 16); part0 += __shfl_xor(part0, 32);
    part1 += __shfl_xor(part1, 16); part1 += __shfl_xor(part1, 32);
    if (lane < 16) {
      atomicAdd(&colsum[cbase], part0);
      atomicAdd(&colsum[cbase + 16], part1);
    }
  }
  if (COEF) {
#pragma unroll
    for (int m = 0; m < 2; ++m) {
#pragma unroll
      for (int r = 0; r < 4; ++r) {
        float e = esp[m][r], d = edp[m][r];
        e += __shfl_xor(e, 1); e += __shfl_xor(e, 2);
        e += __shfl_xor(e, 4); e += __shfl_xor(e, 8);
        d += __shfl_xor(d, 1); d += __shfl_xor(d, 2);
        d += __shfl_xor(d, 4); d += __shfl_xor(d, 8);
        if ((lane & 15) == 0) {
          int grow2 = rbase + m * 16 + r;
          if (grow2 < Nr) {
            atomicAdd(&es[(size_t)hplane * Nr + grow2], e);
            atomicAdd(&ed[(size_t)hplane * Nr + grow2], d);
          }
        }
      }
    }
  }
}

// ---------------- wave-per-output GEMM: C = relu(A @ Bt^T + bias) ----------------
__global__ void k_dotmm(const float* __restrict__ A, const float* __restrict__ Bt,
                        const float* __restrict__ bias, float* __restrict__ C,
                        int Nr, int K, int M) {
  int wid = (blockIdx.x * blockDim.x + threadIdx.x) >> 6;
  int lane = threadIdx.x & 63;
  if (wid >= Nr * M) return;
  int b = wid / M, m = wid % M;
  const float* ar = A + (size_t)b * K;
  const float* br = Bt + (size_t)m * K;
  float acc = 0.f;
  for (int k = lane * 2; k + 1 < K; k += 128) {
    float2 av = *(const float2*)(ar + k);
    float2 bv = *(const float2*)(br + k);
    acc += av.x * bv.x + av.y * bv.y;
  }
#pragma unroll
  for (int off = 32; off; off >>= 1) acc += __shfl_xor(acc, off);
  if (lane == 0) C[wid] = fmaxf(acc + bias[m], 0.f);
}

// ---------------- CSR build ----------------
__global__ void k_scan(const int* __restrict__ deg, int* __restrict__ rowptr, int N) {
  __shared__ int part[1024];
  int t = threadIdx.x;
  int chunk = (N + 1023) >> 10;
  int b0 = t * chunk, b1 = min(N, b0 + chunk);
  int s = 0;
  for (int i = b0; i < b1; i++) s += deg[i];
  part[t] = s;
  __syncthreads();
  for (int off = 1; off < 1024; off <<= 1) {
    int v = (t >= off) ? part[t - off] : 0;
    __syncthreads();
    part[t] += v;
    __syncthreads();
  }
  int run = (t == 0) ? 0 : part[t - 1];
  for (int i = b0; i < b1; i++) { rowptr[i] = run; run += deg[i]; }
  if (b1 == N) rowptr[N] = run;
}

__global__ void k_fill_adj(const int* __restrict__ src0, const int* __restrict__ dst0,
                           const int* __restrict__ rowptr, int* __restrict__ cursor,
                           int* __restrict__ adj, int E) {
  int e = blockIdx.x * 256 + threadIdx.x;
  if (e >= E) return;
  int s = src0[e], d = dst0[e];
  if (s != d) {
    int pos = rowptr[d] + atomicAdd(&cursor[d], 1);
    adj[pos] = s;
  }
}

// 8-edge broadcast accumulate with (s,p) PACKED per lane:
//   pk = (bf16bits(p) << 16) | s,  requires s < 32768 and p >= 0.
__device__ __forceinline__ void acc8p(const char* xbase, int loff, unsigned pk, int j,
                                      float& a0, float& a1) {
  unsigned k0 = __builtin_amdgcn_readlane(pk, j);
  unsigned k1 = __builtin_amdgcn_readlane(pk, j + 1);
  unsigned k2 = __builtin_amdgcn_readlane(pk, j + 2);
  unsigned k3 = __builtin_amdgcn_readlane(pk, j + 3);
  unsigned k4 = __builtin_amdgcn_readlane(pk, j + 4);
  unsigned k5 = __builtin_amdgcn_readlane(pk, j + 5);
  unsigned k6 = __builtin_amdgcn_readlane(pk, j + 6);
  unsigned k7 = __builtin_amdgcn_readlane(pk, j + 7);
  unsigned u0 = *(const unsigned*)(xbase + (size_t)(k0 & 0x7FFFu) * 256 + loff);
  unsigned u1 = *(const unsigned*)(xbase + (size_t)(k1 & 0x7FFFu) * 256 + loff);
  unsigned u2 = *(const unsigned*)(xbase + (size_t)(k2 & 0x7FFFu) * 256 + loff);
  unsigned u3 = *(const unsigned*)(xbase + (size_t)(k3 & 0x7FFFu) * 256 + loff);
  unsigned u4 = *(const unsigned*)(xbase + (size_t)(k4 & 0x7FFFu) * 256 + loff);
  unsigned u5 = *(const unsigned*)(xbase + (size_t)(k5 & 0x7FFFu) * 256 + loff);
  unsigned u6 = *(const unsigned*)(xbase + (size_t)(k6 & 0x7FFFu) * 256 + loff);
  unsigned u7 = *(const unsigned*)(xbase + (size_t)(k7 & 0x7FFFu) * 256 + loff);
  float p0 = __uint_as_float(k0 & 0xFFFF0000u);
  float p1 = __uint_as_float(k1 & 0xFFFF0000u);
  float p2 = __uint_as_float(k2 & 0xFFFF0000u);
  float p3 = __uint_as_float(k3 & 0xFFFF0000u);
  float p4 = __uint_as_float(k4 & 0xFFFF0000u);
  float p5 = __uint_as_float(k5 & 0xFFFF0000u);
  float p6 = __uint_as_float(k6 & 0xFFFF0000u);
  float p7 = __uint_as_float(k7 & 0xFFFF0000u);
  a0 += p0 * bf2lo(u0); a1 += p0 * bf2hi(u0);
  a0 += p1 * bf2lo(u1); a1 += p1 * bf2hi(u1);
  a0 += p2 * bf2lo(u2); a1 += p2 * bf2hi(u2);
  a0 += p3 * bf2lo(u3); a1 += p3 * bf2hi(u3);
  a0 += p4 * bf2lo(u4); a1 += p4 * bf2hi(u4);
  a0 += p5 * bf2lo(u5); a1 += p5 * bf2hi(u5);
  a0 += p6 * bf2lo(u6); a1 += p6 * bf2hi(u6);
  a0 += p7 * bf2lo(u7); a1 += p7 * bf2hi(u7);
}

// ---------------- fused GAT aggregation: one wave per (node, head), 2D grid ----------
// NOTE: requires N < 32768 (15-bit packed row index); harness N = 20000.
__global__ void k_gat_gather(const int* __restrict__ rowptr, const int* __restrict__ adj,
                             const float* __restrict__ es, const float* __restrict__ ed,
                             const __hip_bfloat16* __restrict__ xh,
                             const float* __restrict__ bias,
                             __hip_bfloat16* __restrict__ gout, int N, int H) {
  int nb = gridDim.x, bx = blockIdx.x;
  int sb = ((nb & 7) == 0) ? ((bx & 7) * (nb >> 3) + (bx >> 3)) : bx;
  int h = blockIdx.y;
  int n = sb * 4 + (threadIdx.x >> 6);
  int lane = threadIdx.x & 63;
  if (n >= N) return;
  int base = rowptr[n];
  int deg = rowptr[n + 1] - base;
  const float* esh = es + (size_t)h * N;
  float edn = ed[(size_t)h * N + n];
  float vself = leaky(esh[n] + edn);
  const char* xbase = (const char*)xh + (size_t)h * N * 256;
  int loff = lane * 4;

  float a0 = 0.f, a1 = 0.f;
  float psum = 0.f, pself, m;

  if (deg <= 64) {
    int s = 0; float v = -3e38f;
    if (lane < deg) { s = adj[base + lane]; v = leaky(esh[s] + edn); }
    m = fmaxf(vself, v);
#pragma unroll
    for (int off = 32; off; off >>= 1) m = fmaxf(m, __shfl_xor(m, off));
    float p = (lane < deg) ? __expf(v - m) : 0.f;
    pself = __expf(vself - m);
    psum = p;
    unsigned pk = (__float_as_uint(p) & 0xFFFF0000u) | (unsigned)s;
    for (int j = 0; j < deg; j += 8) acc8p(xbase, loff, pk, j, a0, a1);
  } else {
    m = vself;
    for (int i = lane; i < deg; i += 64) {
      int s = adj[base + i];
      m = fmaxf(m, leaky(esh[s] + edn));
    }
#pragma unroll
    for (int off = 32; off; off >>= 1) m = fmaxf(m, __shfl_xor(m, off));
    pself = __expf(vself - m);
    for (int c = 0; c < deg; c += 64) {
      int i = c + lane;
      int s = 0; float p = 0.f;
      if (i < deg) {
        s = adj[base + i];
        p = __expf(leaky(esh[s] + edn) - m);
        psum += p;
      }
      unsigned pk = (__float_as_uint(p) & 0xFFFF0000u) | (unsigned)s;
      int cnt = min(64, deg - c);
      for (int j = 0; j < cnt; j += 8) acc8p(xbase, loff, pk, j, a0, a1);
    }
  }

  {
    unsigned u = *(const unsigned*)(xbase + (size_t)n * 256 + loff);
    a0 += pself * bf2lo(u);
    a1 += pself * bf2hi(u);
  }
#pragma unroll
  for (int off = 32; off; off >>= 1) psum += __shfl_xor(psum, off);
  psum += pself;
  float inv = 1.f / psum;
  float2 bv = ((const float2*)(bias + h * 128))[lane];
  float o0 = a0 * inv + bv.x;
  float o1 = a1 * inv + bv.y;
  o0 = o0 > 0.f ? o0 : __expf(o0) - 1.f;
  o1 = o1 > 0.f ? o1 : __expf(o1) - 1.f;
  __hip_bfloat162 r;
  r.x = __float2bfloat16(o0);
  r.y = __float2bfloat16(o1);
  ((__hip_bfloat162*)(gout + (size_t)n * (H * 128) + h * 128))[lane] = r;
}

// single block head MLP -> vvec[384]
__global__ void k_head(const float* __restrict__ colsum, const float* __restrict__ Wfc,
                       const float* __restrict__ bfc, const float* __restrict__ Whg,
                       const float* __restrict__ bhg, const float* __restrict__ Wv,
                       const float* __restrict__ bv, float* __restrict__ vvec, float invN) {
  __shared__ float h[128], t1[256], hg[128];
  int t = threadIdx.x;  // 256
  if (t < 128) h[t] = colsum[t] * invN;
  __syncthreads();
  float acc = bfc[t];
  for (int k = 0; k < 128; k++) acc += h[k] * Wfc[k * 256 + t];
  t1[t] = fmaxf(acc, 0.f);
  __syncthreads();
  if (t < 128) {
    float a2 = bhg[t];
    for (int k = 0; k < 256; k++) a2 += t1[k] * Whg[k * 128 + t];
    hg[t] = a2;
  }
  __syncthreads();
  for (int j = t; j < 384; j += 256) {
    float a3 = bv[j];
    for (int k = 0; k < 128; k++) a3 += hg[k] * Wv[k * 384 + j];
    vvec[j] = fmaxf(a3, 0.f);
  }
}

// per-batch-row BAN tail
__global__ void k_fused(const float* __restrict__ vvec, const float* __restrict__ q,
                        const float* __restrict__ hmat, const float* __restrict__ hbias,
                        float* __restrict__ logits) {
  int b = blockIdx.x, c = threadIdx.x;  // 128 threads
  __shared__ float red[128];
  float t[3];
  float part = 0.f;
#pragma unroll
  for (int j = 0; j < 3; j++) {
    int k = c * 3 + j;
    float hs = hmat[k] + hmat[384 + k] + hmat[768 + k] + hmat[1152 + k];
    t[j] = vvec[k] * q[(size_t)b * 384 + k];
    part += hs * t[j];
  }
  red[c] = part;
  __syncthreads();
  for (int s = 64; s > 0; s >>= 1) {
    if (c < s) red[c] += red[c + s];
    __syncthreads();
  }
  float attsum = red[0] + (hbias[0] + hbias[1] + hbias[2] + hbias[3]);
  logits[(size_t)b * 128 + c] = attsum * (t[0] + t[1] + t[2]);
}

// batchnorm over batch dim (biased var), one block per channel c
__global__ void k_bn(const float* __restrict__ logits, const float* __restrict__ gamma,
                     const float* __restrict__ beta, float* __restrict__ out, int B) {
  int c = blockIdx.x, b = threadIdx.x;  // B threads
  __shared__ float s1[256], s2[256];
  float v = logits[(size_t)b * 128 + c];
  s1[b] = v; s2[b] = v * v;
  __syncthreads();
  for (int s = B / 2; s > 0; s >>= 1) {
    if (b < s) { s1[b] += s1[b + s]; s2[b] += s2[b + s]; }
    __syncthreads();
  }
  float mu = s1[0] / B;
  float var = s2[0] / B - mu * mu;
  out[(size_t)b * 128 + c] = (v - mu) * rsqrtf(var + 1e-5f) * gamma[c] + beta[c];
}

extern "C" void kernel_launch(void* const* d_in, const int* in_sizes, int n_in,
                              void* d_out, int out_size, void* d_ws, size_t ws_size,
                              hipStream_t stream) {
  const float* cell = (const float*)d_in[0];
  const float* Wd   = (const float*)d_in[1];
  const float* bd   = (const float*)d_in[2];
  const float* W1   = (const float*)d_in[3];
  const float* a1s  = (const float*)d_in[4];
  const float* a1d  = (const float*)d_in[5];
  const float* b1   = (const float*)d_in[6];
  const float* Wl1  = (const float*)d_in[7];
  const float* bl1  = (const float*)d_in[8];
  const float* W2   = (const float*)d_in[9];
  const float* a2s  = (const float*)d_in[10];
  const float* a2d  = (const float*)d_in[11];
  const float* b2   = (const float*)d_in[12];
  const float* Wl2  = (const float*)d_in[13];
  const float* bl2  = (const float*)d_in[14];
  const float* Wfc  = (const float*)d_in[15];
  const float* bfc  = (const float*)d_in[16];
  const float* Whg  = (const float*)d_in[17];
  const float* bhg  = (const float*)d_in[18];
  const float* Wc   = (const float*)d_in[19];
  const float* bc   = (const float*)d_in[20];
  const float* Wv   = (const float*)d_in[21];
  const float* bv   = (const float*)d_in[22];
  const float* Wq   = (const float*)d_in[23];
  const float* bq   = (const float*)d_in[24];
  const float* hmat = (const float*)d_in[25];
  const float* hbias= (const float*)d_in[26];
  const float* gamma= (const float*)d_in[27];
  const float* beta = (const float*)d_in[28];
  const int* trip   = (const int*)d_in[29];
  const int* eidx   = (const int*)d_in[30];

  const int N = in_sizes[29] / 4;     // 20000
  const int E = in_sizes[30] / 2;     // 500000
  const int B = in_sizes[0] / 954;    // 256
  float* out = (float*)d_out;

  // ---------------- workspace layout: bf16 region first (16B aligned) ----------------
  __hip_bfloat16* xb    = (__hip_bfloat16*)d_ws;      // N*128
  __hip_bfloat16* xhb   = xb + (size_t)N * 128;       // N*640  (head-major [H][N][128])
  __hip_bfloat16* goutb = xhb + (size_t)N * 640;      // N*640  (row-major [N][H*128])
  __hip_bfloat16* h1b   = goutb + (size_t)N * 640;    // N*128
  __hip_bfloat16* h2b   = h1b + (size_t)N * 128;      // N*128
  __hip_bfloat16* W1t   = h2b + (size_t)N * 128;      // 512*128
  __hip_bfloat16* Wl1t  = W1t + 512 * 128;            // 128*512
  __hip_bfloat16* W2t   = Wl1t + 128 * 512;           // 640*128
  __hip_bfloat16* Wl2t  = W2t + 640 * 128;            // 128*640
  // f32 region: per-layer es/ed (contiguous 18N for one-shot zeroing)
  float* es1    = (float*)(Wl2t + 128 * 640);  // 4N
  float* ed1    = es1 + (size_t)4 * N;         // 4N
  float* es2    = ed1 + (size_t)4 * N;         // 5N
  float* ed2    = es2 + (size_t)5 * N;         // 5N
  float* colsum = ed2 + (size_t)5 * N;         // 128
  float* cbuf   = colsum + 128;                // B*128
  float* qbuf   = cbuf + (size_t)B * 128;      // B*384
  float* vvec   = qbuf + (size_t)B * 384;      // 384
  float* logits = vvec + 384;                  // B*128
  float* Wct    = logits + (size_t)B * 128;    // 128*954
  float* Wqt    = Wct + 128 * 954;             // 384*128
  // int region
  int* rowptr   = (int*)(Wqt + 384 * 128);     // N+1
  int* degb     = rowptr + (N + 1);            // N
  int* cursor   = degb + N;                    // N (contiguous after degb)
  int* adj      = cursor + N;                  // E

  const int* src0 = eidx;
  const int* dst0 = eidx + E;

  // weight transposes + zeroing of colsum/degb/cursor/es/ed in one launch
  {
    int tot = 128*512 + 512*128 + 128*640 + 640*128 + 954*128 + 128*384
              + 128 + 2 * N + 18 * N;
    k_prep<<<CDIV(tot, 256), 256, 0, stream>>>(W1, W1t, Wl1, Wl1t, W2, W2t, Wl2, Wl2t,
                                               Wc, Wct, Wq, Wqt, colsum, degb, es1, N);
  }

  // degree count + drug linear in one dispatch
  k_degdrug<<<CDIV(E + N * 128, 256), 256, 0, stream>>>(src0, dst0, degb, E,
                                                        trip, Wd, bd, xb, N);
  k_scan<<<1, 1024, 0, stream>>>(degb, rowptr, N);
  k_fill_adj<<<CDIV(E, 256), 256, 0, stream>>>(src0, dst0, rowptr, cursor, adj, E);

  // ---------------- GAT1 (H=4) ----------------
  {
    dim3 g(512 / 64, CDIV(N, 64));
    k_gemm_mfma<false, false, true><<<g, 256, 0, stream>>>(
        xb, W1t, nullptr, xhb, nullptr, a1s, a1d, es1, ed1, N, 128, 512);
  }
  {
    dim3 g(CDIV(N, 4), 4);
    k_gat_gather<<<g, 256, 0, stream>>>(rowptr, adj, es1, ed1, xhb, b1, goutb, N, 4);
  }
  {
    dim3 g(128 / 64, CDIV(N, 64));
    k_gemm_mfma<true, true, false><<<g, 256, 0, stream>>>(
        goutb, Wl1t, bl1, h1b, colsum, nullptr, nullptr, nullptr, nullptr, N, 512, 128);
  }

  // ---------------- GAT2 (H=5) ----------------
  {
    dim3 g(640 / 64, CDIV(N, 64));
    k_gemm_mfma<false, false, true><<<g, 256, 0, stream>>>(
        h1b, W2t, nullptr, xhb, nullptr, a2s, a2d, es2, ed2, N, 128, 640);
  }
  {
    dim3 g(CDIV(N, 4), 5);
    k_gat_gather<<<g, 256, 0, stream>>>(rowptr, adj, es2, ed2, xhb, b2, goutb, N, 5);
  }
  {
    dim3 g(128 / 64, CDIV(N, 64));
    k_gemm_mfma<true, true, false><<<g, 256, 0, stream>>>(
        goutb, Wl2t, bl2, h2b, colsum, nullptr, nullptr, nullptr, nullptr, N, 640, 128);
  }

  // ---------------- head + BAN + BN ----------------
  k_head<<<1, 256, 0, stream>>>(colsum, Wfc, bfc, Whg, bhg, Wv, bv, vvec, 1.0f / N);
  k_dotmm<<<CDIV(B * 128, 4), 256, 0, stream>>>(cell, Wct, bc, cbuf, B, 954, 128);
  k_dotmm<<<CDIV(B * 384, 4), 256, 0, stream>>>(cbuf, Wqt, bq, qbuf, B, 128, 384);
  k_fused<<<B, 128, 0, stream>>>(vvec, qbuf, hmat, hbias, logits);
  k_bn<<<128, B, 0, stream>>>(logits, gamma, beta, out, B);
}